// Round 4
// baseline (839.241 us; speedup 1.0000x reference)
//
#include <hip/hip_runtime.h>
#include <cfloat>
#include <cmath>

// ---------------------------------------------------------------------------
// Qwen3Attention fake-quant forward. B=2 S=1024 HID=2048 NH=16 NKV=8 D=128.
// Round 10 (resubmit; round-3 bench was an infra failure): q3-level store.
// The f3 quantization makes each causal logit an exact u16 level; denom
// stores them (masked diag elems store the row's vv level). pv becomes a
// barrier-free dequant-GEMM (read q3 -> n -> PV MFMA), and the 134 MB attn
// f32 write moves to a uniform BW-bound expand kernel. 32-row groups paired
// (j, 31-j) = constant 9 chunk-units/block.
// ---------------------------------------------------------------------------

#define FQ_EPS      1.5259021896696422e-09f   // 0.0001/65535
#define SCALING_F   0.08838834764831845f      // 128**-0.5
#define S_LEN       1024

typedef _Float16 h8_t __attribute__((ext_vector_type(8)));
typedef _Float16 h4_t __attribute__((ext_vector_type(4)));
typedef float    f4_t __attribute__((ext_vector_type(4)));
typedef unsigned short u16x4 __attribute__((ext_vector_type(4)));

// ---- float <-> order-preserving unsigned encoding (for atomic min/max) ----
__device__ __forceinline__ unsigned f2o(float f){
  unsigned u = __float_as_uint(f);
  return (u & 0x80000000u) ? ~u : (u | 0x80000000u);
}
__device__ __forceinline__ float o2f(unsigned u){
  return __uint_as_float((u & 0x80000000u) ? (u ^ 0x80000000u) : ~u);
}
__device__ __forceinline__ float dec_slot(const unsigned* st, int s){ return o2f(st[s*16]); }

// ---- fq16 helpers ----
struct FQP { float scale, zp, inv; };
__device__ __forceinline__ FQP fqp_raw(float mn, float mx){
  FQP p; p.scale = fmaxf((mx - mn)/65535.0f, FQ_EPS); p.zp = rintf(-mn/p.scale);
  p.inv = 1.0f/p.scale; return p;
}
__device__ __forceinline__ FQP fqp(float mn0, float mx0){
  return fqp_raw(fminf(mn0, 0.0f), fmaxf(mx0, 0.0f));
}
__device__ __forceinline__ float fqa(float x, FQP p){
  float q = rintf(x*p.inv) + p.zp;
  q = fminf(fmaxf(q, 0.0f), 65535.0f);
  return (q - p.zp)*p.scale;
}
__device__ __forceinline__ float fq8(float x, float s, float si){
  return fminf(fmaxf(rintf(x*si), -128.0f), 127.0f)*s;
}

// ---- block reductions (blockDim == 256) ----
__device__ __forceinline__ float bred_min(float v, float* red){
  int tid = threadIdx.x; red[tid] = v; __syncthreads();
  for (int s = 128; s > 0; s >>= 1){ if (tid < s) red[tid] = fminf(red[tid], red[tid+s]); __syncthreads(); }
  float r = red[0]; __syncthreads(); return r;
}
__device__ __forceinline__ float bred_max(float v, float* red){
  int tid = threadIdx.x; red[tid] = v; __syncthreads();
  for (int s = 128; s > 0; s >>= 1){ if (tid < s) red[tid] = fmaxf(red[tid], red[tid+s]); __syncthreads(); }
  float r = red[0]; __syncthreads(); return r;
}

// ---- stats slot map (even=min, odd=max) ----
// 0/1 hs | 2/3 qlin | 4/5 klin | 6/7 vlin | 8/9 qn | 10/11 qn2 | 12/13 kn | 14/15 kn2
// 16/17 q*c | 18/19 qrh*s | 20/21 k*c | 22/23 krh*s | 24/25 qsum | 26/27 ksum
// 28/29 logits | 31 unmaskedMax | 32 denomMin | 35 maxOfRowMins | 36/37 ctx

__global__ void k_init(unsigned* stats){
  int i = blockIdx.x*blockDim.x + threadIdx.x;
  if (i < 1024) stats[i] = (((i & 15) == 0) && (((i >> 4) & 1) == 0)) ? 0xFFFFFFFFu : 0u;
}

// lpbq weight quantization -> f16. 4 elems/thread; 8-lane shfl = 32-elem block.
__global__ __launch_bounds__(256) void k_quantw(const float* __restrict__ W, _Float16* __restrict__ Wh){
  int i = blockIdx.x*256 + threadIdx.x;
  float4 v = ((const float4*)W)[i];
  float am = fmaxf(fmaxf(fabsf(v.x), fabsf(v.y)), fmaxf(fabsf(v.z), fabsf(v.w)));
  #pragma unroll
  for (int m = 1; m < 8; m <<= 1) am = fmaxf(am, __shfl_xor(am, m, 64));
  float s = fmaxf(am/7.0f, 1e-12f), si = 1.0f/s;
  h4_t o;
  o[0] = (_Float16)(fminf(fmaxf(rintf(v.x*si), -8.0f), 7.0f)*s);
  o[1] = (_Float16)(fminf(fmaxf(rintf(v.y*si), -8.0f), 7.0f)*s);
  o[2] = (_Float16)(fminf(fmaxf(rintf(v.z*si), -8.0f), 7.0f)*s);
  o[3] = (_Float16)(fminf(fmaxf(rintf(v.w*si), -8.0f), 7.0f)*s);
  *(h4_t*)(Wh + ((size_t)i << 2)) = o;
}

__global__ __launch_bounds__(256) void k_minmax(const float* __restrict__ x, int n, unsigned* stats, int slot){
  float mn = FLT_MAX, mx = -FLT_MAX;
  for (int i = blockIdx.x*256 + threadIdx.x; i < n; i += gridDim.x*256){
    float v = x[i]; mn = fminf(mn, v); mx = fmaxf(mx, v);
  }
  __shared__ float red[256];
  float bmn = bred_min(mn, red), bmx = bred_max(mx, red);
  if (threadIdx.x == 0){ atomicMin(&stats[slot*16], f2o(bmn)); atomicMax(&stats[(slot+1)*16], f2o(bmx)); }
}

// fq16 elementwise -> f16, 4 elems/thread
__global__ __launch_bounds__(256) void k_fq_ew16(const float* __restrict__ x, _Float16* __restrict__ y,
                                                 const unsigned* stats, int slot){
  FQP p = fqp(dec_slot(stats, slot), dec_slot(stats, slot+1));
  int i = blockIdx.x*256 + threadIdx.x;
  float4 v = ((const float4*)x)[i];
  h4_t o;
  o[0] = (_Float16)fqa(v.x, p); o[1] = (_Float16)fqa(v.y, p);
  o[2] = (_Float16)fqa(v.z, p); o[3] = (_Float16)fqa(v.w, p);
  *(h4_t*)(y + ((size_t)i << 2)) = o;
}

// fq8(fq16(x)) elementwise -> f16 (for K)
__global__ __launch_bounds__(256) void k_fq8_ew16(const float* __restrict__ x, _Float16* __restrict__ y,
                                                  const unsigned* stats, int slot){
  FQP p = fqp(dec_slot(stats, slot), dec_slot(stats, slot+1));
  float lo = fqa(dec_slot(stats, slot), p), hi = fqa(dec_slot(stats, slot+1), p);
  float s8 = fmaxf(fmaxf(fabsf(lo), fabsf(hi))/127.0f, 1e-12f), s8i = 1.0f/s8;
  int i = blockIdx.x*256 + threadIdx.x;
  float4 v = ((const float4*)x)[i];
  h4_t o;
  o[0] = (_Float16)fq8(fqa(v.x, p), s8, s8i); o[1] = (_Float16)fq8(fqa(v.y, p), s8, s8i);
  o[2] = (_Float16)fq8(fqa(v.z, p), s8, s8i); o[3] = (_Float16)fq8(fqa(v.w, p), s8, s8i);
  *(h4_t*)(y + ((size_t)i << 2)) = o;
}

// ================= f16 MFMA GEMM core for projections (NT) =================
// async staging: LDS dest is wave-uniform base + lane*16B (constraint-safe).
#define GLDS16(g, l) __builtin_amdgcn_global_load_lds( \
    (__attribute__((address_space(1))) unsigned int*)(g), \
    (__attribute__((address_space(3))) unsigned int*)(l), 16, 0, 0)

__device__ __forceinline__ void stage_tile(const _Float16* __restrict__ src, int ld, int k0,
                                           _Float16* __restrict__ dst){
  #pragma unroll
  for (int it = 0; it < 2; it++){
    int c = threadIdx.x + (it << 8);
    int row = c >> 2, off = (c & 3) << 3;
    GLDS16(src + (size_t)row*ld + k0 + off, dst + (c << 3));
  }
}

__device__ __forceinline__ void hgemm_main(const _Float16* __restrict__ A, int lda,
                                           const _Float16* __restrict__ B, int ldb, int K,
                                           f4_t acc[4][4], _Float16* As, _Float16* Bs){
  int lane = threadIdx.x & 63, wave = threadIdx.x >> 6;
  int wm = wave & 1, wn = wave >> 1, quad = lane >> 4, l15 = lane & 15;
  for (int k0 = 0; k0 < K; k0 += 32){
    __syncthreads();
    stage_tile(A, lda, k0, As);
    stage_tile(B, ldb, k0, Bs);
    __syncthreads();
    h8_t af[4], bf[4];
    #pragma unroll
    for (int mt = 0; mt < 4; mt++)
      af[mt] = *(const h8_t*)(As + ((((wm<<6) + (mt<<4) + l15)) << 5) + (quad << 3));
    #pragma unroll
    for (int nt = 0; nt < 4; nt++)
      bf[nt] = *(const h8_t*)(Bs + ((((wn<<6) + (nt<<4) + l15)) << 5) + (quad << 3));
    #pragma unroll
    for (int mt = 0; mt < 4; mt++)
      #pragma unroll
      for (int nt = 0; nt < 4; nt++)
        acc[mt][nt] = __builtin_amdgcn_mfma_f32_16x16x32_f16(af[mt], bf[nt], acc[mt][nt], 0, 0, 0);
  }
}

#define HG_PROLOG  \
  __shared__ __align__(16) _Float16 As[4096], Bs[4096]; \
  __shared__ float red[256]; \
  f4_t acc[4][4]; \
  { f4_t zz = {0.f,0.f,0.f,0.f}; \
    for (int i=0;i<4;i++) for (int j=0;j<4;j++) acc[i][j] = zz; } \
  int lane = threadIdx.x & 63, wave = threadIdx.x >> 6; \
  int wm = wave & 1, wn = wave >> 1, quad = lane >> 4, l15 = lane & 15; (void)red; (void)lane;

// C/D lane map (m89-verified): D[row=(quad*4+reg)][col=l15].

__global__ __launch_bounds__(256) void k_hgemm_f(const _Float16* __restrict__ A, const _Float16* __restrict__ B,
                                                 float* __restrict__ C, int N, int K,
                                                 unsigned* stats, int slotC){
  HG_PROLOG
  int bm = blockIdx.y << 7, bn = blockIdx.x << 7;
  hgemm_main(A + (size_t)bm*K, K, B + (size_t)bn*K, K, K, acc, As, Bs);
  float mn = FLT_MAX, mx = -FLT_MAX;
  #pragma unroll
  for (int mt = 0; mt < 4; mt++)
    #pragma unroll
    for (int nt = 0; nt < 4; nt++){
      int Cc = bn + (wn<<6) + (nt<<4) + l15;
      #pragma unroll
      for (int i = 0; i < 4; i++){
        int R = bm + (wm<<6) + (mt<<4) + (quad<<2) + i;
        float v = acc[mt][nt][i];
        C[(size_t)R*N + Cc] = v;
        mn = fminf(mn, v); mx = fmaxf(mx, v);
      }
    }
  if (slotC >= 0){
    float bmn = bred_min(mn, red), bmx = bred_max(mx, red);
    if (threadIdx.x == 0){ atomicMin(&stats[slotC*16], f2o(bmn)); atomicMax(&stats[(slotC+1)*16], f2o(bmx)); }
  }
}

// fused K/V projections: z=0 -> (Bk, Ck, slot4), z=1 -> (Bv, Cv, slot6)
__global__ __launch_bounds__(256) void k_hgemm_kv(const _Float16* __restrict__ A,
                                                  const _Float16* __restrict__ Bk, const _Float16* __restrict__ Bv,
                                                  float* __restrict__ Ck, float* __restrict__ Cv,
                                                  int K, unsigned* stats){
  HG_PROLOG
  const _Float16* B = blockIdx.z ? Bv : Bk;
  float* C = blockIdx.z ? Cv : Ck;
  int slotC = blockIdx.z ? 6 : 4;
  int bm = blockIdx.y << 7, bn = blockIdx.x << 7;
  hgemm_main(A + (size_t)bm*K, K, B + (size_t)bn*K, K, K, acc, As, Bs);
  float mn = FLT_MAX, mx = -FLT_MAX;
  #pragma unroll
  for (int mt = 0; mt < 4; mt++)
    #pragma unroll
    for (int nt = 0; nt < 4; nt++){
      int Cc = bn + (wn<<6) + (nt<<4) + l15;
      #pragma unroll
      for (int i = 0; i < 4; i++){
        int R = bm + (wm<<6) + (mt<<4) + (quad<<2) + i;
        float v = acc[mt][nt][i];
        C[(size_t)R*1024 + Cc] = v;
        mn = fminf(mn, v); mx = fmaxf(mx, v);
      }
    }
  float bmn = bred_min(mn, red), bmx = bred_max(mx, red);
  if (threadIdx.x == 0){ atomicMin(&stats[slotC*16], f2o(bmn)); atomicMax(&stats[(slotC+1)*16], f2o(bmx)); }
}

// ====================== QK^T attention passes (32-row) =====================
// block = 256 thr (4 waves). A 32-row group r (0..31) covers q-rows
// [32r, 32r+32); it needs nch(r) = (r>>2)+1 K-chunks of 128. Wave wn owns
// cols [32*wn, 32*wn+32): acc[2][2]. Pairing (j, 31-j) -> constant 9
// chunk-units per block. q3 levels (post-f3 u16) are exact -> stored once by
// denom, consumed by pv (PV GEMM) and expand (attn f32 write) bit-exactly.
// causal unit index: cum(r) = (a+1)*(2a+b), a=r>>2, b=r&3; unit = cum + chunk.

#define QK_IDS \
  int lane = threadIdx.x & 63, wn = threadIdx.x >> 6; \
  int quad = lane >> 4, l15 = lane & 15; \
  int tid = threadIdx.x; (void)tid; (void)lane;

__device__ __forceinline__ void qk_load_a(const _Float16* __restrict__ Ab, int quad, int l15,
                                          h8_t Aq[2][4]){
  #pragma unroll
  for (int mt = 0; mt < 2; mt++)
    #pragma unroll
    for (int k0 = 0; k0 < 4; k0++)
      Aq[mt][k0] = *(const h8_t*)(Ab + (size_t)((mt<<4) + l15)*128 + (k0<<5) + (quad<<3));
}

__device__ __forceinline__ void qk_chunk32(const h8_t Aq[2][4], const _Float16* __restrict__ Kb,
                                           int bn, int wn, int quad, int l15, f4_t acc[2][2]){
  #pragma unroll
  for (int k0 = 0; k0 < 4; k0++){
    h8_t bf[2];
    #pragma unroll
    for (int nt = 0; nt < 2; nt++)
      bf[nt] = *(const h8_t*)(Kb + (size_t)(bn + (wn<<5) + (nt<<4) + l15)*128 + (k0<<5) + (quad<<3));
    #pragma unroll
    for (int mt = 0; mt < 2; mt++)
      #pragma unroll
      for (int nt = 0; nt < 2; nt++)
        acc[mt][nt] = __builtin_amdgcn_mfma_f32_16x16x32_f16(Aq[mt][k0], bf[nt], acc[mt][nt], 0, 0, 0);
  }
}

// pass 1: global logit stats + per-row min / unmasked max (full sweep; the
// fq16 range covers pre-mask logits). 32-row groups, grid (32, 32).
__global__ __launch_bounds__(256) void k_qk_stats(const _Float16* __restrict__ q_h, const _Float16* __restrict__ k_h,
                                                  unsigned* stats, unsigned* rowmin, unsigned* rowmax){
  QK_IDS
  int bm = blockIdx.x << 5, z = blockIdx.y;
  int b = z >> 4, h = z & 15;
  const _Float16* Ab = q_h + (size_t)z*131072 + (size_t)bm*128;
  const _Float16* Kb = k_h + (size_t)(b*8 + (h>>1))*131072;
  h8_t Aq[2][4];
  qk_load_a(Ab, quad, l15, Aq);
  float rmv[2][4], rxv[2][4];
  #pragma unroll
  for (int mt = 0; mt < 2; mt++)
    #pragma unroll
    for (int i = 0; i < 4; i++){ rmv[mt][i] = FLT_MAX; rxv[mt][i] = -FLT_MAX; }
  float mn = FLT_MAX, mx = -FLT_MAX, mxU = -FLT_MAX;
  for (int bn = 0; bn < 1024; bn += 128){
    f4_t acc[2][2];
    { f4_t zz = {0.f,0.f,0.f,0.f}; for (int i=0;i<2;i++) for (int j=0;j<2;j++) acc[i][j]=zz; }
    qk_chunk32(Aq, Kb, bn, wn, quad, l15, acc);
    #pragma unroll
    for (int mt = 0; mt < 2; mt++){
      int rb = bm + (mt<<4) + (quad<<2);
      #pragma unroll
      for (int nt = 0; nt < 2; nt++){
        int t = bn + (wn<<5) + (nt<<4) + l15;
        #pragma unroll
        for (int i = 0; i < 4; i++){
          float v = acc[mt][nt][i];
          mn = fminf(mn, v); mx = fmaxf(mx, v);
          rmv[mt][i] = fminf(rmv[mt][i], v);
          if (t <= rb + i){ mxU = fmaxf(mxU, v); rxv[mt][i] = fmaxf(rxv[mt][i], v); }
        }
      }
    }
  }
  #pragma unroll
  for (int d = 1; d < 16; d <<= 1)
    #pragma unroll
    for (int mt = 0; mt < 2; mt++)
      #pragma unroll
      for (int i = 0; i < 4; i++){
        rmv[mt][i] = fminf(rmv[mt][i], __shfl_xor(rmv[mt][i], d, 64));
        rxv[mt][i] = fmaxf(rxv[mt][i], __shfl_xor(rxv[mt][i], d, 64));
      }
  __shared__ float rminS[4][32], rmaxS[4][32];
  if (l15 == 0){
    #pragma unroll
    for (int mt = 0; mt < 2; mt++)
      #pragma unroll
      for (int i = 0; i < 4; i++){
        int rl = (mt<<4) + (quad<<2) + i;
        rminS[wn][rl] = rmv[mt][i];
        rmaxS[wn][rl] = rxv[mt][i];
      }
  }
  __syncthreads();
  if (tid < 32){
    float a = fminf(fminf(rminS[0][tid], rminS[1][tid]), fminf(rminS[2][tid], rminS[3][tid]));
    float c = fmaxf(fmaxf(rmaxS[0][tid], rmaxS[1][tid]), fmaxf(rmaxS[2][tid], rmaxS[3][tid]));
    rowmin[(z << 10) + bm + tid] = f2o(a);
    rowmax[(z << 10) + bm + tid] = f2o(c);
  }
  __shared__ float red[256];
  float bmn = bred_min(mn, red), bmx = bred_max(mx, red), bmU = bred_max(mxU, red);
  if (tid == 0){
    atomicMin(&stats[28*16], f2o(bmn));
    atomicMax(&stats[29*16], f2o(bmx));
    atomicMax(&stats[31*16], f2o(bmU));
  }
}

__global__ __launch_bounds__(256) void k_rowstat_m2(const unsigned* __restrict__ rowmin, unsigned* stats, int n){
  float lm = -FLT_MAX;
  for (int i = blockIdx.x*256 + threadIdx.x; i < n; i += gridDim.x*256) lm = fmaxf(lm, o2f(rowmin[i]));
  __shared__ float red[256];
  float m = bred_max(lm, red);
  if (threadIdx.x == 0) atomicMax(&stats[35*16], f2o(m));
}
__global__ __launch_bounds__(256) void k_denom_min(const float* __restrict__ denomS, unsigned* stats, int n){
  float lm = FLT_MAX;
  for (int i = blockIdx.x*256 + threadIdx.x; i < n; i += gridDim.x*256) lm = fminf(lm, denomS[i]);
  __shared__ float red[256];
  float m = -bred_max(-lm, red);
  if (threadIdx.x == 0) atomicMin(&stats[32*16], f2o(m));
}

struct LogitQ { FQP f1, f2, fam, fvv, f3; float sc, c20; };
__device__ LogitQ derive_logit(const unsigned* st){
  LogitQ L;
  FQP ps = fqp(SCALING_F, SCALING_F); L.sc = fqa(SCALING_F, ps);
  FQP p20 = fqp(-20.0f, -20.0f);      L.c20 = fqa(-20.0f, p20);
  float gmn = dec_slot(st, 28), gmx = dec_slot(st, 29);
  float gU = dec_slot(st, 31), M2 = dec_slot(st, 35);
  L.f1 = fqp(gmn, gmx);
  float l1lo = fqa(gmn, L.f1), l1hi = fqa(gmx, L.f1);
  L.f2 = fqp(l1lo*L.sc, l1hi*L.sc);
  float amlo = fqa(fqa(gmn, L.f1)*L.sc, L.f2);
  float amhi = fqa(fqa(M2, L.f1)*L.sc, L.f2);
  L.fam = fqp(amlo, amhi);
  float vslo = fqa(amlo, L.fam) + L.c20, vshi = fqa(amhi, L.fam) + L.c20;
  L.fvv = fqp(vslo, vshi);
  float mn3 = fqa(vslo, L.fvv);
  float mx3 = fqa(fqa(gU, L.f1)*L.sc, L.f2);
  L.f3 = fqp(mn3, mx3);
  return L;
}
__device__ __forceinline__ float chainU(float raw, const LogitQ& L){
  return fqa(fqa(fqa(raw, L.f1)*L.sc, L.f2), L.f3);
}

// pass 2: per-row denominators + q3-level store (u16, causal-packed).
// Paired 32-row groups (j, 31-j) = 9 units/block. Skipped masked chunks
// contribute count*exp(vv-m) per row analytically.
__global__ __launch_bounds__(256) void k_qk_denom(const _Float16* __restrict__ q_h, const _Float16* __restrict__ k_h,
                                                  const unsigned* __restrict__ rowmin,
                                                  const unsigned* __restrict__ rowmax,
                                                  float* __restrict__ denomS,
                                                  unsigned short* __restrict__ q3buf,
                                                  const unsigned* stats){
  QK_IDS
  int j = blockIdx.x, z = blockIdx.y;
  int b = z >> 4, h = z & 15;
  LogitQ L = derive_logit(stats);
  const _Float16* Kb = k_h + (size_t)(b*8 + (h>>1))*131072;
  __shared__ float mRow[32], vvRow[32], vvLev[32];
  __shared__ float dS[4][32];
  for (int g = 0; g < 2; g++){
    int r = g ? (31 - j) : j;
    int bm = r << 5;
    int nch = (r >> 2) + 1;
    int cstar = (r >> 2) << 7;          // diagonal-chunk base
    int aa = r >> 2, bb2 = r & 3;
    int cum = (aa + 1)*(2*aa + bb2);    // causal units before group r
    unsigned short* Qu = q3buf + ((size_t)z*144 + cum)*4096;
    __syncthreads();                    // prior group done with mRow/vvRow/dS
    if (tid < 32){
      int row = (z << 10) + bm + tid;
      mRow[tid] = chainU(o2f(rowmax[row]), L);
      float tr = fqa(fqa(o2f(rowmin[row]), L.f1)*L.sc, L.f2);
      float w = fqa(fqa(tr, L.fam) + L.c20, L.fvv);
      float lv = fminf(fmaxf(rintf(w*L.f3.inv) + L.f3.zp, 0.0f), 65535.0f);
      vvLev[tid] = lv;
      vvRow[tid] = (lv - L.f3.zp)*L.f3.scale;   // == fqa(w, f3)
    }
    const _Float16* Ab = q_h + (size_t)z*131072 + (size_t)bm*128;
    h8_t Aq[2][4];
    qk_load_a(Ab, quad, l15, Aq);
    __syncthreads();                    // mRow/vvRow/vvLev visible
    float rs[2][4];
    #pragma unroll
    for (int mt = 0; mt < 2; mt++)
      #pragma unroll
      for (int i = 0; i < 4; i++) rs[mt][i] = 0.0f;
    for (int bn = 0; bn < (nch << 7); bn += 128){
      f4_t acc[2][2];
      { f4_t zz = {0.f,0.f,0.f,0.f}; for (int i=0;i<2;i++) for (int jj=0;jj<2;jj++) acc[i][jj]=zz; }
      qk_chunk32(Aq, Kb, bn, wn, quad, l15, acc);
      unsigned short* Qc = Qu + (size_t)(bn >> 7)*4096;
      if (bn < cstar){
        // fully unmasked chunk: no causal select
        #pragma unroll
        for (int mt = 0; mt < 2; mt++){
          #pragma unroll
          for (int nt = 0; nt < 2; nt++){
            int cl = (wn<<5) + (nt<<4) + l15;
            #pragma unroll
            for (int i = 0; i < 4; i++){
              int rl = (mt<<4) + (quad<<2) + i;
              float a2 = fqa(fqa(acc[mt][nt][i], L.f1)*L.sc, L.f2);
              float lvl = fminf(fmaxf(rintf(a2*L.f3.inv) + L.f3.zp, 0.0f), 65535.0f);
              Qc[rl*128 + cl] = (unsigned short)lvl;
              float a3 = (lvl - L.f3.zp)*L.f3.scale;   // == fqa(a2, f3)
              rs[mt][i] += __expf(a3 - mRow[rl]);
            }
          }
        }
      } else {
        // diagonal (mixed) chunk: per-element causal select on the LEVEL
        #pragma unroll
        for (int mt = 0; mt < 2; mt++){
          #pragma unroll
          for (int nt = 0; nt < 2; nt++){
            int cl = (wn<<5) + (nt<<4) + l15;
            int t = bn + cl;
            #pragma unroll
            for (int i = 0; i < 4; i++){
              int rl = (mt<<4) + (quad<<2) + i;
              float a2 = fqa(fqa(acc[mt][nt][i], L.f1)*L.sc, L.f2);
              float lvl = fminf(fmaxf(rintf(a2*L.f3.inv) + L.f3.zp, 0.0f), 65535.0f);
              float qs = (t <= bm + rl) ? lvl : vvLev[rl];
              Qc[rl*128 + cl] = (unsigned short)qs;
              float a3 = (qs - L.f3.zp)*L.f3.scale;
              rs[mt][i] += __expf(a3 - mRow[rl]);
            }
          }
        }
      }
    }
    #pragma unroll
    for (int d = 1; d < 16; d <<= 1)
      #pragma unroll
      for (int mt = 0; mt < 2; mt++)
        #pragma unroll
        for (int i = 0; i < 4; i++) rs[mt][i] += __shfl_xor(rs[mt][i], d, 64);
    if (l15 == 0){
      #pragma unroll
      for (int mt = 0; mt < 2; mt++)
        #pragma unroll
        for (int i = 0; i < 4; i++) dS[wn][(mt<<4) + (quad<<2) + i] = rs[mt][i];
    }
    __syncthreads();
    if (tid < 32){
      float nMask = (float)(1024 - (nch << 7));
      denomS[(z << 10) + bm + tid] = (dS[0][tid] + dS[1][tid]) + (dS[2][tid] + dS[3][tid])
                                     + nMask*__expf(vvRow[tid] - mRow[tid]);
    }
  }
}

// pass 3: PV dequant-GEMM. No QK recompute, no LDS marshalling, no barriers:
// read q3 levels in A-fragment layout, n = clamp(rint(exp((q-zp)s - m)*rp)),
// af = f16(n*scale*1024), MFMA with vT, direct ctx store. Paired groups.
__global__ __launch_bounds__(256) void k_qk_pv(const unsigned short* __restrict__ q3buf,
                                               const _Float16* __restrict__ vT,
                                               float* __restrict__ ctx,
                                               const unsigned* __restrict__ rowmax,
                                               const float* __restrict__ denomS, unsigned* stats){
  QK_IDS
  int j = blockIdx.x, z = blockIdx.y;
  int b = z >> 4, h = z & 15;
  LogitQ L = derive_logit(stats);
  FQP p4 = fqp(0.0f, 1.0f/dec_slot(stats, 32));
  float c1024 = p4.scale*1024.0f;
  float zp3 = L.f3.zp, s3 = L.f3.scale;
  const _Float16* Vb = vT + (size_t)(b*8 + (h>>1))*131072;
  float* Cb = ctx + ((size_t)b << 10)*2048 + (size_t)h*128;
  float cmn = FLT_MAX, cmx = -FLT_MAX;
  for (int g = 0; g < 2; g++){
    int r = g ? (31 - j) : j;
    int bm = r << 5;
    int nch = (r >> 2) + 1;
    int aa = r >> 2, bb2 = r & 3;
    int cum = (aa + 1)*(2*aa + bb2);
    const unsigned short* Qu = q3buf + ((size_t)z*144 + cum)*4096;
    float mR[2], rpR[2];
    #pragma unroll
    for (int mt = 0; mt < 2; mt++){
      int row = (z << 10) + bm + (mt<<4) + l15;
      mR[mt] = chainU(o2f(rowmax[row]), L);
      rpR[mt] = p4.inv/denomS[row];
    }
    f4_t pacc[2][2];
    { f4_t zz = {0.f,0.f,0.f,0.f}; for (int i=0;i<2;i++) for (int jj=0;jj<2;jj++) pacc[i][jj]=zz; }
    for (int c = 0; c < nch; c++){
      const unsigned short* Qc = Qu + (size_t)c*4096;
      #pragma unroll
      for (int k0 = 0; k0 < 4; k0++){
        h8_t af[2], bf[2];
        #pragma unroll
        for (int mt = 0; mt < 2; mt++){
          const unsigned short* pr = Qc + ((mt<<4) + l15)*128 + (k0<<5) + (quad<<3);
          u16x4 u = *(const u16x4*)pr, w = *(const u16x4*)(pr + 4);
          h8_t o;
          #pragma unroll
          for (int jj = 0; jj < 4; jj++){
            float a3u = ((float)u[jj] - zp3)*s3;
            float nu = fminf(fmaxf(rintf(__expf(a3u - mR[mt])*rpR[mt]), 0.0f), 65535.0f);
            o[jj] = (_Float16)(nu*c1024);
            float a3w = ((float)w[jj] - zp3)*s3;
            float nw = fminf(fmaxf(rintf(__expf(a3w - mR[mt])*rpR[mt]), 0.0f), 65535.0f);
            o[jj+4] = (_Float16)(nw*c1024);
          }
          af[mt] = o;
        }
        #pragma unroll
        for (int nt = 0; nt < 2; nt++)
          bf[nt] = *(const h8_t*)(Vb + (size_t)((wn<<5) + (nt<<4) + l15)*1024 + (c<<7) + (k0<<5) + (quad<<3));
        #pragma unroll
        for (int mt = 0; mt < 2; mt++)
          #pragma unroll
          for (int nt = 0; nt < 2; nt++)
            pacc[mt][nt] = __builtin_amdgcn_mfma_f32_16x16x32_f16(af[mt], bf[nt], pacc[mt][nt], 0, 0, 0);
      }
    }
    #pragma unroll
    for (int mt = 0; mt < 2; mt++)
      #pragma unroll
      for (int nt = 0; nt < 2; nt++){
        int Cc = (wn<<5) + (nt<<4) + l15;
        #pragma unroll
        for (int i = 0; i < 4; i++){
          int R = bm + (mt<<4) + (quad<<2) + i;
          float v = pacc[mt][nt][i]*(1.0f/1024.0f);
          Cb[(size_t)R*2048 + Cc] = v;
          cmn = fminf(cmn, v); cmx = fmaxf(cmx, v);
        }
      }
  }
  __shared__ float red[256];
  float bmn = bred_min(cmn, red), bmx = bred_max(cmx, red);
  if (tid == 0){ atomicMin(&stats[36*16], f2o(bmn)); atomicMax(&stats[37*16], f2o(bmx)); }
}

// attn f32 expansion: uniform BW-bound. grid (chunk=8, group=32, z=32).
// Causal units: n = clamp(rint(exp((q-zp)s - m)*rp)); attn = n*p4.scale
// (bit-identical to the old in-loop stream). Masked units: zero-fill.
__global__ __launch_bounds__(256) void k_attn_expand(const unsigned short* __restrict__ q3buf,
                                                     float* __restrict__ attn,
                                                     const unsigned* __restrict__ rowmax,
                                                     const float* __restrict__ denomS,
                                                     const unsigned* stats){
  int c = blockIdx.x, r = blockIdx.y, z = blockIdx.z;
  int nch = (r >> 2) + 1;
  int tid = threadIdx.x;
  int row = tid >> 3, col0 = (tid & 7) << 4;
  float* Cp = attn + ((size_t)z << 20) + (size_t)((r<<5) + row)*1024 + (c<<7) + col0;
  if (c >= nch){
    f4_t zz = {0.f,0.f,0.f,0.f};
    #pragma unroll
    for (int q = 0; q < 4; q++) __builtin_nontemporal_store(zz, (f4_t*)(Cp + (q<<2)));
    return;
  }
  LogitQ L = derive_logit(stats);
  FQP p4 = fqp(0.0f, 1.0f/dec_slot(stats, 32));
  float zp3 = L.f3.zp, s3 = L.f3.scale;
  int aa = r >> 2, bb2 = r & 3;
  int cum = (aa + 1)*(2*aa + bb2);
  int grow = (z << 10) + (r<<5) + row;
  float m = chainU(o2f(rowmax[grow]), L);
  float rp = p4.inv/denomS[grow];
  const unsigned short* pr = q3buf + ((size_t)z*144 + cum + c)*4096 + row*128 + col0;
  #pragma unroll
  for (int q = 0; q < 4; q++){
    u16x4 u = *(const u16x4*)(pr + (q<<2));
    f4_t v4;
    #pragma unroll
    for (int jj = 0; jj < 4; jj++){
      float a3 = ((float)u[jj] - zp3)*s3;
      float n = fminf(fmaxf(rintf(__expf(a3 - m)*rp), 0.0f), 65535.0f);
      v4[jj] = n*p4.scale;
    }
    __builtin_nontemporal_store(v4, (f4_t*)(Cp + (q<<2)));
  }
}

// ===========================================================================

// fq16(A) then per-128 rmsnorm; writes (B,NH,S,D) fp32; reduces full+half ranges
__global__ __launch_bounds__(256) void k_rms(const float* __restrict__ lin, float* __restrict__ buf,
                                             const float* __restrict__ gw, unsigned* stats,
                                             int slot_lin, int slot_out, int NHh, int rows){
  FQP pA = fqp(dec_slot(stats, slot_lin), dec_slot(stats, slot_lin+1));
  int lane = threadIdx.x & 63;
  int wv = (blockIdx.x*256 + threadIdx.x) >> 6;
  int nwv = (gridDim.x*256) >> 6;
  float w0 = gw[lane], w1 = gw[lane + 64];
  float fmn = FLT_MAX, fmx = -FLT_MAX, hmn = FLT_MAX, hmx = -FLT_MAX;
  for (int r = wv; r < rows; r += nwv){
    int h = r % NHh; int rem = r / NHh; int s2 = rem & 1023; int b = rem >> 10;
    const float* src = lin + (size_t)r*128;
    float x0 = fqa(src[lane], pA), x1 = fqa(src[lane + 64], pA);
    float ss = x0*x0 + x1*x1;
    #pragma unroll
    for (int m = 1; m < 64; m <<= 1) ss += __shfl_xor(ss, m, 64);
    float rr = 1.0f/sqrtf(ss*(1.0f/128.0f) + 1e-6f);
    float y0 = x0*rr*w0, y1 = x1*rr*w1;
    float* dst = buf + ((size_t)((b*NHh + h) << 10) + s2)*128;
    dst[lane] = y0; dst[lane + 64] = y1;
    fmn = fminf(fmn, fminf(y0, y1)); fmx = fmaxf(fmx, fmaxf(y0, y1));
    hmn = fminf(hmn, y1); hmx = fmaxf(hmx, y1);
  }
  __shared__ float red[256];
  float a = bred_min(fmn, red), bb = bred_max(fmx, red);
  float c = bred_min(hmn, red), d = bred_max(hmx, red);
  if (threadIdx.x == 0){
    atomicMin(&stats[slot_out*16], f2o(a));     atomicMax(&stats[(slot_out+1)*16], f2o(bb));
    atomicMin(&stats[(slot_out+2)*16], f2o(c)); atomicMax(&stats[(slot_out+3)*16], f2o(d));
  }
}

struct RopeQ { FQP B, C, E, F; };
__device__ RopeQ derive_rope(const unsigned* st, int base){
  float ymn = dec_slot(st, base),   ymx = dec_slot(st, base+1);
  float y2mn = dec_slot(st, base+2), y2mx = dec_slot(st, base+3);
  RopeQ r;
  r.B = fqp(ymn, ymx);
  float zmn = fqa(ymn, r.B), zmx = fqa(ymx, r.B);
  r.C = fqp(zmn, zmx);
  float zlo = fqa(zmn, r.C), zhi = fqa(zmx, r.C);
  float z2lo = fqa(fqa(y2mn, r.B), r.C), z2hi = fqa(fqa(y2mx, r.B), r.C);
  r.E = fqp(-z2hi, -z2lo);
  float nlo = fqa(-z2hi, r.E), nhi = fqa(-z2lo, r.E);
  r.F = fqp_raw(fminf(fminf(zlo, nlo), 0.0f), fmaxf(fmaxf(zhi, nhi), 0.0f));
  return r;
}

__global__ __launch_bounds__(256) void k_rope(float* __restrict__ buf, const float* __restrict__ cosp,
                                              const float* __restrict__ sinp, unsigned* stats,
                                              int slot_norm, int slot_prod, int slot_sum,
                                              int NHh, int rows, int do_write){
  RopeQ R = derive_rope(stats, slot_norm);
  FQP pD, pG;
  if (do_write){
    pD = fqp(dec_slot(stats, slot_prod),   dec_slot(stats, slot_prod+1));
    pG = fqp(dec_slot(stats, slot_prod+2), dec_slot(stats, slot_prod+3));
  }
  int lane = threadIdx.x & 63;
  int wv = (blockIdx.x*256 + threadIdx.x) >> 6, nwv = (gridDim.x*256) >> 6;
  float m0 = FLT_MAX, M0 = -FLT_MAX, m1 = FLT_MAX, M1 = -FLT_MAX;
  for (int r = wv; r < rows; r += nwv){
    int s2 = r & 1023; int bh = r >> 10; int b = bh/NHh;
    float* base = buf + (size_t)r*128;
    float y0 = base[lane], y1 = base[lane + 64];
    float z0 = fqa(fqa(y0, R.B), R.C), z1 = fqa(fqa(y1, R.B), R.C);
    const float* cr = cosp + (size_t)((b << 10) + s2)*128;
    const float* sr = sinp + (size_t)((b << 10) + s2)*128;
    float c0 = cr[lane], c1 = cr[lane + 64], sn0 = sr[lane], sn1 = sr[lane + 64];
    float pc0 = z0*c0, pc1 = z1*c1;
    float rh0 = fqa(fqa(-z1, R.E), R.F);
    float rh1 = fqa(z0, R.F);
    float ps0 = rh0*sn0, ps1 = rh1*sn1;
    if (!do_write){
      m0 = fminf(m0, fminf(pc0, pc1)); M0 = fmaxf(M0, fmaxf(pc0, pc1));
      m1 = fminf(m1, fminf(ps0, ps1)); M1 = fmaxf(M1, fmaxf(ps0, ps1));
    } else {
      float sv0 = fqa(pc0, pD) + fqa(ps0, pG);
      float sv1 = fqa(pc1, pD) + fqa(ps1, pG);
      base[lane] = sv0; base[lane + 64] = sv1;
      m0 = fminf(m0, fminf(sv0, sv1)); M0 = fmaxf(M0, fmaxf(sv0, sv1));
    }
  }
  __shared__ float red[256];
  if (!do_write){
    float a = bred_min(m0, red), bb = bred_max(M0, red);
    float c = bred_min(m1, red), d = bred_max(M1, red);
    if (threadIdx.x == 0){
      atomicMin(&stats[slot_prod*16], f2o(a));     atomicMax(&stats[(slot_prod+1)*16], f2o(bb));
      atomicMin(&stats[(slot_prod+2)*16], f2o(c)); atomicMax(&stats[(slot_prod+3)*16], f2o(d));
    }
  } else {
    float a = bred_min(m0, red), bb = bred_max(M0, red);
    if (threadIdx.x == 0){ atomicMin(&stats[slot_sum*16], f2o(a)); atomicMax(&stats[(slot_sum+1)*16], f2o(bb)); }
  }
}

// V transpose + fq8(fq16) -> f16: vT[b][kv][d][t]
__global__ __launch_bounds__(256) void k_vT(const float* __restrict__ vlin, _Float16* __restrict__ vT,
                                            const unsigned* stats){
  FQP pv = fqp(dec_slot(stats, 6), dec_slot(stats, 7));
  float vlo = fqa(dec_slot(stats, 6), pv), vhi = fqa(dec_slot(stats, 7), pv);
  float v8s = fmaxf(fmaxf(fabsf(vlo), fabsf(vhi))/127.0f, 1e-12f), v8si = 1.0f/v8s;
  __shared__ float tile[64][65];
  int bkv = blockIdx.z, t0 = blockIdx.x << 6, d0 = blockIdx.y << 6;
  int b = bkv >> 3, kv = bkv & 7;
  const float* src = vlin + ((size_t)(b << 10))*1024 + (size_t)kv*128;
  int tx = threadIdx.x & 63, tq = threadIdx.x >> 6;
  #pragma unroll
  for (int i = 0; i < 16; i++){
    int tt = (i << 2) + tq;
    float x = src[(size_t)(t0 + tt)*1024 + d0 + tx];
    tile[tx][tt] = fq8(fqa(x, pv), v8s, v8si);
  }
  __syncthreads();
  _Float16* dst = vT + (size_t)bkv*131072;
  #pragma unroll
  for (int i = 0; i < 16; i++){
    int dd = (i << 2) + tq;
    dst[(size_t)(d0 + dd)*1024 + t0 + tx] = (_Float16)tile[dd][tx];
  }
}

extern "C" void kernel_launch(void* const* d_in, const int* in_sizes, int n_in,
                              void* d_out, int out_size, void* d_ws, size_t ws_size,
                              hipStream_t stream){
  (void)in_sizes; (void)n_in; (void)out_size; (void)ws_size;
  const float* hs   = (const float*)d_in[0];
  const float* cosp = (const float*)d_in[1];
  const float* sinp = (const float*)d_in[2];
  const float* Wq   = (const float*)d_in[4];
  const float* Wk   = (const float*)d_in[5];
  const float* Wv   = (const float*)d_in[6];
  const float* Wo   = (const float*)d_in[7];
  const float* qnw  = (const float*)d_in[8];
  const float* knw  = (const float*)d_in[9];

  float* outp = (float*)d_out;
  float* attn = outp + 4194304;      // final quantized softmax

  const size_t MEG = 1u << 20;       // floats
  float* wsf = (float*)d_ws;
  _Float16* woq_h = (_Float16*)(wsf + 0);
  _Float16* wqq_h = (_Float16*)(wsf + 2*MEG);
  _Float16* wkq_h = (_Float16*)(wsf + 4*MEG);
  _Float16* wvq_h = (_Float16*)(wsf + 5*MEG);
  _Float16* hsq_h = (_Float16*)(wsf + 6*MEG);
  float* qlin = wsf + 8*MEG;  float* ctx = qlin;   // ctx reuses qlin
  float* klin = wsf + 12*MEG;
  float* vlin = wsf + 14*MEG;
  float* qbuf = wsf + 16*MEG;
  float* kbuf = wsf + 20*MEG;
  _Float16* q_h   = (_Float16*)(wsf + 22*MEG);
  _Float16* k_h   = (_Float16*)(wsf + 24*MEG);
  _Float16* vT_h  = (_Float16*)(wsf + 25*MEG);
  _Float16* ctx_h = (_Float16*)(wsf + 26*MEG);
  unsigned* rowmin = (unsigned*)(wsf + 28*MEG);
  unsigned* rowmax = (unsigned*)(wsf + 28*MEG + 32768);
  float* denomS = wsf + 28*MEG + 65536;
  unsigned* stats = (unsigned*)(wsf + 28*MEG + 98304);
  // q3 levels: 32 z * 144 units * 4096 u16 = 36 MB. Overlays klin/vlin/qbuf/
  // kbuf (wsf+12M..21M floats) -- all dead before k_qk_denom writes it.
  unsigned short* q3buf = (unsigned short*)(wsf + 12*MEG);

  k_init<<<4, 256, 0, stream>>>(stats);

  k_quantw<<<4096, 256, 0, stream>>>(Wq, wqq_h);
  k_quantw<<<2048, 256, 0, stream>>>(Wk, wkq_h);
  k_quantw<<<2048, 256, 0, stream>>>(Wv, wvq_h);
  k_quantw<<<4096, 256, 0, stream>>>(Wo, woq_h);

  k_minmax<<<1024, 256, 0, stream>>>(hs, 4194304, stats, 0);
  k_fq_ew16<<<4096, 256, 0, stream>>>(hs, hsq_h, stats, 0);

  // projections (f16 MFMA, async LDS staging), raw-output range stats fused
  k_hgemm_f<<<dim3(16, 16), 256, 0, stream>>>(hsq_h, wqq_h, qlin, 2048, 2048, stats, 2);
  k_hgemm_kv<<<dim3(8, 16, 2), 256, 0, stream>>>(hsq_h, wkq_h, wvq_h, klin, vlin, 2048, stats);

  // fq16 + rmsnorm (fp32) + range reductions
  k_rms<<<1024, 256, 0, stream>>>(qlin, qbuf, qnw, stats, 2, 8, 16, 32768);
  k_rms<<<512, 256, 0, stream>>>(klin, kbuf, knw, stats, 4, 12, 8, 16384);

  // RoPE: range pass then write pass
  k_rope<<<1024, 256, 0, stream>>>(qbuf, cosp, sinp, stats, 8, 16, 24, 16, 32768, 0);
  k_rope<<<512, 256, 0, stream>>>(kbuf, cosp, sinp, stats, 12, 20, 26, 8, 16384, 0);
  k_rope<<<1024, 256, 0, stream>>>(qbuf, cosp, sinp, stats, 8, 16, 24, 16, 32768, 1);
  k_rope<<<512, 256, 0, stream>>>(kbuf, cosp, sinp, stats, 12, 20, 26, 8, 16384, 1);

  // operand conversion for QK and V transpose
  k_fq_ew16<<<4096, 256, 0, stream>>>(qbuf, q_h, stats, 24);
  k_fq8_ew16<<<2048, 256, 0, stream>>>(kbuf, k_h, stats, 26);
  k_vT<<<dim3(16, 2, 16), 256, 0, stream>>>(vlin, vT_h, stats);

  // attention: stats (full sweep) -> denom (+q3 store) -> pv (dequant-GEMM)
  // -> expand (attn f32 write). denom/pv paired (j, 31-j) = 9 units/block.
  k_qk_stats<<<dim3(32, 32), 256, 0, stream>>>(q_h, k_h, stats, rowmin, rowmax);
  k_rowstat_m2<<<8, 256, 0, stream>>>(rowmin, stats, 32768);
  k_qk_denom<<<dim3(16, 32), 256, 0, stream>>>(q_h, k_h, rowmin, rowmax, denomS, q3buf, stats);
  k_denom_min<<<8, 256, 0, stream>>>(denomS, stats, 32768);
  k_qk_pv<<<dim3(16, 32), 256, 0, stream>>>(q3buf, vT_h, ctx, rowmax, denomS, stats);
  k_attn_expand<<<dim3(8, 32, 32), 256, 0, stream>>>(q3buf, attn, rowmax, denomS, stats);

  // ctx (stats fused in PV) -> f16 -> O-proj
  k_fq_ew16<<<4096, 256, 0, stream>>>(ctx, ctx_h, stats, 36);
  k_hgemm_f<<<dim3(16, 16), 256, 0, stream>>>(ctx_h, woq_h, outp, 2048, 2048, stats, -1);
}

// Round 5
// 685.946 us; speedup vs baseline: 1.2235x; 1.2235x over previous
//
#include <hip/hip_runtime.h>
#include <cfloat>
#include <cmath>

// ---------------------------------------------------------------------------
// Qwen3Attention fake-quant forward. B=2 S=1024 HID=2048 NH=16 NKV=8 D=128.
// Round 11: fix k_attn_expand write coalescing. Round-10's mapping wrote 16B
// every 64B per wave instruction + nontemporal -> 2.5x HBM write
// amplification (330 MB for 134 MB logical). New mapping: idx=it*256+tid,
// row=idx>>5, col=(idx&31)<<2 -> 32 lanes x 16B = 512B contiguous per
// instruction (the round-1 pv pattern that measured exactly 147 MB).
// ---------------------------------------------------------------------------

#define FQ_EPS      1.5259021896696422e-09f   // 0.0001/65535
#define SCALING_F   0.08838834764831845f      // 128**-0.5
#define S_LEN       1024

typedef _Float16 h8_t __attribute__((ext_vector_type(8)));
typedef _Float16 h4_t __attribute__((ext_vector_type(4)));
typedef float    f4_t __attribute__((ext_vector_type(4)));
typedef unsigned short u16x4 __attribute__((ext_vector_type(4)));

// ---- float <-> order-preserving unsigned encoding (for atomic min/max) ----
__device__ __forceinline__ unsigned f2o(float f){
  unsigned u = __float_as_uint(f);
  return (u & 0x80000000u) ? ~u : (u | 0x80000000u);
}
__device__ __forceinline__ float o2f(unsigned u){
  return __uint_as_float((u & 0x80000000u) ? (u ^ 0x80000000u) : ~u);
}
__device__ __forceinline__ float dec_slot(const unsigned* st, int s){ return o2f(st[s*16]); }

// ---- fq16 helpers ----
struct FQP { float scale, zp, inv; };
__device__ __forceinline__ FQP fqp_raw(float mn, float mx){
  FQP p; p.scale = fmaxf((mx - mn)/65535.0f, FQ_EPS); p.zp = rintf(-mn/p.scale);
  p.inv = 1.0f/p.scale; return p;
}
__device__ __forceinline__ FQP fqp(float mn0, float mx0){
  return fqp_raw(fminf(mn0, 0.0f), fmaxf(mx0, 0.0f));
}
__device__ __forceinline__ float fqa(float x, FQP p){
  float q = rintf(x*p.inv) + p.zp;
  q = fminf(fmaxf(q, 0.0f), 65535.0f);
  return (q - p.zp)*p.scale;
}
__device__ __forceinline__ float fq8(float x, float s, float si){
  return fminf(fmaxf(rintf(x*si), -128.0f), 127.0f)*s;
}

// ---- block reductions (blockDim == 256) ----
__device__ __forceinline__ float bred_min(float v, float* red){
  int tid = threadIdx.x; red[tid] = v; __syncthreads();
  for (int s = 128; s > 0; s >>= 1){ if (tid < s) red[tid] = fminf(red[tid], red[tid+s]); __syncthreads(); }
  float r = red[0]; __syncthreads(); return r;
}
__device__ __forceinline__ float bred_max(float v, float* red){
  int tid = threadIdx.x; red[tid] = v; __syncthreads();
  for (int s = 128; s > 0; s >>= 1){ if (tid < s) red[tid] = fmaxf(red[tid], red[tid+s]); __syncthreads(); }
  float r = red[0]; __syncthreads(); return r;
}

// ---- stats slot map (even=min, odd=max) ----
// 0/1 hs | 2/3 qlin | 4/5 klin | 6/7 vlin | 8/9 qn | 10/11 qn2 | 12/13 kn | 14/15 kn2
// 16/17 q*c | 18/19 qrh*s | 20/21 k*c | 22/23 krh*s | 24/25 qsum | 26/27 ksum
// 28/29 logits | 31 unmaskedMax | 32 denomMin | 35 maxOfRowMins | 36/37 ctx

__global__ void k_init(unsigned* stats){
  int i = blockIdx.x*blockDim.x + threadIdx.x;
  if (i < 1024) stats[i] = (((i & 15) == 0) && (((i >> 4) & 1) == 0)) ? 0xFFFFFFFFu : 0u;
}

// lpbq weight quantization -> f16. 4 elems/thread; 8-lane shfl = 32-elem block.
__global__ __launch_bounds__(256) void k_quantw(const float* __restrict__ W, _Float16* __restrict__ Wh){
  int i = blockIdx.x*256 + threadIdx.x;
  float4 v = ((const float4*)W)[i];
  float am = fmaxf(fmaxf(fabsf(v.x), fabsf(v.y)), fmaxf(fabsf(v.z), fabsf(v.w)));
  #pragma unroll
  for (int m = 1; m < 8; m <<= 1) am = fmaxf(am, __shfl_xor(am, m, 64));
  float s = fmaxf(am/7.0f, 1e-12f), si = 1.0f/s;
  h4_t o;
  o[0] = (_Float16)(fminf(fmaxf(rintf(v.x*si), -8.0f), 7.0f)*s);
  o[1] = (_Float16)(fminf(fmaxf(rintf(v.y*si), -8.0f), 7.0f)*s);
  o[2] = (_Float16)(fminf(fmaxf(rintf(v.z*si), -8.0f), 7.0f)*s);
  o[3] = (_Float16)(fminf(fmaxf(rintf(v.w*si), -8.0f), 7.0f)*s);
  *(h4_t*)(Wh + ((size_t)i << 2)) = o;
}

__global__ __launch_bounds__(256) void k_minmax(const float* __restrict__ x, int n, unsigned* stats, int slot){
  float mn = FLT_MAX, mx = -FLT_MAX;
  for (int i = blockIdx.x*256 + threadIdx.x; i < n; i += gridDim.x*256){
    float v = x[i]; mn = fminf(mn, v); mx = fmaxf(mx, v);
  }
  __shared__ float red[256];
  float bmn = bred_min(mn, red), bmx = bred_max(mx, red);
  if (threadIdx.x == 0){ atomicMin(&stats[slot*16], f2o(bmn)); atomicMax(&stats[(slot+1)*16], f2o(bmx)); }
}

// fq16 elementwise -> f16, 4 elems/thread
__global__ __launch_bounds__(256) void k_fq_ew16(const float* __restrict__ x, _Float16* __restrict__ y,
                                                 const unsigned* stats, int slot){
  FQP p = fqp(dec_slot(stats, slot), dec_slot(stats, slot+1));
  int i = blockIdx.x*256 + threadIdx.x;
  float4 v = ((const float4*)x)[i];
  h4_t o;
  o[0] = (_Float16)fqa(v.x, p); o[1] = (_Float16)fqa(v.y, p);
  o[2] = (_Float16)fqa(v.z, p); o[3] = (_Float16)fqa(v.w, p);
  *(h4_t*)(y + ((size_t)i << 2)) = o;
}

// fq8(fq16(x)) elementwise -> f16 (for K)
__global__ __launch_bounds__(256) void k_fq8_ew16(const float* __restrict__ x, _Float16* __restrict__ y,
                                                  const unsigned* stats, int slot){
  FQP p = fqp(dec_slot(stats, slot), dec_slot(stats, slot+1));
  float lo = fqa(dec_slot(stats, slot), p), hi = fqa(dec_slot(stats, slot+1), p);
  float s8 = fmaxf(fmaxf(fabsf(lo), fabsf(hi))/127.0f, 1e-12f), s8i = 1.0f/s8;
  int i = blockIdx.x*256 + threadIdx.x;
  float4 v = ((const float4*)x)[i];
  h4_t o;
  o[0] = (_Float16)fq8(fqa(v.x, p), s8, s8i); o[1] = (_Float16)fq8(fqa(v.y, p), s8, s8i);
  o[2] = (_Float16)fq8(fqa(v.z, p), s8, s8i); o[3] = (_Float16)fq8(fqa(v.w, p), s8, s8i);
  *(h4_t*)(y + ((size_t)i << 2)) = o;
}

// ================= f16 MFMA GEMM core for projections (NT) =================
// async staging: LDS dest is wave-uniform base + lane*16B (constraint-safe).
#define GLDS16(g, l) __builtin_amdgcn_global_load_lds( \
    (__attribute__((address_space(1))) unsigned int*)(g), \
    (__attribute__((address_space(3))) unsigned int*)(l), 16, 0, 0)

__device__ __forceinline__ void stage_tile(const _Float16* __restrict__ src, int ld, int k0,
                                           _Float16* __restrict__ dst){
  #pragma unroll
  for (int it = 0; it < 2; it++){
    int c = threadIdx.x + (it << 8);
    int row = c >> 2, off = (c & 3) << 3;
    GLDS16(src + (size_t)row*ld + k0 + off, dst + (c << 3));
  }
}

__device__ __forceinline__ void hgemm_main(const _Float16* __restrict__ A, int lda,
                                           const _Float16* __restrict__ B, int ldb, int K,
                                           f4_t acc[4][4], _Float16* As, _Float16* Bs){
  int lane = threadIdx.x & 63, wave = threadIdx.x >> 6;
  int wm = wave & 1, wn = wave >> 1, quad = lane >> 4, l15 = lane & 15;
  for (int k0 = 0; k0 < K; k0 += 32){
    __syncthreads();
    stage_tile(A, lda, k0, As);
    stage_tile(B, ldb, k0, Bs);
    __syncthreads();
    h8_t af[4], bf[4];
    #pragma unroll
    for (int mt = 0; mt < 4; mt++)
      af[mt] = *(const h8_t*)(As + ((((wm<<6) + (mt<<4) + l15)) << 5) + (quad << 3));
    #pragma unroll
    for (int nt = 0; nt < 4; nt++)
      bf[nt] = *(const h8_t*)(Bs + ((((wn<<6) + (nt<<4) + l15)) << 5) + (quad << 3));
    #pragma unroll
    for (int mt = 0; mt < 4; mt++)
      #pragma unroll
      for (int nt = 0; nt < 4; nt++)
        acc[mt][nt] = __builtin_amdgcn_mfma_f32_16x16x32_f16(af[mt], bf[nt], acc[mt][nt], 0, 0, 0);
  }
}

#define HG_PROLOG  \
  __shared__ __align__(16) _Float16 As[4096], Bs[4096]; \
  __shared__ float red[256]; \
  f4_t acc[4][4]; \
  { f4_t zz = {0.f,0.f,0.f,0.f}; \
    for (int i=0;i<4;i++) for (int j=0;j<4;j++) acc[i][j] = zz; } \
  int lane = threadIdx.x & 63, wave = threadIdx.x >> 6; \
  int wm = wave & 1, wn = wave >> 1, quad = lane >> 4, l15 = lane & 15; (void)red; (void)lane;

// C/D lane map (m89-verified): D[row=(quad*4+reg)][col=l15].

__global__ __launch_bounds__(256) void k_hgemm_f(const _Float16* __restrict__ A, const _Float16* __restrict__ B,
                                                 float* __restrict__ C, int N, int K,
                                                 unsigned* stats, int slotC){
  HG_PROLOG
  int bm = blockIdx.y << 7, bn = blockIdx.x << 7;
  hgemm_main(A + (size_t)bm*K, K, B + (size_t)bn*K, K, K, acc, As, Bs);
  float mn = FLT_MAX, mx = -FLT_MAX;
  #pragma unroll
  for (int mt = 0; mt < 4; mt++)
    #pragma unroll
    for (int nt = 0; nt < 4; nt++){
      int Cc = bn + (wn<<6) + (nt<<4) + l15;
      #pragma unroll
      for (int i = 0; i < 4; i++){
        int R = bm + (wm<<6) + (mt<<4) + (quad<<2) + i;
        float v = acc[mt][nt][i];
        C[(size_t)R*N + Cc] = v;
        mn = fminf(mn, v); mx = fmaxf(mx, v);
      }
    }
  if (slotC >= 0){
    float bmn = bred_min(mn, red), bmx = bred_max(mx, red);
    if (threadIdx.x == 0){ atomicMin(&stats[slotC*16], f2o(bmn)); atomicMax(&stats[(slotC+1)*16], f2o(bmx)); }
  }
}

// fused K/V projections: z=0 -> (Bk, Ck, slot4), z=1 -> (Bv, Cv, slot6)
__global__ __launch_bounds__(256) void k_hgemm_kv(const _Float16* __restrict__ A,
                                                  const _Float16* __restrict__ Bk, const _Float16* __restrict__ Bv,
                                                  float* __restrict__ Ck, float* __restrict__ Cv,
                                                  int K, unsigned* stats){
  HG_PROLOG
  const _Float16* B = blockIdx.z ? Bv : Bk;
  float* C = blockIdx.z ? Cv : Ck;
  int slotC = blockIdx.z ? 6 : 4;
  int bm = blockIdx.y << 7, bn = blockIdx.x << 7;
  hgemm_main(A + (size_t)bm*K, K, B + (size_t)bn*K, K, K, acc, As, Bs);
  float mn = FLT_MAX, mx = -FLT_MAX;
  #pragma unroll
  for (int mt = 0; mt < 4; mt++)
    #pragma unroll
    for (int nt = 0; nt < 4; nt++){
      int Cc = bn + (wn<<6) + (nt<<4) + l15;
      #pragma unroll
      for (int i = 0; i < 4; i++){
        int R = bm + (wm<<6) + (mt<<4) + (quad<<2) + i;
        float v = acc[mt][nt][i];
        C[(size_t)R*1024 + Cc] = v;
        mn = fminf(mn, v); mx = fmaxf(mx, v);
      }
    }
  float bmn = bred_min(mn, red), bmx = bred_max(mx, red);
  if (threadIdx.x == 0){ atomicMin(&stats[slotC*16], f2o(bmn)); atomicMax(&stats[(slotC+1)*16], f2o(bmx)); }
}

// ====================== QK^T attention passes (32-row) =====================
// block = 256 thr (4 waves). A 32-row group r (0..31) covers q-rows
// [32r, 32r+32); it needs nch(r) = (r>>2)+1 K-chunks of 128. Wave wn owns
// cols [32*wn, 32*wn+32): acc[2][2]. Pairing (j, 31-j) -> constant 9
// chunk-units per block. q3 levels (post-f3 u16) are exact -> stored once by
// denom, consumed by pv (PV GEMM) and expand (attn f32 write) bit-exactly.
// causal unit index: cum(r) = (a+1)*(2a+b), a=r>>2, b=r&3; unit = cum + chunk.

#define QK_IDS \
  int lane = threadIdx.x & 63, wn = threadIdx.x >> 6; \
  int quad = lane >> 4, l15 = lane & 15; \
  int tid = threadIdx.x; (void)tid; (void)lane;

__device__ __forceinline__ void qk_load_a(const _Float16* __restrict__ Ab, int quad, int l15,
                                          h8_t Aq[2][4]){
  #pragma unroll
  for (int mt = 0; mt < 2; mt++)
    #pragma unroll
    for (int k0 = 0; k0 < 4; k0++)
      Aq[mt][k0] = *(const h8_t*)(Ab + (size_t)((mt<<4) + l15)*128 + (k0<<5) + (quad<<3));
}

__device__ __forceinline__ void qk_chunk32(const h8_t Aq[2][4], const _Float16* __restrict__ Kb,
                                           int bn, int wn, int quad, int l15, f4_t acc[2][2]){
  #pragma unroll
  for (int k0 = 0; k0 < 4; k0++){
    h8_t bf[2];
    #pragma unroll
    for (int nt = 0; nt < 2; nt++)
      bf[nt] = *(const h8_t*)(Kb + (size_t)(bn + (wn<<5) + (nt<<4) + l15)*128 + (k0<<5) + (quad<<3));
    #pragma unroll
    for (int mt = 0; mt < 2; mt++)
      #pragma unroll
      for (int nt = 0; nt < 2; nt++)
        acc[mt][nt] = __builtin_amdgcn_mfma_f32_16x16x32_f16(Aq[mt][k0], bf[nt], acc[mt][nt], 0, 0, 0);
  }
}

// pass 1: global logit stats + per-row min / unmasked max (full sweep; the
// fq16 range covers pre-mask logits). 32-row groups, grid (32, 32).
__global__ __launch_bounds__(256) void k_qk_stats(const _Float16* __restrict__ q_h, const _Float16* __restrict__ k_h,
                                                  unsigned* stats, unsigned* rowmin, unsigned* rowmax){
  QK_IDS
  int bm = blockIdx.x << 5, z = blockIdx.y;
  int b = z >> 4, h = z & 15;
  const _Float16* Ab = q_h + (size_t)z*131072 + (size_t)bm*128;
  const _Float16* Kb = k_h + (size_t)(b*8 + (h>>1))*131072;
  h8_t Aq[2][4];
  qk_load_a(Ab, quad, l15, Aq);
  float rmv[2][4], rxv[2][4];
  #pragma unroll
  for (int mt = 0; mt < 2; mt++)
    #pragma unroll
    for (int i = 0; i < 4; i++){ rmv[mt][i] = FLT_MAX; rxv[mt][i] = -FLT_MAX; }
  float mn = FLT_MAX, mx = -FLT_MAX, mxU = -FLT_MAX;
  for (int bn = 0; bn < 1024; bn += 128){
    f4_t acc[2][2];
    { f4_t zz = {0.f,0.f,0.f,0.f}; for (int i=0;i<2;i++) for (int j=0;j<2;j++) acc[i][j]=zz; }
    qk_chunk32(Aq, Kb, bn, wn, quad, l15, acc);
    #pragma unroll
    for (int mt = 0; mt < 2; mt++){
      int rb = bm + (mt<<4) + (quad<<2);
      #pragma unroll
      for (int nt = 0; nt < 2; nt++){
        int t = bn + (wn<<5) + (nt<<4) + l15;
        #pragma unroll
        for (int i = 0; i < 4; i++){
          float v = acc[mt][nt][i];
          mn = fminf(mn, v); mx = fmaxf(mx, v);
          rmv[mt][i] = fminf(rmv[mt][i], v);
          if (t <= rb + i){ mxU = fmaxf(mxU, v); rxv[mt][i] = fmaxf(rxv[mt][i], v); }
        }
      }
    }
  }
  #pragma unroll
  for (int d = 1; d < 16; d <<= 1)
    #pragma unroll
    for (int mt = 0; mt < 2; mt++)
      #pragma unroll
      for (int i = 0; i < 4; i++){
        rmv[mt][i] = fminf(rmv[mt][i], __shfl_xor(rmv[mt][i], d, 64));
        rxv[mt][i] = fmaxf(rxv[mt][i], __shfl_xor(rxv[mt][i], d, 64));
      }
  __shared__ float rminS[4][32], rmaxS[4][32];
  if (l15 == 0){
    #pragma unroll
    for (int mt = 0; mt < 2; mt++)
      #pragma unroll
      for (int i = 0; i < 4; i++){
        int rl = (mt<<4) + (quad<<2) + i;
        rminS[wn][rl] = rmv[mt][i];
        rmaxS[wn][rl] = rxv[mt][i];
      }
  }
  __syncthreads();
  if (tid < 32){
    float a = fminf(fminf(rminS[0][tid], rminS[1][tid]), fminf(rminS[2][tid], rminS[3][tid]));
    float c = fmaxf(fmaxf(rmaxS[0][tid], rmaxS[1][tid]), fmaxf(rmaxS[2][tid], rmaxS[3][tid]));
    rowmin[(z << 10) + bm + tid] = f2o(a);
    rowmax[(z << 10) + bm + tid] = f2o(c);
  }
  __shared__ float red[256];
  float bmn = bred_min(mn, red), bmx = bred_max(mx, red), bmU = bred_max(mxU, red);
  if (tid == 0){
    atomicMin(&stats[28*16], f2o(bmn));
    atomicMax(&stats[29*16], f2o(bmx));
    atomicMax(&stats[31*16], f2o(bmU));
  }
}

__global__ __launch_bounds__(256) void k_rowstat_m2(const unsigned* __restrict__ rowmin, unsigned* stats, int n){
  float lm = -FLT_MAX;
  for (int i = blockIdx.x*256 + threadIdx.x; i < n; i += gridDim.x*256) lm = fmaxf(lm, o2f(rowmin[i]));
  __shared__ float red[256];
  float m = bred_max(lm, red);
  if (threadIdx.x == 0) atomicMax(&stats[35*16], f2o(m));
}
__global__ __launch_bounds__(256) void k_denom_min(const float* __restrict__ denomS, unsigned* stats, int n){
  float lm = FLT_MAX;
  for (int i = blockIdx.x*256 + threadIdx.x; i < n; i += gridDim.x*256) lm = fminf(lm, denomS[i]);
  __shared__ float red[256];
  float m = -bred_max(-lm, red);
  if (threadIdx.x == 0) atomicMin(&stats[32*16], f2o(m));
}

struct LogitQ { FQP f1, f2, fam, fvv, f3; float sc, c20; };
__device__ LogitQ derive_logit(const unsigned* st){
  LogitQ L;
  FQP ps = fqp(SCALING_F, SCALING_F); L.sc = fqa(SCALING_F, ps);
  FQP p20 = fqp(-20.0f, -20.0f);      L.c20 = fqa(-20.0f, p20);
  float gmn = dec_slot(st, 28), gmx = dec_slot(st, 29);
  float gU = dec_slot(st, 31), M2 = dec_slot(st, 35);
  L.f1 = fqp(gmn, gmx);
  float l1lo = fqa(gmn, L.f1), l1hi = fqa(gmx, L.f1);
  L.f2 = fqp(l1lo*L.sc, l1hi*L.sc);
  float amlo = fqa(fqa(gmn, L.f1)*L.sc, L.f2);
  float amhi = fqa(fqa(M2, L.f1)*L.sc, L.f2);
  L.fam = fqp(amlo, amhi);
  float vslo = fqa(amlo, L.fam) + L.c20, vshi = fqa(amhi, L.fam) + L.c20;
  L.fvv = fqp(vslo, vshi);
  float mn3 = fqa(vslo, L.fvv);
  float mx3 = fqa(fqa(gU, L.f1)*L.sc, L.f2);
  L.f3 = fqp(mn3, mx3);
  return L;
}
__device__ __forceinline__ float chainU(float raw, const LogitQ& L){
  return fqa(fqa(fqa(raw, L.f1)*L.sc, L.f2), L.f3);
}

// pass 2: per-row denominators + q3-level store (u16, causal-packed).
// Paired 32-row groups (j, 31-j) = 9 units/block. Skipped masked chunks
// contribute count*exp(vv-m) per row analytically.
__global__ __launch_bounds__(256) void k_qk_denom(const _Float16* __restrict__ q_h, const _Float16* __restrict__ k_h,
                                                  const unsigned* __restrict__ rowmin,
                                                  const unsigned* __restrict__ rowmax,
                                                  float* __restrict__ denomS,
                                                  unsigned short* __restrict__ q3buf,
                                                  const unsigned* stats){
  QK_IDS
  int j = blockIdx.x, z = blockIdx.y;
  int b = z >> 4, h = z & 15;
  LogitQ L = derive_logit(stats);
  const _Float16* Kb = k_h + (size_t)(b*8 + (h>>1))*131072;
  __shared__ float mRow[32], vvRow[32], vvLev[32];
  __shared__ float dS[4][32];
  for (int g = 0; g < 2; g++){
    int r = g ? (31 - j) : j;
    int bm = r << 5;
    int nch = (r >> 2) + 1;
    int cstar = (r >> 2) << 7;          // diagonal-chunk base
    int aa = r >> 2, bb2 = r & 3;
    int cum = (aa + 1)*(2*aa + bb2);    // causal units before group r
    unsigned short* Qu = q3buf + ((size_t)z*144 + cum)*4096;
    __syncthreads();                    // prior group done with mRow/vvRow/dS
    if (tid < 32){
      int row = (z << 10) + bm + tid;
      mRow[tid] = chainU(o2f(rowmax[row]), L);
      float tr = fqa(fqa(o2f(rowmin[row]), L.f1)*L.sc, L.f2);
      float w = fqa(fqa(tr, L.fam) + L.c20, L.fvv);
      float lv = fminf(fmaxf(rintf(w*L.f3.inv) + L.f3.zp, 0.0f), 65535.0f);
      vvLev[tid] = lv;
      vvRow[tid] = (lv - L.f3.zp)*L.f3.scale;   // == fqa(w, f3)
    }
    const _Float16* Ab = q_h + (size_t)z*131072 + (size_t)bm*128;
    h8_t Aq[2][4];
    qk_load_a(Ab, quad, l15, Aq);
    __syncthreads();                    // mRow/vvRow/vvLev visible
    float rs[2][4];
    #pragma unroll
    for (int mt = 0; mt < 2; mt++)
      #pragma unroll
      for (int i = 0; i < 4; i++) rs[mt][i] = 0.0f;
    for (int bn = 0; bn < (nch << 7); bn += 128){
      f4_t acc[2][2];
      { f4_t zz = {0.f,0.f,0.f,0.f}; for (int i=0;i<2;i++) for (int jj=0;jj<2;jj++) acc[i][jj]=zz; }
      qk_chunk32(Aq, Kb, bn, wn, quad, l15, acc);
      unsigned short* Qc = Qu + (size_t)(bn >> 7)*4096;
      if (bn < cstar){
        // fully unmasked chunk: no causal select
        #pragma unroll
        for (int mt = 0; mt < 2; mt++){
          #pragma unroll
          for (int nt = 0; nt < 2; nt++){
            int cl = (wn<<5) + (nt<<4) + l15;
            #pragma unroll
            for (int i = 0; i < 4; i++){
              int rl = (mt<<4) + (quad<<2) + i;
              float a2 = fqa(fqa(acc[mt][nt][i], L.f1)*L.sc, L.f2);
              float lvl = fminf(fmaxf(rintf(a2*L.f3.inv) + L.f3.zp, 0.0f), 65535.0f);
              Qc[rl*128 + cl] = (unsigned short)lvl;
              float a3 = (lvl - L.f3.zp)*L.f3.scale;   // == fqa(a2, f3)
              rs[mt][i] += __expf(a3 - mRow[rl]);
            }
          }
        }
      } else {
        // diagonal (mixed) chunk: per-element causal select on the LEVEL
        #pragma unroll
        for (int mt = 0; mt < 2; mt++){
          #pragma unroll
          for (int nt = 0; nt < 2; nt++){
            int cl = (wn<<5) + (nt<<4) + l15;
            int t = bn + cl;
            #pragma unroll
            for (int i = 0; i < 4; i++){
              int rl = (mt<<4) + (quad<<2) + i;
              float a2 = fqa(fqa(acc[mt][nt][i], L.f1)*L.sc, L.f2);
              float lvl = fminf(fmaxf(rintf(a2*L.f3.inv) + L.f3.zp, 0.0f), 65535.0f);
              float qs = (t <= bm + rl) ? lvl : vvLev[rl];
              Qc[rl*128 + cl] = (unsigned short)qs;
              float a3 = (qs - L.f3.zp)*L.f3.scale;
              rs[mt][i] += __expf(a3 - mRow[rl]);
            }
          }
        }
      }
    }
    #pragma unroll
    for (int d = 1; d < 16; d <<= 1)
      #pragma unroll
      for (int mt = 0; mt < 2; mt++)
        #pragma unroll
        for (int i = 0; i < 4; i++) rs[mt][i] += __shfl_xor(rs[mt][i], d, 64);
    if (l15 == 0){
      #pragma unroll
      for (int mt = 0; mt < 2; mt++)
        #pragma unroll
        for (int i = 0; i < 4; i++) dS[wn][(mt<<4) + (quad<<2) + i] = rs[mt][i];
    }
    __syncthreads();
    if (tid < 32){
      float nMask = (float)(1024 - (nch << 7));
      denomS[(z << 10) + bm + tid] = (dS[0][tid] + dS[1][tid]) + (dS[2][tid] + dS[3][tid])
                                     + nMask*__expf(vvRow[tid] - mRow[tid]);
    }
  }
}

// pass 3: PV dequant-GEMM. No QK recompute, no LDS marshalling, no barriers:
// read q3 levels in A-fragment layout, n = clamp(rint(exp((q-zp)s - m)*rp)),
// af = f16(n*scale*1024), MFMA with vT, direct ctx store. Paired groups.
__global__ __launch_bounds__(256) void k_qk_pv(const unsigned short* __restrict__ q3buf,
                                               const _Float16* __restrict__ vT,
                                               float* __restrict__ ctx,
                                               const unsigned* __restrict__ rowmax,
                                               const float* __restrict__ denomS, unsigned* stats){
  QK_IDS
  int j = blockIdx.x, z = blockIdx.y;
  int b = z >> 4, h = z & 15;
  LogitQ L = derive_logit(stats);
  FQP p4 = fqp(0.0f, 1.0f/dec_slot(stats, 32));
  float c1024 = p4.scale*1024.0f;
  float zp3 = L.f3.zp, s3 = L.f3.scale;
  const _Float16* Vb = vT + (size_t)(b*8 + (h>>1))*131072;
  float* Cb = ctx + ((size_t)b << 10)*2048 + (size_t)h*128;
  float cmn = FLT_MAX, cmx = -FLT_MAX;
  for (int g = 0; g < 2; g++){
    int r = g ? (31 - j) : j;
    int bm = r << 5;
    int nch = (r >> 2) + 1;
    int aa = r >> 2, bb2 = r & 3;
    int cum = (aa + 1)*(2*aa + bb2);
    const unsigned short* Qu = q3buf + ((size_t)z*144 + cum)*4096;
    float mR[2], rpR[2];
    #pragma unroll
    for (int mt = 0; mt < 2; mt++){
      int row = (z << 10) + bm + (mt<<4) + l15;
      mR[mt] = chainU(o2f(rowmax[row]), L);
      rpR[mt] = p4.inv/denomS[row];
    }
    f4_t pacc[2][2];
    { f4_t zz = {0.f,0.f,0.f,0.f}; for (int i=0;i<2;i++) for (int jj=0;jj<2;jj++) pacc[i][jj]=zz; }
    for (int c = 0; c < nch; c++){
      const unsigned short* Qc = Qu + (size_t)c*4096;
      #pragma unroll
      for (int k0 = 0; k0 < 4; k0++){
        h8_t af[2], bf[2];
        #pragma unroll
        for (int mt = 0; mt < 2; mt++){
          const unsigned short* pr = Qc + ((mt<<4) + l15)*128 + (k0<<5) + (quad<<3);
          u16x4 u = *(const u16x4*)pr, w = *(const u16x4*)(pr + 4);
          h8_t o;
          #pragma unroll
          for (int jj = 0; jj < 4; jj++){
            float a3u = ((float)u[jj] - zp3)*s3;
            float nu = fminf(fmaxf(rintf(__expf(a3u - mR[mt])*rpR[mt]), 0.0f), 65535.0f);
            o[jj] = (_Float16)(nu*c1024);
            float a3w = ((float)w[jj] - zp3)*s3;
            float nw = fminf(fmaxf(rintf(__expf(a3w - mR[mt])*rpR[mt]), 0.0f), 65535.0f);
            o[jj+4] = (_Float16)(nw*c1024);
          }
          af[mt] = o;
        }
        #pragma unroll
        for (int nt = 0; nt < 2; nt++)
          bf[nt] = *(const h8_t*)(Vb + (size_t)((wn<<5) + (nt<<4) + l15)*1024 + (c<<7) + (k0<<5) + (quad<<3));
        #pragma unroll
        for (int mt = 0; mt < 2; mt++)
          #pragma unroll
          for (int nt = 0; nt < 2; nt++)
            pacc[mt][nt] = __builtin_amdgcn_mfma_f32_16x16x32_f16(af[mt], bf[nt], pacc[mt][nt], 0, 0, 0);
      }
    }
    #pragma unroll
    for (int mt = 0; mt < 2; mt++)
      #pragma unroll
      for (int nt = 0; nt < 2; nt++){
        int Cc = (wn<<5) + (nt<<4) + l15;
        #pragma unroll
        for (int i = 0; i < 4; i++){
          int R = bm + (mt<<4) + (quad<<2) + i;
          float v = pacc[mt][nt][i]*(1.0f/1024.0f);
          Cb[(size_t)R*2048 + Cc] = v;
          cmn = fminf(cmn, v); cmx = fmaxf(cmx, v);
        }
      }
  }
  __shared__ float red[256];
  float bmn = bred_min(cmn, red), bmx = bred_max(cmx, red);
  if (tid == 0){ atomicMin(&stats[36*16], f2o(bmn)); atomicMax(&stats[37*16], f2o(bmx)); }
}

// attn f32 expansion: uniform BW-bound. grid (chunk=8, group=32, z=32).
// Lane mapping: idx = it*256 + tid, row = idx>>5, col = (idx&31)<<2 ->
// 32 lanes x 16B = 512B contiguous per wave store (full-line coverage,
// no write amplification; proven pattern from round-1 pv: 147 MB measured).
__global__ __launch_bounds__(256) void k_attn_expand(const unsigned short* __restrict__ q3buf,
                                                     float* __restrict__ attn,
                                                     const unsigned* __restrict__ rowmax,
                                                     const float* __restrict__ denomS,
                                                     const unsigned* stats){
  int c = blockIdx.x, r = blockIdx.y, z = blockIdx.z;
  int nch = (r >> 2) + 1;
  int tid = threadIdx.x;
  float* Cb = attn + ((size_t)z << 20) + ((size_t)(r << 5))*1024 + (c << 7);
  if (c >= nch){
    f4_t zz = {0.f,0.f,0.f,0.f};
    #pragma unroll
    for (int it = 0; it < 4; it++){
      int idx = (it << 8) + tid;           // 1024 f4 = 32 rows x 32 segs
      int row = idx >> 5, col = (idx & 31) << 2;
      __builtin_nontemporal_store(zz, (f4_t*)(Cb + (size_t)row*1024 + col));
    }
    return;
  }
  LogitQ L = derive_logit(stats);
  FQP p4 = fqp(0.0f, 1.0f/dec_slot(stats, 32));
  float zp3 = L.f3.zp, s3 = L.f3.scale;
  int aa = r >> 2, bb2 = r & 3;
  int cum = (aa + 1)*(2*aa + bb2);
  const unsigned short* Qu = q3buf + ((size_t)z*144 + cum + c)*4096;
  #pragma unroll
  for (int it = 0; it < 4; it++){
    int idx = (it << 8) + tid;
    int row = idx >> 5, col = (idx & 31) << 2;
    int grow = (z << 10) + (r << 5) + row;
    float m = chainU(o2f(rowmax[grow]), L);
    float rp = p4.inv/denomS[grow];
    u16x4 u = *(const u16x4*)(Qu + row*128 + col);
    f4_t v4;
    #pragma unroll
    for (int jj = 0; jj < 4; jj++){
      float a3 = ((float)u[jj] - zp3)*s3;
      float n = fminf(fmaxf(rintf(__expf(a3 - m)*rp), 0.0f), 65535.0f);
      v4[jj] = n*p4.scale;
    }
    __builtin_nontemporal_store(v4, (f4_t*)(Cb + (size_t)row*1024 + col));
  }
}

// ===========================================================================

// fq16(A) then per-128 rmsnorm; writes (B,NH,S,D) fp32; reduces full+half ranges
__global__ __launch_bounds__(256) void k_rms(const float* __restrict__ lin, float* __restrict__ buf,
                                             const float* __restrict__ gw, unsigned* stats,
                                             int slot_lin, int slot_out, int NHh, int rows){
  FQP pA = fqp(dec_slot(stats, slot_lin), dec_slot(stats, slot_lin+1));
  int lane = threadIdx.x & 63;
  int wv = (blockIdx.x*256 + threadIdx.x) >> 6;
  int nwv = (gridDim.x*256) >> 6;
  float w0 = gw[lane], w1 = gw[lane + 64];
  float fmn = FLT_MAX, fmx = -FLT_MAX, hmn = FLT_MAX, hmx = -FLT_MAX;
  for (int r = wv; r < rows; r += nwv){
    int h = r % NHh; int rem = r / NHh; int s2 = rem & 1023; int b = rem >> 10;
    const float* src = lin + (size_t)r*128;
    float x0 = fqa(src[lane], pA), x1 = fqa(src[lane + 64], pA);
    float ss = x0*x0 + x1*x1;
    #pragma unroll
    for (int m = 1; m < 64; m <<= 1) ss += __shfl_xor(ss, m, 64);
    float rr = 1.0f/sqrtf(ss*(1.0f/128.0f) + 1e-6f);
    float y0 = x0*rr*w0, y1 = x1*rr*w1;
    float* dst = buf + ((size_t)((b*NHh + h) << 10) + s2)*128;
    dst[lane] = y0; dst[lane + 64] = y1;
    fmn = fminf(fmn, fminf(y0, y1)); fmx = fmaxf(fmx, fmaxf(y0, y1));
    hmn = fminf(hmn, y1); hmx = fmaxf(hmx, y1);
  }
  __shared__ float red[256];
  float a = bred_min(fmn, red), bb = bred_max(fmx, red);
  float c = bred_min(hmn, red), d = bred_max(hmx, red);
  if (threadIdx.x == 0){
    atomicMin(&stats[slot_out*16], f2o(a));     atomicMax(&stats[(slot_out+1)*16], f2o(bb));
    atomicMin(&stats[(slot_out+2)*16], f2o(c)); atomicMax(&stats[(slot_out+3)*16], f2o(d));
  }
}

struct RopeQ { FQP B, C, E, F; };
__device__ RopeQ derive_rope(const unsigned* st, int base){
  float ymn = dec_slot(st, base),   ymx = dec_slot(st, base+1);
  float y2mn = dec_slot(st, base+2), y2mx = dec_slot(st, base+3);
  RopeQ r;
  r.B = fqp(ymn, ymx);
  float zmn = fqa(ymn, r.B), zmx = fqa(ymx, r.B);
  r.C = fqp(zmn, zmx);
  float zlo = fqa(zmn, r.C), zhi = fqa(zmx, r.C);
  float z2lo = fqa(fqa(y2mn, r.B), r.C), z2hi = fqa(fqa(y2mx, r.B), r.C);
  r.E = fqp(-z2hi, -z2lo);
  float nlo = fqa(-z2hi, r.E), nhi = fqa(-z2lo, r.E);
  r.F = fqp_raw(fminf(fminf(zlo, nlo), 0.0f), fmaxf(fmaxf(zhi, nhi), 0.0f));
  return r;
}

__global__ __launch_bounds__(256) void k_rope(float* __restrict__ buf, const float* __restrict__ cosp,
                                              const float* __restrict__ sinp, unsigned* stats,
                                              int slot_norm, int slot_prod, int slot_sum,
                                              int NHh, int rows, int do_write){
  RopeQ R = derive_rope(stats, slot_norm);
  FQP pD, pG;
  if (do_write){
    pD = fqp(dec_slot(stats, slot_prod),   dec_slot(stats, slot_prod+1));
    pG = fqp(dec_slot(stats, slot_prod+2), dec_slot(stats, slot_prod+3));
  }
  int lane = threadIdx.x & 63;
  int wv = (blockIdx.x*256 + threadIdx.x) >> 6, nwv = (gridDim.x*256) >> 6;
  float m0 = FLT_MAX, M0 = -FLT_MAX, m1 = FLT_MAX, M1 = -FLT_MAX;
  for (int r = wv; r < rows; r += nwv){
    int s2 = r & 1023; int bh = r >> 10; int b = bh/NHh;
    float* base = buf + (size_t)r*128;
    float y0 = base[lane], y1 = base[lane + 64];
    float z0 = fqa(fqa(y0, R.B), R.C), z1 = fqa(fqa(y1, R.B), R.C);
    const float* cr = cosp + (size_t)((b << 10) + s2)*128;
    const float* sr = sinp + (size_t)((b << 10) + s2)*128;
    float c0 = cr[lane], c1 = cr[lane + 64], sn0 = sr[lane], sn1 = sr[lane + 64];
    float pc0 = z0*c0, pc1 = z1*c1;
    float rh0 = fqa(fqa(-z1, R.E), R.F);
    float rh1 = fqa(z0, R.F);
    float ps0 = rh0*sn0, ps1 = rh1*sn1;
    if (!do_write){
      m0 = fminf(m0, fminf(pc0, pc1)); M0 = fmaxf(M0, fmaxf(pc0, pc1));
      m1 = fminf(m1, fminf(ps0, ps1)); M1 = fmaxf(M1, fmaxf(ps0, ps1));
    } else {
      float sv0 = fqa(pc0, pD) + fqa(ps0, pG);
      float sv1 = fqa(pc1, pD) + fqa(ps1, pG);
      base[lane] = sv0; base[lane + 64] = sv1;
      m0 = fminf(m0, fminf(sv0, sv1)); M0 = fmaxf(M0, fmaxf(sv0, sv1));
    }
  }
  __shared__ float red[256];
  if (!do_write){
    float a = bred_min(m0, red), bb = bred_max(M0, red);
    float c = bred_min(m1, red), d = bred_max(M1, red);
    if (threadIdx.x == 0){
      atomicMin(&stats[slot_prod*16], f2o(a));     atomicMax(&stats[(slot_prod+1)*16], f2o(bb));
      atomicMin(&stats[(slot_prod+2)*16], f2o(c)); atomicMax(&stats[(slot_prod+3)*16], f2o(d));
    }
  } else {
    float a = bred_min(m0, red), bb = bred_max(M0, red);
    if (threadIdx.x == 0){ atomicMin(&stats[slot_sum*16], f2o(a)); atomicMax(&stats[(slot_sum+1)*16], f2o(bb)); }
  }
}

// V transpose + fq8(fq16) -> f16: vT[b][kv][d][t]
__global__ __launch_bounds__(256) void k_vT(const float* __restrict__ vlin, _Float16* __restrict__ vT,
                                            const unsigned* stats){
  FQP pv = fqp(dec_slot(stats, 6), dec_slot(stats, 7));
  float vlo = fqa(dec_slot(stats, 6), pv), vhi = fqa(dec_slot(stats, 7), pv);
  float v8s = fmaxf(fmaxf(fabsf(vlo), fabsf(vhi))/127.0f, 1e-12f), v8si = 1.0f/v8s;
  __shared__ float tile[64][65];
  int bkv = blockIdx.z, t0 = blockIdx.x << 6, d0 = blockIdx.y << 6;
  int b = bkv >> 3, kv = bkv & 7;
  const float* src = vlin + ((size_t)(b << 10))*1024 + (size_t)kv*128;
  int tx = threadIdx.x & 63, tq = threadIdx.x >> 6;
  #pragma unroll
  for (int i = 0; i < 16; i++){
    int tt = (i << 2) + tq;
    float x = src[(size_t)(t0 + tt)*1024 + d0 + tx];
    tile[tx][tt] = fq8(fqa(x, pv), v8s, v8si);
  }
  __syncthreads();
  _Float16* dst = vT + (size_t)bkv*131072;
  #pragma unroll
  for (int i = 0; i < 16; i++){
    int dd = (i << 2) + tq;
    dst[(size_t)(d0 + dd)*1024 + t0 + tx] = (_Float16)tile[dd][tx];
  }
}

extern "C" void kernel_launch(void* const* d_in, const int* in_sizes, int n_in,
                              void* d_out, int out_size, void* d_ws, size_t ws_size,
                              hipStream_t stream){
  (void)in_sizes; (void)n_in; (void)out_size; (void)ws_size;
  const float* hs   = (const float*)d_in[0];
  const float* cosp = (const float*)d_in[1];
  const float* sinp = (const float*)d_in[2];
  const float* Wq   = (const float*)d_in[4];
  const float* Wk   = (const float*)d_in[5];
  const float* Wv   = (const float*)d_in[6];
  const float* Wo   = (const float*)d_in[7];
  const float* qnw  = (const float*)d_in[8];
  const float* knw  = (const float*)d_in[9];

  float* outp = (float*)d_out;
  float* attn = outp + 4194304;      // final quantized softmax

  const size_t MEG = 1u << 20;       // floats
  float* wsf = (float*)d_ws;
  _Float16* woq_h = (_Float16*)(wsf + 0);
  _Float16* wqq_h = (_Float16*)(wsf + 2*MEG);
  _Float16* wkq_h = (_Float16*)(wsf + 4*MEG);
  _Float16* wvq_h = (_Float16*)(wsf + 5*MEG);
  _Float16* hsq_h = (_Float16*)(wsf + 6*MEG);
  float* qlin = wsf + 8*MEG;  float* ctx = qlin;   // ctx reuses qlin
  float* klin = wsf + 12*MEG;
  float* vlin = wsf + 14*MEG;
  float* qbuf = wsf + 16*MEG;
  float* kbuf = wsf + 20*MEG;
  _Float16* q_h   = (_Float16*)(wsf + 22*MEG);
  _Float16* k_h   = (_Float16*)(wsf + 24*MEG);
  _Float16* vT_h  = (_Float16*)(wsf + 25*MEG);
  _Float16* ctx_h = (_Float16*)(wsf + 26*MEG);
  unsigned* rowmin = (unsigned*)(wsf + 28*MEG);
  unsigned* rowmax = (unsigned*)(wsf + 28*MEG + 32768);
  float* denomS = wsf + 28*MEG + 65536;
  unsigned* stats = (unsigned*)(wsf + 28*MEG + 98304);
  // q3 levels: 32 z * 144 units * 4096 u16 = 36 MB. Overlays klin/vlin/qbuf/
  // kbuf (wsf+12M..21M floats) -- all dead before k_qk_denom writes it.
  unsigned short* q3buf = (unsigned short*)(wsf + 12*MEG);

  k_init<<<4, 256, 0, stream>>>(stats);

  k_quantw<<<4096, 256, 0, stream>>>(Wq, wqq_h);
  k_quantw<<<2048, 256, 0, stream>>>(Wk, wkq_h);
  k_quantw<<<2048, 256, 0, stream>>>(Wv, wvq_h);
  k_quantw<<<4096, 256, 0, stream>>>(Wo, woq_h);

  k_minmax<<<1024, 256, 0, stream>>>(hs, 4194304, stats, 0);
  k_fq_ew16<<<4096, 256, 0, stream>>>(hs, hsq_h, stats, 0);

  // projections (f16 MFMA, async LDS staging), raw-output range stats fused
  k_hgemm_f<<<dim3(16, 16), 256, 0, stream>>>(hsq_h, wqq_h, qlin, 2048, 2048, stats, 2);
  k_hgemm_kv<<<dim3(8, 16, 2), 256, 0, stream>>>(hsq_h, wkq_h, wvq_h, klin, vlin, 2048, stats);

  // fq16 + rmsnorm (fp32) + range reductions
  k_rms<<<1024, 256, 0, stream>>>(qlin, qbuf, qnw, stats, 2, 8, 16, 32768);
  k_rms<<<512, 256, 0, stream>>>(klin, kbuf, knw, stats, 4, 12, 8, 16384);

  // RoPE: range pass then write pass
  k_rope<<<1024, 256, 0, stream>>>(qbuf, cosp, sinp, stats, 8, 16, 24, 16, 32768, 0);
  k_rope<<<512, 256, 0, stream>>>(kbuf, cosp, sinp, stats, 12, 20, 26, 8, 16384, 0);
  k_rope<<<1024, 256, 0, stream>>>(qbuf, cosp, sinp, stats, 8, 16, 24, 16, 32768, 1);
  k_rope<<<512, 256, 0, stream>>>(kbuf, cosp, sinp, stats, 12, 20, 26, 8, 16384, 1);

  // operand conversion for QK and V transpose
  k_fq_ew16<<<4096, 256, 0, stream>>>(qbuf, q_h, stats, 24);
  k_fq8_ew16<<<2048, 256, 0, stream>>>(kbuf, k_h, stats, 26);
  k_vT<<<dim3(16, 2, 16), 256, 0, stream>>>(vlin, vT_h, stats);

  // attention: stats (full sweep) -> denom (+q3 store) -> pv (dequant-GEMM)
  // -> expand (attn f32 write). denom/pv paired (j, 31-j) = 9 units/block.
  k_qk_stats<<<dim3(32, 32), 256, 0, stream>>>(q_h, k_h, stats, rowmin, rowmax);
  k_rowstat_m2<<<8, 256, 0, stream>>>(rowmin, stats, 32768);
  k_qk_denom<<<dim3(16, 32), 256, 0, stream>>>(q_h, k_h, rowmin, rowmax, denomS, q3buf, stats);
  k_denom_min<<<8, 256, 0, stream>>>(denomS, stats, 32768);
  k_qk_pv<<<dim3(16, 32), 256, 0, stream>>>(q3buf, vT_h, ctx, rowmax, denomS, stats);
  k_attn_expand<<<dim3(8, 32, 32), 256, 0, stream>>>(q3buf, attn, rowmax, denomS, stats);

  // ctx (stats fused in PV) -> f16 -> O-proj
  k_fq_ew16<<<4096, 256, 0, stream>>>(ctx, ctx_h, stats, 36);
  k_hgemm_f<<<dim3(16, 16), 256, 0, stream>>>(ctx_h, woq_h, outp, 2048, 2048, stats, -1);
}

// Round 6
// 642.827 us; speedup vs baseline: 1.3055x; 1.0671x over previous
//
#include <hip/hip_runtime.h>
#include <cfloat>
#include <cmath>

// ---------------------------------------------------------------------------
// Qwen3Attention fake-quant forward. B=2 S=1024 HID=2048 NH=16 NKV=8 D=128.
// Round 12: projection occupancy. Q/K/V projections fused into one kernel,
// grid (8,16,4): z=0,1 -> Q col-halves, z=2 -> K, z=3 -> V. 512 blocks =
// 2 blocks/CU = 8 waves/CU, so one block's staging-barrier drain overlaps
// the other's MFMA (previously 1 block/CU: drain fully exposed). Same MFMA
// chain / staging / k-order per output element -> bit-exact. quantw x4
// merged into one launch.
// ---------------------------------------------------------------------------

#define FQ_EPS      1.5259021896696422e-09f   // 0.0001/65535
#define SCALING_F   0.08838834764831845f      // 128**-0.5
#define S_LEN       1024

typedef _Float16 h8_t __attribute__((ext_vector_type(8)));
typedef _Float16 h4_t __attribute__((ext_vector_type(4)));
typedef float    f4_t __attribute__((ext_vector_type(4)));
typedef unsigned short u16x4 __attribute__((ext_vector_type(4)));

// ---- float <-> order-preserving unsigned encoding (for atomic min/max) ----
__device__ __forceinline__ unsigned f2o(float f){
  unsigned u = __float_as_uint(f);
  return (u & 0x80000000u) ? ~u : (u | 0x80000000u);
}
__device__ __forceinline__ float o2f(unsigned u){
  return __uint_as_float((u & 0x80000000u) ? (u ^ 0x80000000u) : ~u);
}
__device__ __forceinline__ float dec_slot(const unsigned* st, int s){ return o2f(st[s*16]); }

// ---- fq16 helpers ----
struct FQP { float scale, zp, inv; };
__device__ __forceinline__ FQP fqp_raw(float mn, float mx){
  FQP p; p.scale = fmaxf((mx - mn)/65535.0f, FQ_EPS); p.zp = rintf(-mn/p.scale);
  p.inv = 1.0f/p.scale; return p;
}
__device__ __forceinline__ FQP fqp(float mn0, float mx0){
  return fqp_raw(fminf(mn0, 0.0f), fmaxf(mx0, 0.0f));
}
__device__ __forceinline__ float fqa(float x, FQP p){
  float q = rintf(x*p.inv) + p.zp;
  q = fminf(fmaxf(q, 0.0f), 65535.0f);
  return (q - p.zp)*p.scale;
}
__device__ __forceinline__ float fq8(float x, float s, float si){
  return fminf(fmaxf(rintf(x*si), -128.0f), 127.0f)*s;
}

// ---- block reductions (blockDim == 256) ----
__device__ __forceinline__ float bred_min(float v, float* red){
  int tid = threadIdx.x; red[tid] = v; __syncthreads();
  for (int s = 128; s > 0; s >>= 1){ if (tid < s) red[tid] = fminf(red[tid], red[tid+s]); __syncthreads(); }
  float r = red[0]; __syncthreads(); return r;
}
__device__ __forceinline__ float bred_max(float v, float* red){
  int tid = threadIdx.x; red[tid] = v; __syncthreads();
  for (int s = 128; s > 0; s >>= 1){ if (tid < s) red[tid] = fmaxf(red[tid], red[tid+s]); __syncthreads(); }
  float r = red[0]; __syncthreads(); return r;
}

// ---- stats slot map (even=min, odd=max) ----
// 0/1 hs | 2/3 qlin | 4/5 klin | 6/7 vlin | 8/9 qn | 10/11 qn2 | 12/13 kn | 14/15 kn2
// 16/17 q*c | 18/19 qrh*s | 20/21 k*c | 22/23 krh*s | 24/25 qsum | 26/27 ksum
// 28/29 logits | 31 unmaskedMax | 32 denomMin | 35 maxOfRowMins | 36/37 ctx

__global__ void k_init(unsigned* stats){
  int i = blockIdx.x*blockDim.x + threadIdx.x;
  if (i < 1024) stats[i] = (((i & 15) == 0) && (((i >> 4) & 1) == 0)) ? 0xFFFFFFFFu : 0u;
}

// lpbq weight quantization -> f16, all four weights in one launch.
// 4 elems/thread; 8-lane shfl = 32-elem block.
__global__ __launch_bounds__(256) void k_quantw4(const float* __restrict__ Wq, const float* __restrict__ Wk,
                                                 const float* __restrict__ Wv, const float* __restrict__ Wo,
                                                 _Float16* __restrict__ Qh, _Float16* __restrict__ Kh,
                                                 _Float16* __restrict__ Vh, _Float16* __restrict__ Oh){
  int bx = blockIdx.x;
  const float* W; _Float16* Wh; int base;
  if (bx < 4096){ W = Wq; Wh = Qh; base = 0; }
  else if (bx < 6144){ W = Wk; Wh = Kh; base = 4096; }
  else if (bx < 8192){ W = Wv; Wh = Vh; base = 6144; }
  else { W = Wo; Wh = Oh; base = 8192; }
  int i = (bx - base)*256 + threadIdx.x;
  float4 v = ((const float4*)W)[i];
  float am = fmaxf(fmaxf(fabsf(v.x), fabsf(v.y)), fmaxf(fabsf(v.z), fabsf(v.w)));
  #pragma unroll
  for (int m = 1; m < 8; m <<= 1) am = fmaxf(am, __shfl_xor(am, m, 64));
  float s = fmaxf(am/7.0f, 1e-12f), si = 1.0f/s;
  h4_t o;
  o[0] = (_Float16)(fminf(fmaxf(rintf(v.x*si), -8.0f), 7.0f)*s);
  o[1] = (_Float16)(fminf(fmaxf(rintf(v.y*si), -8.0f), 7.0f)*s);
  o[2] = (_Float16)(fminf(fmaxf(rintf(v.z*si), -8.0f), 7.0f)*s);
  o[3] = (_Float16)(fminf(fmaxf(rintf(v.w*si), -8.0f), 7.0f)*s);
  *(h4_t*)(Wh + ((size_t)i << 2)) = o;
}

__global__ __launch_bounds__(256) void k_minmax(const float* __restrict__ x, int n, unsigned* stats, int slot){
  float mn = FLT_MAX, mx = -FLT_MAX;
  for (int i = blockIdx.x*256 + threadIdx.x; i < n; i += gridDim.x*256){
    float v = x[i]; mn = fminf(mn, v); mx = fmaxf(mx, v);
  }
  __shared__ float red[256];
  float bmn = bred_min(mn, red), bmx = bred_max(mx, red);
  if (threadIdx.x == 0){ atomicMin(&stats[slot*16], f2o(bmn)); atomicMax(&stats[(slot+1)*16], f2o(bmx)); }
}

// fq16 elementwise -> f16, 4 elems/thread
__global__ __launch_bounds__(256) void k_fq_ew16(const float* __restrict__ x, _Float16* __restrict__ y,
                                                 const unsigned* stats, int slot){
  FQP p = fqp(dec_slot(stats, slot), dec_slot(stats, slot+1));
  int i = blockIdx.x*256 + threadIdx.x;
  float4 v = ((const float4*)x)[i];
  h4_t o;
  o[0] = (_Float16)fqa(v.x, p); o[1] = (_Float16)fqa(v.y, p);
  o[2] = (_Float16)fqa(v.z, p); o[3] = (_Float16)fqa(v.w, p);
  *(h4_t*)(y + ((size_t)i << 2)) = o;
}

// fq8(fq16(x)) elementwise -> f16 (for K)
__global__ __launch_bounds__(256) void k_fq8_ew16(const float* __restrict__ x, _Float16* __restrict__ y,
                                                  const unsigned* stats, int slot){
  FQP p = fqp(dec_slot(stats, slot), dec_slot(stats, slot+1));
  float lo = fqa(dec_slot(stats, slot), p), hi = fqa(dec_slot(stats, slot+1), p);
  float s8 = fmaxf(fmaxf(fabsf(lo), fabsf(hi))/127.0f, 1e-12f), s8i = 1.0f/s8;
  int i = blockIdx.x*256 + threadIdx.x;
  float4 v = ((const float4*)x)[i];
  h4_t o;
  o[0] = (_Float16)fq8(fqa(v.x, p), s8, s8i); o[1] = (_Float16)fq8(fqa(v.y, p), s8, s8i);
  o[2] = (_Float16)fq8(fqa(v.z, p), s8, s8i); o[3] = (_Float16)fq8(fqa(v.w, p), s8, s8i);
  *(h4_t*)(y + ((size_t)i << 2)) = o;
}

// ================= f16 MFMA GEMM core for projections (NT) =================
// async staging: LDS dest is wave-uniform base + lane*16B (constraint-safe).
#define GLDS16(g, l) __builtin_amdgcn_global_load_lds( \
    (__attribute__((address_space(1))) unsigned int*)(g), \
    (__attribute__((address_space(3))) unsigned int*)(l), 16, 0, 0)

__device__ __forceinline__ void stage_tile(const _Float16* __restrict__ src, int ld, int k0,
                                           _Float16* __restrict__ dst){
  #pragma unroll
  for (int it = 0; it < 2; it++){
    int c = threadIdx.x + (it << 8);
    int row = c >> 2, off = (c & 3) << 3;
    GLDS16(src + (size_t)row*ld + k0 + off, dst + (c << 3));
  }
}

__device__ __forceinline__ void hgemm_main(const _Float16* __restrict__ A, int lda,
                                           const _Float16* __restrict__ B, int ldb, int K,
                                           f4_t acc[4][4], _Float16* As, _Float16* Bs){
  int lane = threadIdx.x & 63, wave = threadIdx.x >> 6;
  int wm = wave & 1, wn = wave >> 1, quad = lane >> 4, l15 = lane & 15;
  for (int k0 = 0; k0 < K; k0 += 32){
    __syncthreads();
    stage_tile(A, lda, k0, As);
    stage_tile(B, ldb, k0, Bs);
    __syncthreads();
    h8_t af[4], bf[4];
    #pragma unroll
    for (int mt = 0; mt < 4; mt++)
      af[mt] = *(const h8_t*)(As + ((((wm<<6) + (mt<<4) + l15)) << 5) + (quad << 3));
    #pragma unroll
    for (int nt = 0; nt < 4; nt++)
      bf[nt] = *(const h8_t*)(Bs + ((((wn<<6) + (nt<<4) + l15)) << 5) + (quad << 3));
    #pragma unroll
    for (int mt = 0; mt < 4; mt++)
      #pragma unroll
      for (int nt = 0; nt < 4; nt++)
        acc[mt][nt] = __builtin_amdgcn_mfma_f32_16x16x32_f16(af[mt], bf[nt], acc[mt][nt], 0, 0, 0);
  }
}

#define HG_PROLOG  \
  __shared__ __align__(16) _Float16 As[4096], Bs[4096]; \
  __shared__ float red[256]; \
  f4_t acc[4][4]; \
  { f4_t zz = {0.f,0.f,0.f,0.f}; \
    for (int i=0;i<4;i++) for (int j=0;j<4;j++) acc[i][j] = zz; } \
  int lane = threadIdx.x & 63, wave = threadIdx.x >> 6; \
  int wm = wave & 1, wn = wave >> 1, quad = lane >> 4, l15 = lane & 15; (void)red; (void)lane;

// C/D lane map (m89-verified): D[row=(quad*4+reg)][col=l15].

__global__ __launch_bounds__(256) void k_hgemm_f(const _Float16* __restrict__ A, const _Float16* __restrict__ B,
                                                 float* __restrict__ C, int N, int K,
                                                 unsigned* stats, int slotC){
  HG_PROLOG
  int bm = blockIdx.y << 7, bn = blockIdx.x << 7;
  hgemm_main(A + (size_t)bm*K, K, B + (size_t)bn*K, K, K, acc, As, Bs);
  float mn = FLT_MAX, mx = -FLT_MAX;
  #pragma unroll
  for (int mt = 0; mt < 4; mt++)
    #pragma unroll
    for (int nt = 0; nt < 4; nt++){
      int Cc = bn + (wn<<6) + (nt<<4) + l15;
      #pragma unroll
      for (int i = 0; i < 4; i++){
        int R = bm + (wm<<6) + (mt<<4) + (quad<<2) + i;
        float v = acc[mt][nt][i];
        C[(size_t)R*N + Cc] = v;
        mn = fminf(mn, v); mx = fmaxf(mx, v);
      }
    }
  if (slotC >= 0){
    float bmn = bred_min(mn, red), bmx = bred_max(mx, red);
    if (threadIdx.x == 0){ atomicMin(&stats[slotC*16], f2o(bmn)); atomicMax(&stats[(slotC+1)*16], f2o(bmx)); }
  }
}

// fused Q/K/V projections: z=0,1 -> Q col-halves (slot 2), z=2 -> K (slot 4),
// z=3 -> V (slot 6). 512 blocks -> 2 blocks/CU -> 8 waves/CU.
__global__ __launch_bounds__(256) void k_hgemm_qkv(const _Float16* __restrict__ A,
                                                   const _Float16* __restrict__ Bq,
                                                   const _Float16* __restrict__ Bk,
                                                   const _Float16* __restrict__ Bv,
                                                   float* __restrict__ Cq, float* __restrict__ Ck,
                                                   float* __restrict__ Cv,
                                                   int K, unsigned* stats){
  HG_PROLOG
  int z = blockIdx.z;
  const _Float16* Bmat; float* C; int slotC, N, cbase;
  if (z < 2){ Bmat = Bq + (((size_t)z << 10))*K; C = Cq; slotC = 2; N = 2048; cbase = z << 10; }
  else if (z == 2){ Bmat = Bk; C = Ck; slotC = 4; N = 1024; cbase = 0; }
  else { Bmat = Bv; C = Cv; slotC = 6; N = 1024; cbase = 0; }
  int bm = blockIdx.y << 7, bn = blockIdx.x << 7;
  hgemm_main(A + (size_t)bm*K, K, Bmat + (size_t)bn*K, K, K, acc, As, Bs);
  float mn = FLT_MAX, mx = -FLT_MAX;
  #pragma unroll
  for (int mt = 0; mt < 4; mt++)
    #pragma unroll
    for (int nt = 0; nt < 4; nt++){
      int Cc = cbase + bn + (wn<<6) + (nt<<4) + l15;
      #pragma unroll
      for (int i = 0; i < 4; i++){
        int R = bm + (wm<<6) + (mt<<4) + (quad<<2) + i;
        float v = acc[mt][nt][i];
        C[(size_t)R*N + Cc] = v;
        mn = fminf(mn, v); mx = fmaxf(mx, v);
      }
    }
  float bmn = bred_min(mn, red), bmx = bred_max(mx, red);
  if (threadIdx.x == 0){ atomicMin(&stats[slotC*16], f2o(bmn)); atomicMax(&stats[(slotC+1)*16], f2o(bmx)); }
}

// ====================== QK^T attention passes (32-row) =====================
// block = 256 thr (4 waves). A 32-row group r (0..31) covers q-rows
// [32r, 32r+32); it needs nch(r) = (r>>2)+1 K-chunks of 128. Wave wn owns
// cols [32*wn, 32*wn+32): acc[2][2]. Pairing (j, 31-j) -> constant 9
// chunk-units per block. q3 levels (post-f3 u16) are exact -> stored once by
// denom, consumed by pv (PV GEMM) and expand (attn f32 write) bit-exactly.
// causal unit index: cum(r) = (a+1)*(2a+b), a=r>>2, b=r&3; unit = cum + chunk.

#define QK_IDS \
  int lane = threadIdx.x & 63, wn = threadIdx.x >> 6; \
  int quad = lane >> 4, l15 = lane & 15; \
  int tid = threadIdx.x; (void)tid; (void)lane;

__device__ __forceinline__ void qk_load_a(const _Float16* __restrict__ Ab, int quad, int l15,
                                          h8_t Aq[2][4]){
  #pragma unroll
  for (int mt = 0; mt < 2; mt++)
    #pragma unroll
    for (int k0 = 0; k0 < 4; k0++)
      Aq[mt][k0] = *(const h8_t*)(Ab + (size_t)((mt<<4) + l15)*128 + (k0<<5) + (quad<<3));
}

__device__ __forceinline__ void qk_chunk32(const h8_t Aq[2][4], const _Float16* __restrict__ Kb,
                                           int bn, int wn, int quad, int l15, f4_t acc[2][2]){
  #pragma unroll
  for (int k0 = 0; k0 < 4; k0++){
    h8_t bf[2];
    #pragma unroll
    for (int nt = 0; nt < 2; nt++)
      bf[nt] = *(const h8_t*)(Kb + (size_t)(bn + (wn<<5) + (nt<<4) + l15)*128 + (k0<<5) + (quad<<3));
    #pragma unroll
    for (int mt = 0; mt < 2; mt++)
      #pragma unroll
      for (int nt = 0; nt < 2; nt++)
        acc[mt][nt] = __builtin_amdgcn_mfma_f32_16x16x32_f16(Aq[mt][k0], bf[nt], acc[mt][nt], 0, 0, 0);
  }
}

// pass 1: global logit stats + per-row min / unmasked max (full sweep; the
// fq16 range covers pre-mask logits). 32-row groups, grid (32, 32).
__global__ __launch_bounds__(256) void k_qk_stats(const _Float16* __restrict__ q_h, const _Float16* __restrict__ k_h,
                                                  unsigned* stats, unsigned* rowmin, unsigned* rowmax){
  QK_IDS
  int bm = blockIdx.x << 5, z = blockIdx.y;
  int b = z >> 4, h = z & 15;
  const _Float16* Ab = q_h + (size_t)z*131072 + (size_t)bm*128;
  const _Float16* Kb = k_h + (size_t)(b*8 + (h>>1))*131072;
  h8_t Aq[2][4];
  qk_load_a(Ab, quad, l15, Aq);
  float rmv[2][4], rxv[2][4];
  #pragma unroll
  for (int mt = 0; mt < 2; mt++)
    #pragma unroll
    for (int i = 0; i < 4; i++){ rmv[mt][i] = FLT_MAX; rxv[mt][i] = -FLT_MAX; }
  float mn = FLT_MAX, mx = -FLT_MAX, mxU = -FLT_MAX;
  for (int bn = 0; bn < 1024; bn += 128){
    f4_t acc[2][2];
    { f4_t zz = {0.f,0.f,0.f,0.f}; for (int i=0;i<2;i++) for (int j=0;j<2;j++) acc[i][j]=zz; }
    qk_chunk32(Aq, Kb, bn, wn, quad, l15, acc);
    #pragma unroll
    for (int mt = 0; mt < 2; mt++){
      int rb = bm + (mt<<4) + (quad<<2);
      #pragma unroll
      for (int nt = 0; nt < 2; nt++){
        int t = bn + (wn<<5) + (nt<<4) + l15;
        #pragma unroll
        for (int i = 0; i < 4; i++){
          float v = acc[mt][nt][i];
          mn = fminf(mn, v); mx = fmaxf(mx, v);
          rmv[mt][i] = fminf(rmv[mt][i], v);
          if (t <= rb + i){ mxU = fmaxf(mxU, v); rxv[mt][i] = fmaxf(rxv[mt][i], v); }
        }
      }
    }
  }
  #pragma unroll
  for (int d = 1; d < 16; d <<= 1)
    #pragma unroll
    for (int mt = 0; mt < 2; mt++)
      #pragma unroll
      for (int i = 0; i < 4; i++){
        rmv[mt][i] = fminf(rmv[mt][i], __shfl_xor(rmv[mt][i], d, 64));
        rxv[mt][i] = fmaxf(rxv[mt][i], __shfl_xor(rxv[mt][i], d, 64));
      }
  __shared__ float rminS[4][32], rmaxS[4][32];
  if (l15 == 0){
    #pragma unroll
    for (int mt = 0; mt < 2; mt++)
      #pragma unroll
      for (int i = 0; i < 4; i++){
        int rl = (mt<<4) + (quad<<2) + i;
        rminS[wn][rl] = rmv[mt][i];
        rmaxS[wn][rl] = rxv[mt][i];
      }
  }
  __syncthreads();
  if (tid < 32){
    float a = fminf(fminf(rminS[0][tid], rminS[1][tid]), fminf(rminS[2][tid], rminS[3][tid]));
    float c = fmaxf(fmaxf(rmaxS[0][tid], rmaxS[1][tid]), fmaxf(rmaxS[2][tid], rmaxS[3][tid]));
    rowmin[(z << 10) + bm + tid] = f2o(a);
    rowmax[(z << 10) + bm + tid] = f2o(c);
  }
  __shared__ float red[256];
  float bmn = bred_min(mn, red), bmx = bred_max(mx, red), bmU = bred_max(mxU, red);
  if (tid == 0){
    atomicMin(&stats[28*16], f2o(bmn));
    atomicMax(&stats[29*16], f2o(bmx));
    atomicMax(&stats[31*16], f2o(bmU));
  }
}

__global__ __launch_bounds__(256) void k_rowstat_m2(const unsigned* __restrict__ rowmin, unsigned* stats, int n){
  float lm = -FLT_MAX;
  for (int i = blockIdx.x*256 + threadIdx.x; i < n; i += gridDim.x*256) lm = fmaxf(lm, o2f(rowmin[i]));
  __shared__ float red[256];
  float m = bred_max(lm, red);
  if (threadIdx.x == 0) atomicMax(&stats[35*16], f2o(m));
}
__global__ __launch_bounds__(256) void k_denom_min(const float* __restrict__ denomS, unsigned* stats, int n){
  float lm = FLT_MAX;
  for (int i = blockIdx.x*256 + threadIdx.x; i < n; i += gridDim.x*256) lm = fminf(lm, denomS[i]);
  __shared__ float red[256];
  float m = -bred_max(-lm, red);
  if (threadIdx.x == 0) atomicMin(&stats[32*16], f2o(m));
}

struct LogitQ { FQP f1, f2, fam, fvv, f3; float sc, c20; };
__device__ LogitQ derive_logit(const unsigned* st){
  LogitQ L;
  FQP ps = fqp(SCALING_F, SCALING_F); L.sc = fqa(SCALING_F, ps);
  FQP p20 = fqp(-20.0f, -20.0f);      L.c20 = fqa(-20.0f, p20);
  float gmn = dec_slot(st, 28), gmx = dec_slot(st, 29);
  float gU = dec_slot(st, 31), M2 = dec_slot(st, 35);
  L.f1 = fqp(gmn, gmx);
  float l1lo = fqa(gmn, L.f1), l1hi = fqa(gmx, L.f1);
  L.f2 = fqp(l1lo*L.sc, l1hi*L.sc);
  float amlo = fqa(fqa(gmn, L.f1)*L.sc, L.f2);
  float amhi = fqa(fqa(M2, L.f1)*L.sc, L.f2);
  L.fam = fqp(amlo, amhi);
  float vslo = fqa(amlo, L.fam) + L.c20, vshi = fqa(amhi, L.fam) + L.c20;
  L.fvv = fqp(vslo, vshi);
  float mn3 = fqa(vslo, L.fvv);
  float mx3 = fqa(fqa(gU, L.f1)*L.sc, L.f2);
  L.f3 = fqp(mn3, mx3);
  return L;
}
__device__ __forceinline__ float chainU(float raw, const LogitQ& L){
  return fqa(fqa(fqa(raw, L.f1)*L.sc, L.f2), L.f3);
}

// pass 2: per-row denominators + q3-level store (u16, causal-packed).
// Paired 32-row groups (j, 31-j) = 9 units/block. Skipped masked chunks
// contribute count*exp(vv-m) per row analytically.
__global__ __launch_bounds__(256) void k_qk_denom(const _Float16* __restrict__ q_h, const _Float16* __restrict__ k_h,
                                                  const unsigned* __restrict__ rowmin,
                                                  const unsigned* __restrict__ rowmax,
                                                  float* __restrict__ denomS,
                                                  unsigned short* __restrict__ q3buf,
                                                  const unsigned* stats){
  QK_IDS
  int j = blockIdx.x, z = blockIdx.y;
  int b = z >> 4, h = z & 15;
  LogitQ L = derive_logit(stats);
  const _Float16* Kb = k_h + (size_t)(b*8 + (h>>1))*131072;
  __shared__ float mRow[32], vvRow[32], vvLev[32];
  __shared__ float dS[4][32];
  for (int g = 0; g < 2; g++){
    int r = g ? (31 - j) : j;
    int bm = r << 5;
    int nch = (r >> 2) + 1;
    int cstar = (r >> 2) << 7;          // diagonal-chunk base
    int aa = r >> 2, bb2 = r & 3;
    int cum = (aa + 1)*(2*aa + bb2);    // causal units before group r
    unsigned short* Qu = q3buf + ((size_t)z*144 + cum)*4096;
    __syncthreads();                    // prior group done with mRow/vvRow/dS
    if (tid < 32){
      int row = (z << 10) + bm + tid;
      mRow[tid] = chainU(o2f(rowmax[row]), L);
      float tr = fqa(fqa(o2f(rowmin[row]), L.f1)*L.sc, L.f2);
      float w = fqa(fqa(tr, L.fam) + L.c20, L.fvv);
      float lv = fminf(fmaxf(rintf(w*L.f3.inv) + L.f3.zp, 0.0f), 65535.0f);
      vvLev[tid] = lv;
      vvRow[tid] = (lv - L.f3.zp)*L.f3.scale;   // == fqa(w, f3)
    }
    const _Float16* Ab = q_h + (size_t)z*131072 + (size_t)bm*128;
    h8_t Aq[2][4];
    qk_load_a(Ab, quad, l15, Aq);
    __syncthreads();                    // mRow/vvRow/vvLev visible
    float rs[2][4];
    #pragma unroll
    for (int mt = 0; mt < 2; mt++)
      #pragma unroll
      for (int i = 0; i < 4; i++) rs[mt][i] = 0.0f;
    for (int bn = 0; bn < (nch << 7); bn += 128){
      f4_t acc[2][2];
      { f4_t zz = {0.f,0.f,0.f,0.f}; for (int i=0;i<2;i++) for (int jj=0;jj<2;jj++) acc[i][jj]=zz; }
      qk_chunk32(Aq, Kb, bn, wn, quad, l15, acc);
      unsigned short* Qc = Qu + (size_t)(bn >> 7)*4096;
      if (bn < cstar){
        // fully unmasked chunk: no causal select
        #pragma unroll
        for (int mt = 0; mt < 2; mt++){
          #pragma unroll
          for (int nt = 0; nt < 2; nt++){
            int cl = (wn<<5) + (nt<<4) + l15;
            #pragma unroll
            for (int i = 0; i < 4; i++){
              int rl = (mt<<4) + (quad<<2) + i;
              float a2 = fqa(fqa(acc[mt][nt][i], L.f1)*L.sc, L.f2);
              float lvl = fminf(fmaxf(rintf(a2*L.f3.inv) + L.f3.zp, 0.0f), 65535.0f);
              Qc[rl*128 + cl] = (unsigned short)lvl;
              float a3 = (lvl - L.f3.zp)*L.f3.scale;   // == fqa(a2, f3)
              rs[mt][i] += __expf(a3 - mRow[rl]);
            }
          }
        }
      } else {
        // diagonal (mixed) chunk: per-element causal select on the LEVEL
        #pragma unroll
        for (int mt = 0; mt < 2; mt++){
          #pragma unroll
          for (int nt = 0; nt < 2; nt++){
            int cl = (wn<<5) + (nt<<4) + l15;
            int t = bn + cl;
            #pragma unroll
            for (int i = 0; i < 4; i++){
              int rl = (mt<<4) + (quad<<2) + i;
              float a2 = fqa(fqa(acc[mt][nt][i], L.f1)*L.sc, L.f2);
              float lvl = fminf(fmaxf(rintf(a2*L.f3.inv) + L.f3.zp, 0.0f), 65535.0f);
              float qs = (t <= bm + rl) ? lvl : vvLev[rl];
              Qc[rl*128 + cl] = (unsigned short)qs;
              float a3 = (qs - L.f3.zp)*L.f3.scale;
              rs[mt][i] += __expf(a3 - mRow[rl]);
            }
          }
        }
      }
    }
    #pragma unroll
    for (int d = 1; d < 16; d <<= 1)
      #pragma unroll
      for (int mt = 0; mt < 2; mt++)
        #pragma unroll
        for (int i = 0; i < 4; i++) rs[mt][i] += __shfl_xor(rs[mt][i], d, 64);
    if (l15 == 0){
      #pragma unroll
      for (int mt = 0; mt < 2; mt++)
        #pragma unroll
        for (int i = 0; i < 4; i++) dS[wn][(mt<<4) + (quad<<2) + i] = rs[mt][i];
    }
    __syncthreads();
    if (tid < 32){
      float nMask = (float)(1024 - (nch << 7));
      denomS[(z << 10) + bm + tid] = (dS[0][tid] + dS[1][tid]) + (dS[2][tid] + dS[3][tid])
                                     + nMask*__expf(vvRow[tid] - mRow[tid]);
    }
  }
}

// pass 3: PV dequant-GEMM. No QK recompute, no LDS marshalling, no barriers:
// read q3 levels in A-fragment layout, n = clamp(rint(exp((q-zp)s - m)*rp)),
// af = f16(n*scale*1024), MFMA with vT, direct ctx store. Paired groups.
__global__ __launch_bounds__(256) void k_qk_pv(const unsigned short* __restrict__ q3buf,
                                               const _Float16* __restrict__ vT,
                                               float* __restrict__ ctx,
                                               const unsigned* __restrict__ rowmax,
                                               const float* __restrict__ denomS, unsigned* stats){
  QK_IDS
  int j = blockIdx.x, z = blockIdx.y;
  int b = z >> 4, h = z & 15;
  LogitQ L = derive_logit(stats);
  FQP p4 = fqp(0.0f, 1.0f/dec_slot(stats, 32));
  float c1024 = p4.scale*1024.0f;
  float zp3 = L.f3.zp, s3 = L.f3.scale;
  const _Float16* Vb = vT + (size_t)(b*8 + (h>>1))*131072;
  float* Cb = ctx + ((size_t)b << 10)*2048 + (size_t)h*128;
  float cmn = FLT_MAX, cmx = -FLT_MAX;
  for (int g = 0; g < 2; g++){
    int r = g ? (31 - j) : j;
    int bm = r << 5;
    int nch = (r >> 2) + 1;
    int aa = r >> 2, bb2 = r & 3;
    int cum = (aa + 1)*(2*aa + bb2);
    const unsigned short* Qu = q3buf + ((size_t)z*144 + cum)*4096;
    float mR[2], rpR[2];
    #pragma unroll
    for (int mt = 0; mt < 2; mt++){
      int row = (z << 10) + bm + (mt<<4) + l15;
      mR[mt] = chainU(o2f(rowmax[row]), L);
      rpR[mt] = p4.inv/denomS[row];
    }
    f4_t pacc[2][2];
    { f4_t zz = {0.f,0.f,0.f,0.f}; for (int i=0;i<2;i++) for (int jj=0;jj<2;jj++) pacc[i][jj]=zz; }
    for (int c = 0; c < nch; c++){
      const unsigned short* Qc = Qu + (size_t)c*4096;
      #pragma unroll
      for (int k0 = 0; k0 < 4; k0++){
        h8_t af[2], bf[2];
        #pragma unroll
        for (int mt = 0; mt < 2; mt++){
          const unsigned short* pr = Qc + ((mt<<4) + l15)*128 + (k0<<5) + (quad<<3);
          u16x4 u = *(const u16x4*)pr, w = *(const u16x4*)(pr + 4);
          h8_t o;
          #pragma unroll
          for (int jj = 0; jj < 4; jj++){
            float a3u = ((float)u[jj] - zp3)*s3;
            float nu = fminf(fmaxf(rintf(__expf(a3u - mR[mt])*rpR[mt]), 0.0f), 65535.0f);
            o[jj] = (_Float16)(nu*c1024);
            float a3w = ((float)w[jj] - zp3)*s3;
            float nw = fminf(fmaxf(rintf(__expf(a3w - mR[mt])*rpR[mt]), 0.0f), 65535.0f);
            o[jj+4] = (_Float16)(nw*c1024);
          }
          af[mt] = o;
        }
        #pragma unroll
        for (int nt = 0; nt < 2; nt++)
          bf[nt] = *(const h8_t*)(Vb + (size_t)((wn<<5) + (nt<<4) + l15)*1024 + (c<<7) + (k0<<5) + (quad<<3));
        #pragma unroll
        for (int mt = 0; mt < 2; mt++)
          #pragma unroll
          for (int nt = 0; nt < 2; nt++)
            pacc[mt][nt] = __builtin_amdgcn_mfma_f32_16x16x32_f16(af[mt], bf[nt], pacc[mt][nt], 0, 0, 0);
      }
    }
    #pragma unroll
    for (int mt = 0; mt < 2; mt++)
      #pragma unroll
      for (int nt = 0; nt < 2; nt++){
        int Cc = (wn<<5) + (nt<<4) + l15;
        #pragma unroll
        for (int i = 0; i < 4; i++){
          int R = bm + (mt<<4) + (quad<<2) + i;
          float v = pacc[mt][nt][i]*(1.0f/1024.0f);
          Cb[(size_t)R*2048 + Cc] = v;
          cmn = fminf(cmn, v); cmx = fmaxf(cmx, v);
        }
      }
  }
  __shared__ float red[256];
  float bmn = bred_min(cmn, red), bmx = bred_max(cmx, red);
  if (tid == 0){ atomicMin(&stats[36*16], f2o(bmn)); atomicMax(&stats[37*16], f2o(bmx)); }
}

// attn f32 expansion: uniform BW-bound. grid (chunk=8, group=32, z=32).
// Lane mapping: idx = it*256 + tid, row = idx>>5, col = (idx&31)<<2 ->
// 32 lanes x 16B = 512B contiguous per wave store (full-line coverage).
__global__ __launch_bounds__(256) void k_attn_expand(const unsigned short* __restrict__ q3buf,
                                                     float* __restrict__ attn,
                                                     const unsigned* __restrict__ rowmax,
                                                     const float* __restrict__ denomS,
                                                     const unsigned* stats){
  int c = blockIdx.x, r = blockIdx.y, z = blockIdx.z;
  int nch = (r >> 2) + 1;
  int tid = threadIdx.x;
  float* Cb = attn + ((size_t)z << 20) + ((size_t)(r << 5))*1024 + (c << 7);
  if (c >= nch){
    f4_t zz = {0.f,0.f,0.f,0.f};
    #pragma unroll
    for (int it = 0; it < 4; it++){
      int idx = (it << 8) + tid;           // 1024 f4 = 32 rows x 32 segs
      int row = idx >> 5, col = (idx & 31) << 2;
      __builtin_nontemporal_store(zz, (f4_t*)(Cb + (size_t)row*1024 + col));
    }
    return;
  }
  LogitQ L = derive_logit(stats);
  FQP p4 = fqp(0.0f, 1.0f/dec_slot(stats, 32));
  float zp3 = L.f3.zp, s3 = L.f3.scale;
  int aa = r >> 2, bb2 = r & 3;
  int cum = (aa + 1)*(2*aa + bb2);
  const unsigned short* Qu = q3buf + ((size_t)z*144 + cum + c)*4096;
  #pragma unroll
  for (int it = 0; it < 4; it++){
    int idx = (it << 8) + tid;
    int row = idx >> 5, col = (idx & 31) << 2;
    int grow = (z << 10) + (r << 5) + row;
    float m = chainU(o2f(rowmax[grow]), L);
    float rp = p4.inv/denomS[grow];
    u16x4 u = *(const u16x4*)(Qu + row*128 + col);
    f4_t v4;
    #pragma unroll
    for (int jj = 0; jj < 4; jj++){
      float a3 = ((float)u[jj] - zp3)*s3;
      float n = fminf(fmaxf(rintf(__expf(a3 - m)*rp), 0.0f), 65535.0f);
      v4[jj] = n*p4.scale;
    }
    __builtin_nontemporal_store(v4, (f4_t*)(Cb + (size_t)row*1024 + col));
  }
}

// ===========================================================================

// fq16(A) then per-128 rmsnorm; writes (B,NH,S,D) fp32; reduces full+half ranges
__global__ __launch_bounds__(256) void k_rms(const float* __restrict__ lin, float* __restrict__ buf,
                                             const float* __restrict__ gw, unsigned* stats,
                                             int slot_lin, int slot_out, int NHh, int rows){
  FQP pA = fqp(dec_slot(stats, slot_lin), dec_slot(stats, slot_lin+1));
  int lane = threadIdx.x & 63;
  int wv = (blockIdx.x*256 + threadIdx.x) >> 6;
  int nwv = (gridDim.x*256) >> 6;
  float w0 = gw[lane], w1 = gw[lane + 64];
  float fmn = FLT_MAX, fmx = -FLT_MAX, hmn = FLT_MAX, hmx = -FLT_MAX;
  for (int r = wv; r < rows; r += nwv){
    int h = r % NHh; int rem = r / NHh; int s2 = rem & 1023; int b = rem >> 10;
    const float* src = lin + (size_t)r*128;
    float x0 = fqa(src[lane], pA), x1 = fqa(src[lane + 64], pA);
    float ss = x0*x0 + x1*x1;
    #pragma unroll
    for (int m = 1; m < 64; m <<= 1) ss += __shfl_xor(ss, m, 64);
    float rr = 1.0f/sqrtf(ss*(1.0f/128.0f) + 1e-6f);
    float y0 = x0*rr*w0, y1 = x1*rr*w1;
    float* dst = buf + ((size_t)((b*NHh + h) << 10) + s2)*128;
    dst[lane] = y0; dst[lane + 64] = y1;
    fmn = fminf(fmn, fminf(y0, y1)); fmx = fmaxf(fmx, fmaxf(y0, y1));
    hmn = fminf(hmn, y1); hmx = fmaxf(hmx, y1);
  }
  __shared__ float red[256];
  float a = bred_min(fmn, red), bb = bred_max(fmx, red);
  float c = bred_min(hmn, red), d = bred_max(hmx, red);
  if (threadIdx.x == 0){
    atomicMin(&stats[slot_out*16], f2o(a));     atomicMax(&stats[(slot_out+1)*16], f2o(bb));
    atomicMin(&stats[(slot_out+2)*16], f2o(c)); atomicMax(&stats[(slot_out+3)*16], f2o(d));
  }
}

struct RopeQ { FQP B, C, E, F; };
__device__ RopeQ derive_rope(const unsigned* st, int base){
  float ymn = dec_slot(st, base),   ymx = dec_slot(st, base+1);
  float y2mn = dec_slot(st, base+2), y2mx = dec_slot(st, base+3);
  RopeQ r;
  r.B = fqp(ymn, ymx);
  float zmn = fqa(ymn, r.B), zmx = fqa(ymx, r.B);
  r.C = fqp(zmn, zmx);
  float zlo = fqa(zmn, r.C), zhi = fqa(zmx, r.C);
  float z2lo = fqa(fqa(y2mn, r.B), r.C), z2hi = fqa(fqa(y2mx, r.B), r.C);
  r.E = fqp(-z2hi, -z2lo);
  float nlo = fqa(-z2hi, r.E), nhi = fqa(-z2lo, r.E);
  r.F = fqp_raw(fminf(fminf(zlo, nlo), 0.0f), fmaxf(fmaxf(zhi, nhi), 0.0f));
  return r;
}

__global__ __launch_bounds__(256) void k_rope(float* __restrict__ buf, const float* __restrict__ cosp,
                                              const float* __restrict__ sinp, unsigned* stats,
                                              int slot_norm, int slot_prod, int slot_sum,
                                              int NHh, int rows, int do_write){
  RopeQ R = derive_rope(stats, slot_norm);
  FQP pD, pG;
  if (do_write){
    pD = fqp(dec_slot(stats, slot_prod),   dec_slot(stats, slot_prod+1));
    pG = fqp(dec_slot(stats, slot_prod+2), dec_slot(stats, slot_prod+3));
  }
  int lane = threadIdx.x & 63;
  int wv = (blockIdx.x*256 + threadIdx.x) >> 6, nwv = (gridDim.x*256) >> 6;
  float m0 = FLT_MAX, M0 = -FLT_MAX, m1 = FLT_MAX, M1 = -FLT_MAX;
  for (int r = wv; r < rows; r += nwv){
    int s2 = r & 1023; int bh = r >> 10; int b = bh/NHh;
    float* base = buf + (size_t)r*128;
    float y0 = base[lane], y1 = base[lane + 64];
    float z0 = fqa(fqa(y0, R.B), R.C), z1 = fqa(fqa(y1, R.B), R.C);
    const float* cr = cosp + (size_t)((b << 10) + s2)*128;
    const float* sr = sinp + (size_t)((b << 10) + s2)*128;
    float c0 = cr[lane], c1 = cr[lane + 64], sn0 = sr[lane], sn1 = sr[lane + 64];
    float pc0 = z0*c0, pc1 = z1*c1;
    float rh0 = fqa(fqa(-z1, R.E), R.F);
    float rh1 = fqa(z0, R.F);
    float ps0 = rh0*sn0, ps1 = rh1*sn1;
    if (!do_write){
      m0 = fminf(m0, fminf(pc0, pc1)); M0 = fmaxf(M0, fmaxf(pc0, pc1));
      m1 = fminf(m1, fminf(ps0, ps1)); M1 = fmaxf(M1, fmaxf(ps0, ps1));
    } else {
      float sv0 = fqa(pc0, pD) + fqa(ps0, pG);
      float sv1 = fqa(pc1, pD) + fqa(ps1, pG);
      base[lane] = sv0; base[lane + 64] = sv1;
      m0 = fminf(m0, fminf(sv0, sv1)); M0 = fmaxf(M0, fmaxf(sv0, sv1));
    }
  }
  __shared__ float red[256];
  if (!do_write){
    float a = bred_min(m0, red), bb = bred_max(M0, red);
    float c = bred_min(m1, red), d = bred_max(M1, red);
    if (threadIdx.x == 0){
      atomicMin(&stats[slot_prod*16], f2o(a));     atomicMax(&stats[(slot_prod+1)*16], f2o(bb));
      atomicMin(&stats[(slot_prod+2)*16], f2o(c)); atomicMax(&stats[(slot_prod+3)*16], f2o(d));
    }
  } else {
    float a = bred_min(m0, red), bb = bred_max(M0, red);
    if (threadIdx.x == 0){ atomicMin(&stats[slot_sum*16], f2o(a)); atomicMax(&stats[(slot_sum+1)*16], f2o(bb)); }
  }
}

// V transpose + fq8(fq16) -> f16: vT[b][kv][d][t]
__global__ __launch_bounds__(256) void k_vT(const float* __restrict__ vlin, _Float16* __restrict__ vT,
                                            const unsigned* stats){
  FQP pv = fqp(dec_slot(stats, 6), dec_slot(stats, 7));
  float vlo = fqa(dec_slot(stats, 6), pv), vhi = fqa(dec_slot(stats, 7), pv);
  float v8s = fmaxf(fmaxf(fabsf(vlo), fabsf(vhi))/127.0f, 1e-12f), v8si = 1.0f/v8s;
  __shared__ float tile[64][65];
  int bkv = blockIdx.z, t0 = blockIdx.x << 6, d0 = blockIdx.y << 6;
  int b = bkv >> 3, kv = bkv & 7;
  const float* src = vlin + ((size_t)(b << 10))*1024 + (size_t)kv*128;
  int tx = threadIdx.x & 63, tq = threadIdx.x >> 6;
  #pragma unroll
  for (int i = 0; i < 16; i++){
    int tt = (i << 2) + tq;
    float x = src[(size_t)(t0 + tt)*1024 + d0 + tx];
    tile[tx][tt] = fq8(fqa(x, pv), v8s, v8si);
  }
  __syncthreads();
  _Float16* dst = vT + (size_t)bkv*131072;
  #pragma unroll
  for (int i = 0; i < 16; i++){
    int dd = (i << 2) + tq;
    dst[(size_t)(d0 + dd)*1024 + t0 + tx] = (_Float16)tile[dd][tx];
  }
}

extern "C" void kernel_launch(void* const* d_in, const int* in_sizes, int n_in,
                              void* d_out, int out_size, void* d_ws, size_t ws_size,
                              hipStream_t stream){
  (void)in_sizes; (void)n_in; (void)out_size; (void)ws_size;
  const float* hs   = (const float*)d_in[0];
  const float* cosp = (const float*)d_in[1];
  const float* sinp = (const float*)d_in[2];
  const float* Wq   = (const float*)d_in[4];
  const float* Wk   = (const float*)d_in[5];
  const float* Wv   = (const float*)d_in[6];
  const float* Wo   = (const float*)d_in[7];
  const float* qnw  = (const float*)d_in[8];
  const float* knw  = (const float*)d_in[9];

  float* outp = (float*)d_out;
  float* attn = outp + 4194304;      // final quantized softmax

  const size_t MEG = 1u << 20;       // floats
  float* wsf = (float*)d_ws;
  _Float16* woq_h = (_Float16*)(wsf + 0);
  _Float16* wqq_h = (_Float16*)(wsf + 2*MEG);
  _Float16* wkq_h = (_Float16*)(wsf + 4*MEG);
  _Float16* wvq_h = (_Float16*)(wsf + 5*MEG);
  _Float16* hsq_h = (_Float16*)(wsf + 6*MEG);
  float* qlin = wsf + 8*MEG;  float* ctx = qlin;   // ctx reuses qlin
  float* klin = wsf + 12*MEG;
  float* vlin = wsf + 14*MEG;
  float* qbuf = wsf + 16*MEG;
  float* kbuf = wsf + 20*MEG;
  _Float16* q_h   = (_Float16*)(wsf + 22*MEG);
  _Float16* k_h   = (_Float16*)(wsf + 24*MEG);
  _Float16* vT_h  = (_Float16*)(wsf + 25*MEG);
  _Float16* ctx_h = (_Float16*)(wsf + 26*MEG);
  unsigned* rowmin = (unsigned*)(wsf + 28*MEG);
  unsigned* rowmax = (unsigned*)(wsf + 28*MEG + 32768);
  float* denomS = wsf + 28*MEG + 65536;
  unsigned* stats = (unsigned*)(wsf + 28*MEG + 98304);
  // q3 levels: 32 z * 144 units * 4096 u16 = 36 MB. Overlays klin/vlin/qbuf/
  // kbuf (wsf+12M..21M floats) -- all dead before k_qk_denom writes it.
  unsigned short* q3buf = (unsigned short*)(wsf + 12*MEG);

  k_init<<<4, 256, 0, stream>>>(stats);

  k_quantw4<<<12288, 256, 0, stream>>>(Wq, Wk, Wv, Wo, wqq_h, wkq_h, wvq_h, woq_h);

  k_minmax<<<1024, 256, 0, stream>>>(hs, 4194304, stats, 0);
  k_fq_ew16<<<4096, 256, 0, stream>>>(hs, hsq_h, stats, 0);

  // fused Q/K/V projections (512 blocks -> 2 blocks/CU), raw-range stats fused
  k_hgemm_qkv<<<dim3(8, 16, 4), 256, 0, stream>>>(hsq_h, wqq_h, wkq_h, wvq_h,
                                                  qlin, klin, vlin, 2048, stats);

  // fq16 + rmsnorm (fp32) + range reductions
  k_rms<<<1024, 256, 0, stream>>>(qlin, qbuf, qnw, stats, 2, 8, 16, 32768);
  k_rms<<<512, 256, 0, stream>>>(klin, kbuf, knw, stats, 4, 12, 8, 16384);

  // RoPE: range pass then write pass
  k_rope<<<1024, 256, 0, stream>>>(qbuf, cosp, sinp, stats, 8, 16, 24, 16, 32768, 0);
  k_rope<<<512, 256, 0, stream>>>(kbuf, cosp, sinp, stats, 12, 20, 26, 8, 16384, 0);
  k_rope<<<1024, 256, 0, stream>>>(qbuf, cosp, sinp, stats, 8, 16, 24, 16, 32768, 1);
  k_rope<<<512, 256, 0, stream>>>(kbuf, cosp, sinp, stats, 12, 20, 26, 8, 16384, 1);

  // operand conversion for QK and V transpose
  k_fq_ew16<<<4096, 256, 0, stream>>>(qbuf, q_h, stats, 24);
  k_fq8_ew16<<<2048, 256, 0, stream>>>(kbuf, k_h, stats, 26);
  k_vT<<<dim3(16, 2, 16), 256, 0, stream>>>(vlin, vT_h, stats);

  // attention: stats (full sweep) -> denom (+q3 store) -> pv (dequant-GEMM)
  // -> expand (attn f32 write). denom/pv paired (j, 31-j) = 9 units/block.
  k_qk_stats<<<dim3(32, 32), 256, 0, stream>>>(q_h, k_h, stats, rowmin, rowmax);
  k_rowstat_m2<<<8, 256, 0, stream>>>(rowmin, stats, 32768);
  k_qk_denom<<<dim3(16, 32), 256, 0, stream>>>(q_h, k_h, rowmin, rowmax, denomS, q3buf, stats);
  k_denom_min<<<8, 256, 0, stream>>>(denomS, stats, 32768);
  k_qk_pv<<<dim3(16, 32), 256, 0, stream>>>(q3buf, vT_h, ctx, rowmax, denomS, stats);
  k_attn_expand<<<dim3(8, 32, 32), 256, 0, stream>>>(q3buf, attn, rowmax, denomS, stats);

  // ctx (stats fused in PV) -> f16 -> O-proj
  k_fq_ew16<<<4096, 256, 0, stream>>>(ctx, ctx_h, stats, 36);
  k_hgemm_f<<<dim3(16, 16), 256, 0, stream>>>(ctx_h, woq_h, outp, 2048, 2048, stats, -1);
}

// Round 7
// 595.300 us; speedup vs baseline: 1.4098x; 1.0798x over previous
//
#include <hip/hip_runtime.h>
#include <cfloat>
#include <cmath>

// ---------------------------------------------------------------------------
// Qwen3Attention fake-quant forward. B=2 S=1024 HID=2048 NH=16 NKV=8 D=128.
// Round 13: (a) O-proj 128x64 tiles -> 512 blocks = 2 blocks/CU (staging
// drain overlapped, same per-element MFMA chain -> bit-exact); (b) stats
// pass keeps only per-row accumulators (rmv/rxa/rxv), global mn/mx/mxU
// derived in epilogue (min/max order-free -> bit-exact), 6 -> 4 VALU/elem;
// (c) rope q+k merged per pass (grid 1536), q/k operand fq merged (6144).
// ---------------------------------------------------------------------------

#define FQ_EPS      1.5259021896696422e-09f   // 0.0001/65535
#define SCALING_F   0.08838834764831845f      // 128**-0.5
#define S_LEN       1024

typedef _Float16 h8_t __attribute__((ext_vector_type(8)));
typedef _Float16 h4_t __attribute__((ext_vector_type(4)));
typedef float    f4_t __attribute__((ext_vector_type(4)));
typedef unsigned short u16x4 __attribute__((ext_vector_type(4)));

// ---- float <-> order-preserving unsigned encoding (for atomic min/max) ----
__device__ __forceinline__ unsigned f2o(float f){
  unsigned u = __float_as_uint(f);
  return (u & 0x80000000u) ? ~u : (u | 0x80000000u);
}
__device__ __forceinline__ float o2f(unsigned u){
  return __uint_as_float((u & 0x80000000u) ? (u ^ 0x80000000u) : ~u);
}
__device__ __forceinline__ float dec_slot(const unsigned* st, int s){ return o2f(st[s*16]); }

// ---- fq16 helpers ----
struct FQP { float scale, zp, inv; };
__device__ __forceinline__ FQP fqp_raw(float mn, float mx){
  FQP p; p.scale = fmaxf((mx - mn)/65535.0f, FQ_EPS); p.zp = rintf(-mn/p.scale);
  p.inv = 1.0f/p.scale; return p;
}
__device__ __forceinline__ FQP fqp(float mn0, float mx0){
  return fqp_raw(fminf(mn0, 0.0f), fmaxf(mx0, 0.0f));
}
__device__ __forceinline__ float fqa(float x, FQP p){
  float q = rintf(x*p.inv) + p.zp;
  q = fminf(fmaxf(q, 0.0f), 65535.0f);
  return (q - p.zp)*p.scale;
}
__device__ __forceinline__ float fq8(float x, float s, float si){
  return fminf(fmaxf(rintf(x*si), -128.0f), 127.0f)*s;
}

// ---- block reductions (blockDim == 256) ----
__device__ __forceinline__ float bred_min(float v, float* red){
  int tid = threadIdx.x; red[tid] = v; __syncthreads();
  for (int s = 128; s > 0; s >>= 1){ if (tid < s) red[tid] = fminf(red[tid], red[tid+s]); __syncthreads(); }
  float r = red[0]; __syncthreads(); return r;
}
__device__ __forceinline__ float bred_max(float v, float* red){
  int tid = threadIdx.x; red[tid] = v; __syncthreads();
  for (int s = 128; s > 0; s >>= 1){ if (tid < s) red[tid] = fmaxf(red[tid], red[tid+s]); __syncthreads(); }
  float r = red[0]; __syncthreads(); return r;
}

// ---- stats slot map (even=min, odd=max) ----
// 0/1 hs | 2/3 qlin | 4/5 klin | 6/7 vlin | 8/9 qn | 10/11 qn2 | 12/13 kn | 14/15 kn2
// 16/17 q*c | 18/19 qrh*s | 20/21 k*c | 22/23 krh*s | 24/25 qsum | 26/27 ksum
// 28/29 logits | 31 unmaskedMax | 32 denomMin | 35 maxOfRowMins | 36/37 ctx

__global__ void k_init(unsigned* stats){
  int i = blockIdx.x*blockDim.x + threadIdx.x;
  if (i < 1024) stats[i] = (((i & 15) == 0) && (((i >> 4) & 1) == 0)) ? 0xFFFFFFFFu : 0u;
}

// lpbq weight quantization -> f16, all four weights in one launch.
// 4 elems/thread; 8-lane shfl = 32-elem block.
__global__ __launch_bounds__(256) void k_quantw4(const float* __restrict__ Wq, const float* __restrict__ Wk,
                                                 const float* __restrict__ Wv, const float* __restrict__ Wo,
                                                 _Float16* __restrict__ Qh, _Float16* __restrict__ Kh,
                                                 _Float16* __restrict__ Vh, _Float16* __restrict__ Oh){
  int bx = blockIdx.x;
  const float* W; _Float16* Wh; int base;
  if (bx < 4096){ W = Wq; Wh = Qh; base = 0; }
  else if (bx < 6144){ W = Wk; Wh = Kh; base = 4096; }
  else if (bx < 8192){ W = Wv; Wh = Vh; base = 6144; }
  else { W = Wo; Wh = Oh; base = 8192; }
  int i = (bx - base)*256 + threadIdx.x;
  float4 v = ((const float4*)W)[i];
  float am = fmaxf(fmaxf(fabsf(v.x), fabsf(v.y)), fmaxf(fabsf(v.z), fabsf(v.w)));
  #pragma unroll
  for (int m = 1; m < 8; m <<= 1) am = fmaxf(am, __shfl_xor(am, m, 64));
  float s = fmaxf(am/7.0f, 1e-12f), si = 1.0f/s;
  h4_t o;
  o[0] = (_Float16)(fminf(fmaxf(rintf(v.x*si), -8.0f), 7.0f)*s);
  o[1] = (_Float16)(fminf(fmaxf(rintf(v.y*si), -8.0f), 7.0f)*s);
  o[2] = (_Float16)(fminf(fmaxf(rintf(v.z*si), -8.0f), 7.0f)*s);
  o[3] = (_Float16)(fminf(fmaxf(rintf(v.w*si), -8.0f), 7.0f)*s);
  *(h4_t*)(Wh + ((size_t)i << 2)) = o;
}

__global__ __launch_bounds__(256) void k_minmax(const float* __restrict__ x, int n, unsigned* stats, int slot){
  float mn = FLT_MAX, mx = -FLT_MAX;
  for (int i = blockIdx.x*256 + threadIdx.x; i < n; i += gridDim.x*256){
    float v = x[i]; mn = fminf(mn, v); mx = fmaxf(mx, v);
  }
  __shared__ float red[256];
  float bmn = bred_min(mn, red), bmx = bred_max(mx, red);
  if (threadIdx.x == 0){ atomicMin(&stats[slot*16], f2o(bmn)); atomicMax(&stats[(slot+1)*16], f2o(bmx)); }
}

// fq16 elementwise -> f16, 4 elems/thread (used for hs and ctx)
__global__ __launch_bounds__(256) void k_fq_ew16(const float* __restrict__ x, _Float16* __restrict__ y,
                                                 const unsigned* stats, int slot){
  FQP p = fqp(dec_slot(stats, slot), dec_slot(stats, slot+1));
  int i = blockIdx.x*256 + threadIdx.x;
  float4 v = ((const float4*)x)[i];
  h4_t o;
  o[0] = (_Float16)fqa(v.x, p); o[1] = (_Float16)fqa(v.y, p);
  o[2] = (_Float16)fqa(v.z, p); o[3] = (_Float16)fqa(v.w, p);
  *(h4_t*)(y + ((size_t)i << 2)) = o;
}

// merged q/k operand conversion: blocks [0,4096) -> fq16(qbuf)->q_h (slot 24),
// blocks [4096,6144) -> fq8(fq16(kbuf))->k_h (slot 26)
__global__ __launch_bounds__(256) void k_fq_qk(const float* __restrict__ qbuf, const float* __restrict__ kbuf,
                                               _Float16* __restrict__ q_h, _Float16* __restrict__ k_h,
                                               const unsigned* stats){
  int bx = blockIdx.x;
  if (bx < 4096){
    FQP p = fqp(dec_slot(stats, 24), dec_slot(stats, 25));
    int i = bx*256 + threadIdx.x;
    float4 v = ((const float4*)qbuf)[i];
    h4_t o;
    o[0] = (_Float16)fqa(v.x, p); o[1] = (_Float16)fqa(v.y, p);
    o[2] = (_Float16)fqa(v.z, p); o[3] = (_Float16)fqa(v.w, p);
    *(h4_t*)(q_h + ((size_t)i << 2)) = o;
  } else {
    FQP p = fqp(dec_slot(stats, 26), dec_slot(stats, 27));
    float lo = fqa(dec_slot(stats, 26), p), hi = fqa(dec_slot(stats, 27), p);
    float s8 = fmaxf(fmaxf(fabsf(lo), fabsf(hi))/127.0f, 1e-12f), s8i = 1.0f/s8;
    int i = (bx - 4096)*256 + threadIdx.x;
    float4 v = ((const float4*)kbuf)[i];
    h4_t o;
    o[0] = (_Float16)fq8(fqa(v.x, p), s8, s8i); o[1] = (_Float16)fq8(fqa(v.y, p), s8, s8i);
    o[2] = (_Float16)fq8(fqa(v.z, p), s8, s8i); o[3] = (_Float16)fq8(fqa(v.w, p), s8, s8i);
    *(h4_t*)(k_h + ((size_t)i << 2)) = o;
  }
}

// ================= f16 MFMA GEMM core for projections (NT) =================
// async staging: LDS dest is wave-uniform base + lane*16B (constraint-safe).
#define GLDS16(g, l) __builtin_amdgcn_global_load_lds( \
    (__attribute__((address_space(1))) unsigned int*)(g), \
    (__attribute__((address_space(3))) unsigned int*)(l), 16, 0, 0)

__device__ __forceinline__ void stage_tile(const _Float16* __restrict__ src, int ld, int k0,
                                           _Float16* __restrict__ dst){
  #pragma unroll
  for (int it = 0; it < 2; it++){
    int c = threadIdx.x + (it << 8);
    int row = c >> 2, off = (c & 3) << 3;
    GLDS16(src + (size_t)row*ld + k0 + off, dst + (c << 3));
  }
}

__device__ __forceinline__ void hgemm_main(const _Float16* __restrict__ A, int lda,
                                           const _Float16* __restrict__ B, int ldb, int K,
                                           f4_t acc[4][4], _Float16* As, _Float16* Bs){
  int lane = threadIdx.x & 63, wave = threadIdx.x >> 6;
  int wm = wave & 1, wn = wave >> 1, quad = lane >> 4, l15 = lane & 15;
  for (int k0 = 0; k0 < K; k0 += 32){
    __syncthreads();
    stage_tile(A, lda, k0, As);
    stage_tile(B, ldb, k0, Bs);
    __syncthreads();
    h8_t af[4], bf[4];
    #pragma unroll
    for (int mt = 0; mt < 4; mt++)
      af[mt] = *(const h8_t*)(As + ((((wm<<6) + (mt<<4) + l15)) << 5) + (quad << 3));
    #pragma unroll
    for (int nt = 0; nt < 4; nt++)
      bf[nt] = *(const h8_t*)(Bs + ((((wn<<6) + (nt<<4) + l15)) << 5) + (quad << 3));
    #pragma unroll
    for (int mt = 0; mt < 4; mt++)
      #pragma unroll
      for (int nt = 0; nt < 4; nt++)
        acc[mt][nt] = __builtin_amdgcn_mfma_f32_16x16x32_f16(af[mt], bf[nt], acc[mt][nt], 0, 0, 0);
  }
}

#define HG_PROLOG  \
  __shared__ __align__(16) _Float16 As[4096], Bs[4096]; \
  __shared__ float red[256]; \
  f4_t acc[4][4]; \
  { f4_t zz = {0.f,0.f,0.f,0.f}; \
    for (int i=0;i<4;i++) for (int j=0;j<4;j++) acc[i][j] = zz; } \
  int lane = threadIdx.x & 63, wave = threadIdx.x >> 6; \
  int wm = wave & 1, wn = wave >> 1, quad = lane >> 4, l15 = lane & 15; (void)red; (void)lane;

// C/D lane map (m89-verified): D[row=(quad*4+reg)][col=l15].

// fused Q/K/V projections: z=0,1 -> Q col-halves (slot 2), z=2 -> K (slot 4),
// z=3 -> V (slot 6). 512 blocks -> 2 blocks/CU -> 8 waves/CU.
__global__ __launch_bounds__(256) void k_hgemm_qkv(const _Float16* __restrict__ A,
                                                   const _Float16* __restrict__ Bq,
                                                   const _Float16* __restrict__ Bk,
                                                   const _Float16* __restrict__ Bv,
                                                   float* __restrict__ Cq, float* __restrict__ Ck,
                                                   float* __restrict__ Cv,
                                                   int K, unsigned* stats){
  HG_PROLOG
  int z = blockIdx.z;
  const _Float16* Bmat; float* C; int slotC, N, cbase;
  if (z < 2){ Bmat = Bq + (((size_t)z << 10))*K; C = Cq; slotC = 2; N = 2048; cbase = z << 10; }
  else if (z == 2){ Bmat = Bk; C = Ck; slotC = 4; N = 1024; cbase = 0; }
  else { Bmat = Bv; C = Cv; slotC = 6; N = 1024; cbase = 0; }
  int bm = blockIdx.y << 7, bn = blockIdx.x << 7;
  hgemm_main(A + (size_t)bm*K, K, Bmat + (size_t)bn*K, K, K, acc, As, Bs);
  float mn = FLT_MAX, mx = -FLT_MAX;
  #pragma unroll
  for (int mt = 0; mt < 4; mt++)
    #pragma unroll
    for (int nt = 0; nt < 4; nt++){
      int Cc = cbase + bn + (wn<<6) + (nt<<4) + l15;
      #pragma unroll
      for (int i = 0; i < 4; i++){
        int R = bm + (wm<<6) + (mt<<4) + (quad<<2) + i;
        float v = acc[mt][nt][i];
        C[(size_t)R*N + Cc] = v;
        mn = fminf(mn, v); mx = fmaxf(mx, v);
      }
    }
  float bmn = bred_min(mn, red), bmx = bred_max(mx, red);
  if (threadIdx.x == 0){ atomicMin(&stats[slotC*16], f2o(bmn)); atomicMax(&stats[(slotC+1)*16], f2o(bmx)); }
}

// O-proj: 128x64 tiles, grid (32,16) = 512 blocks = 2 blocks/CU.
// Per-element MFMA k-chain identical to the 128x128 version -> bit-exact.
// Wave wm = row-half (64 rows), wn = col-half (32 cols): acc[4][2].
__global__ __launch_bounds__(256) void k_hgemm_o(const _Float16* __restrict__ A,
                                                 const _Float16* __restrict__ B,
                                                 float* __restrict__ C){
  __shared__ __align__(16) _Float16 As[4096], Bs[2048];
  f4_t acc[4][2];
  { f4_t zz = {0.f,0.f,0.f,0.f};
    for (int i = 0; i < 4; i++) for (int j = 0; j < 2; j++) acc[i][j] = zz; }
  int lane = threadIdx.x & 63, wave = threadIdx.x >> 6;
  int wm = wave & 1, wn = wave >> 1, quad = lane >> 4, l15 = lane & 15;
  int bm = blockIdx.y << 7, bn = blockIdx.x << 6;
  const _Float16* Ab = A + (size_t)bm*2048;
  const _Float16* Bb = B + (size_t)bn*2048;
  for (int k0 = 0; k0 < 2048; k0 += 32){
    __syncthreads();
    stage_tile(Ab, 2048, k0, As);
    { int c = threadIdx.x;                       // 64 rows x 32 k = 4 KB, one shot
      int row = c >> 2, off = (c & 3) << 3;
      GLDS16(Bb + (size_t)row*2048 + k0 + off, Bs + (c << 3)); }
    __syncthreads();
    h8_t af[4], bf[2];
    #pragma unroll
    for (int mt = 0; mt < 4; mt++)
      af[mt] = *(const h8_t*)(As + ((((wm<<6) + (mt<<4) + l15)) << 5) + (quad << 3));
    #pragma unroll
    for (int nt = 0; nt < 2; nt++)
      bf[nt] = *(const h8_t*)(Bs + ((((wn<<5) + (nt<<4) + l15)) << 5) + (quad << 3));
    #pragma unroll
    for (int mt = 0; mt < 4; mt++)
      #pragma unroll
      for (int nt = 0; nt < 2; nt++)
        acc[mt][nt] = __builtin_amdgcn_mfma_f32_16x16x32_f16(af[mt], bf[nt], acc[mt][nt], 0, 0, 0);
  }
  #pragma unroll
  for (int mt = 0; mt < 4; mt++)
    #pragma unroll
    for (int nt = 0; nt < 2; nt++){
      int Cc = bn + (wn<<5) + (nt<<4) + l15;
      #pragma unroll
      for (int i = 0; i < 4; i++){
        int R = bm + (wm<<6) + (mt<<4) + (quad<<2) + i;
        C[(size_t)R*2048 + Cc] = acc[mt][nt][i];
      }
    }
}

// ====================== QK^T attention passes (32-row) =====================
// block = 256 thr (4 waves). A 32-row group r (0..31) covers q-rows
// [32r, 32r+32); it needs nch(r) = (r>>2)+1 K-chunks of 128. Wave wn owns
// cols [32*wn, 32*wn+32): acc[2][2]. Pairing (j, 31-j) -> constant 9
// chunk-units per block. q3 levels (post-f3 u16) are exact -> stored once by
// denom, consumed by pv (PV GEMM) and expand (attn f32 write) bit-exactly.
// causal unit index: cum(r) = (a+1)*(2a+b), a=r>>2, b=r&3; unit = cum + chunk.

#define QK_IDS \
  int lane = threadIdx.x & 63, wn = threadIdx.x >> 6; \
  int quad = lane >> 4, l15 = lane & 15; \
  int tid = threadIdx.x; (void)tid; (void)lane;

__device__ __forceinline__ void qk_load_a(const _Float16* __restrict__ Ab, int quad, int l15,
                                          h8_t Aq[2][4]){
  #pragma unroll
  for (int mt = 0; mt < 2; mt++)
    #pragma unroll
    for (int k0 = 0; k0 < 4; k0++)
      Aq[mt][k0] = *(const h8_t*)(Ab + (size_t)((mt<<4) + l15)*128 + (k0<<5) + (quad<<3));
}

__device__ __forceinline__ void qk_chunk32(const h8_t Aq[2][4], const _Float16* __restrict__ Kb,
                                           int bn, int wn, int quad, int l15, f4_t acc[2][2]){
  #pragma unroll
  for (int k0 = 0; k0 < 4; k0++){
    h8_t bf[2];
    #pragma unroll
    for (int nt = 0; nt < 2; nt++)
      bf[nt] = *(const h8_t*)(Kb + (size_t)(bn + (wn<<5) + (nt<<4) + l15)*128 + (k0<<5) + (quad<<3));
    #pragma unroll
    for (int mt = 0; mt < 2; mt++)
      #pragma unroll
      for (int nt = 0; nt < 2; nt++)
        acc[mt][nt] = __builtin_amdgcn_mfma_f32_16x16x32_f16(Aq[mt][k0], bf[nt], acc[mt][nt], 0, 0, 0);
  }
}

// pass 1: per-row min (full), max (full), max (causal) accumulators only;
// global mn/mx/mxU derived in epilogue (min/max are order-free -> bit-exact).
// 32-row groups, grid (32, 32).
__global__ __launch_bounds__(256) void k_qk_stats(const _Float16* __restrict__ q_h, const _Float16* __restrict__ k_h,
                                                  unsigned* stats, unsigned* rowmin, unsigned* rowmax){
  QK_IDS
  int bm = blockIdx.x << 5, z = blockIdx.y;
  int b = z >> 4, h = z & 15;
  const _Float16* Ab = q_h + (size_t)z*131072 + (size_t)bm*128;
  const _Float16* Kb = k_h + (size_t)(b*8 + (h>>1))*131072;
  h8_t Aq[2][4];
  qk_load_a(Ab, quad, l15, Aq);
  float rmv[2][4], rxa[2][4], rxv[2][4];
  #pragma unroll
  for (int mt = 0; mt < 2; mt++)
    #pragma unroll
    for (int i = 0; i < 4; i++){ rmv[mt][i] = FLT_MAX; rxa[mt][i] = -FLT_MAX; rxv[mt][i] = -FLT_MAX; }
  for (int bn = 0; bn < 1024; bn += 128){
    f4_t acc[2][2];
    { f4_t zz = {0.f,0.f,0.f,0.f}; for (int i=0;i<2;i++) for (int j=0;j<2;j++) acc[i][j]=zz; }
    qk_chunk32(Aq, Kb, bn, wn, quad, l15, acc);
    #pragma unroll
    for (int mt = 0; mt < 2; mt++){
      int rb = bm + (mt<<4) + (quad<<2);
      #pragma unroll
      for (int nt = 0; nt < 2; nt++){
        int t = bn + (wn<<5) + (nt<<4) + l15;
        #pragma unroll
        for (int i = 0; i < 4; i++){
          float v = acc[mt][nt][i];
          rmv[mt][i] = fminf(rmv[mt][i], v);
          rxa[mt][i] = fmaxf(rxa[mt][i], v);
          if (t <= rb + i) rxv[mt][i] = fmaxf(rxv[mt][i], v);
        }
      }
    }
  }
  #pragma unroll
  for (int d = 1; d < 16; d <<= 1)
    #pragma unroll
    for (int mt = 0; mt < 2; mt++)
      #pragma unroll
      for (int i = 0; i < 4; i++){
        rmv[mt][i] = fminf(rmv[mt][i], __shfl_xor(rmv[mt][i], d, 64));
        rxa[mt][i] = fmaxf(rxa[mt][i], __shfl_xor(rxa[mt][i], d, 64));
        rxv[mt][i] = fmaxf(rxv[mt][i], __shfl_xor(rxv[mt][i], d, 64));
      }
  __shared__ float rminS[4][32], rmaxS[4][32];
  if (l15 == 0){
    #pragma unroll
    for (int mt = 0; mt < 2; mt++)
      #pragma unroll
      for (int i = 0; i < 4; i++){
        int rl = (mt<<4) + (quad<<2) + i;
        rminS[wn][rl] = rmv[mt][i];
        rmaxS[wn][rl] = rxv[mt][i];
      }
  }
  __syncthreads();
  if (tid < 32){
    float a = fminf(fminf(rminS[0][tid], rminS[1][tid]), fminf(rminS[2][tid], rminS[3][tid]));
    float c = fmaxf(fmaxf(rmaxS[0][tid], rmaxS[1][tid]), fmaxf(rmaxS[2][tid], rmaxS[3][tid]));
    rowmin[(z << 10) + bm + tid] = f2o(a);
    rowmax[(z << 10) + bm + tid] = f2o(c);
  }
  float mn = FLT_MAX, mx = -FLT_MAX, mxU = -FLT_MAX;
  #pragma unroll
  for (int mt = 0; mt < 2; mt++)
    #pragma unroll
    for (int i = 0; i < 4; i++){
      mn = fminf(mn, rmv[mt][i]);
      mx = fmaxf(mx, rxa[mt][i]);
      mxU = fmaxf(mxU, rxv[mt][i]);
    }
  __shared__ float red[256];
  float bmn = bred_min(mn, red), bmx = bred_max(mx, red), bmU = bred_max(mxU, red);
  if (tid == 0){
    atomicMin(&stats[28*16], f2o(bmn));
    atomicMax(&stats[29*16], f2o(bmx));
    atomicMax(&stats[31*16], f2o(bmU));
  }
}

__global__ __launch_bounds__(256) void k_rowstat_m2(const unsigned* __restrict__ rowmin, unsigned* stats, int n){
  float lm = -FLT_MAX;
  for (int i = blockIdx.x*256 + threadIdx.x; i < n; i += gridDim.x*256) lm = fmaxf(lm, o2f(rowmin[i]));
  __shared__ float red[256];
  float m = bred_max(lm, red);
  if (threadIdx.x == 0) atomicMax(&stats[35*16], f2o(m));
}
__global__ __launch_bounds__(256) void k_denom_min(const float* __restrict__ denomS, unsigned* stats, int n){
  float lm = FLT_MAX;
  for (int i = blockIdx.x*256 + threadIdx.x; i < n; i += gridDim.x*256) lm = fminf(lm, denomS[i]);
  __shared__ float red[256];
  float m = -bred_max(-lm, red);
  if (threadIdx.x == 0) atomicMin(&stats[32*16], f2o(m));
}

struct LogitQ { FQP f1, f2, fam, fvv, f3; float sc, c20; };
__device__ LogitQ derive_logit(const unsigned* st){
  LogitQ L;
  FQP ps = fqp(SCALING_F, SCALING_F); L.sc = fqa(SCALING_F, ps);
  FQP p20 = fqp(-20.0f, -20.0f);      L.c20 = fqa(-20.0f, p20);
  float gmn = dec_slot(st, 28), gmx = dec_slot(st, 29);
  float gU = dec_slot(st, 31), M2 = dec_slot(st, 35);
  L.f1 = fqp(gmn, gmx);
  float l1lo = fqa(gmn, L.f1), l1hi = fqa(gmx, L.f1);
  L.f2 = fqp(l1lo*L.sc, l1hi*L.sc);
  float amlo = fqa(fqa(gmn, L.f1)*L.sc, L.f2);
  float amhi = fqa(fqa(M2, L.f1)*L.sc, L.f2);
  L.fam = fqp(amlo, amhi);
  float vslo = fqa(amlo, L.fam) + L.c20, vshi = fqa(amhi, L.fam) + L.c20;
  L.fvv = fqp(vslo, vshi);
  float mn3 = fqa(vslo, L.fvv);
  float mx3 = fqa(fqa(gU, L.f1)*L.sc, L.f2);
  L.f3 = fqp(mn3, mx3);
  return L;
}
__device__ __forceinline__ float chainU(float raw, const LogitQ& L){
  return fqa(fqa(fqa(raw, L.f1)*L.sc, L.f2), L.f3);
}

// pass 2: per-row denominators + q3-level store (u16, causal-packed).
// Paired 32-row groups (j, 31-j) = 9 units/block. Skipped masked chunks
// contribute count*exp(vv-m) per row analytically.
__global__ __launch_bounds__(256) void k_qk_denom(const _Float16* __restrict__ q_h, const _Float16* __restrict__ k_h,
                                                  const unsigned* __restrict__ rowmin,
                                                  const unsigned* __restrict__ rowmax,
                                                  float* __restrict__ denomS,
                                                  unsigned short* __restrict__ q3buf,
                                                  const unsigned* stats){
  QK_IDS
  int j = blockIdx.x, z = blockIdx.y;
  int b = z >> 4, h = z & 15;
  LogitQ L = derive_logit(stats);
  const _Float16* Kb = k_h + (size_t)(b*8 + (h>>1))*131072;
  __shared__ float mRow[32], vvRow[32], vvLev[32];
  __shared__ float dS[4][32];
  for (int g = 0; g < 2; g++){
    int r = g ? (31 - j) : j;
    int bm = r << 5;
    int nch = (r >> 2) + 1;
    int cstar = (r >> 2) << 7;          // diagonal-chunk base
    int aa = r >> 2, bb2 = r & 3;
    int cum = (aa + 1)*(2*aa + bb2);    // causal units before group r
    unsigned short* Qu = q3buf + ((size_t)z*144 + cum)*4096;
    __syncthreads();                    // prior group done with mRow/vvRow/dS
    if (tid < 32){
      int row = (z << 10) + bm + tid;
      mRow[tid] = chainU(o2f(rowmax[row]), L);
      float tr = fqa(fqa(o2f(rowmin[row]), L.f1)*L.sc, L.f2);
      float w = fqa(fqa(tr, L.fam) + L.c20, L.fvv);
      float lv = fminf(fmaxf(rintf(w*L.f3.inv) + L.f3.zp, 0.0f), 65535.0f);
      vvLev[tid] = lv;
      vvRow[tid] = (lv - L.f3.zp)*L.f3.scale;   // == fqa(w, f3)
    }
    const _Float16* Ab = q_h + (size_t)z*131072 + (size_t)bm*128;
    h8_t Aq[2][4];
    qk_load_a(Ab, quad, l15, Aq);
    __syncthreads();                    // mRow/vvRow/vvLev visible
    float rs[2][4];
    #pragma unroll
    for (int mt = 0; mt < 2; mt++)
      #pragma unroll
      for (int i = 0; i < 4; i++) rs[mt][i] = 0.0f;
    for (int bn = 0; bn < (nch << 7); bn += 128){
      f4_t acc[2][2];
      { f4_t zz = {0.f,0.f,0.f,0.f}; for (int i=0;i<2;i++) for (int jj=0;jj<2;jj++) acc[i][jj]=zz; }
      qk_chunk32(Aq, Kb, bn, wn, quad, l15, acc);
      unsigned short* Qc = Qu + (size_t)(bn >> 7)*4096;
      if (bn < cstar){
        // fully unmasked chunk: no causal select
        #pragma unroll
        for (int mt = 0; mt < 2; mt++){
          #pragma unroll
          for (int nt = 0; nt < 2; nt++){
            int cl = (wn<<5) + (nt<<4) + l15;
            #pragma unroll
            for (int i = 0; i < 4; i++){
              int rl = (mt<<4) + (quad<<2) + i;
              float a2 = fqa(fqa(acc[mt][nt][i], L.f1)*L.sc, L.f2);
              float lvl = fminf(fmaxf(rintf(a2*L.f3.inv) + L.f3.zp, 0.0f), 65535.0f);
              Qc[rl*128 + cl] = (unsigned short)lvl;
              float a3 = (lvl - L.f3.zp)*L.f3.scale;   // == fqa(a2, f3)
              rs[mt][i] += __expf(a3 - mRow[rl]);
            }
          }
        }
      } else {
        // diagonal (mixed) chunk: per-element causal select on the LEVEL
        #pragma unroll
        for (int mt = 0; mt < 2; mt++){
          #pragma unroll
          for (int nt = 0; nt < 2; nt++){
            int cl = (wn<<5) + (nt<<4) + l15;
            int t = bn + cl;
            #pragma unroll
            for (int i = 0; i < 4; i++){
              int rl = (mt<<4) + (quad<<2) + i;
              float a2 = fqa(fqa(acc[mt][nt][i], L.f1)*L.sc, L.f2);
              float lvl = fminf(fmaxf(rintf(a2*L.f3.inv) + L.f3.zp, 0.0f), 65535.0f);
              float qs = (t <= bm + rl) ? lvl : vvLev[rl];
              Qc[rl*128 + cl] = (unsigned short)qs;
              float a3 = (qs - L.f3.zp)*L.f3.scale;
              rs[mt][i] += __expf(a3 - mRow[rl]);
            }
          }
        }
      }
    }
    #pragma unroll
    for (int d = 1; d < 16; d <<= 1)
      #pragma unroll
      for (int mt = 0; mt < 2; mt++)
        #pragma unroll
        for (int i = 0; i < 4; i++) rs[mt][i] += __shfl_xor(rs[mt][i], d, 64);
    if (l15 == 0){
      #pragma unroll
      for (int mt = 0; mt < 2; mt++)
        #pragma unroll
        for (int i = 0; i < 4; i++) dS[wn][(mt<<4) + (quad<<2) + i] = rs[mt][i];
    }
    __syncthreads();
    if (tid < 32){
      float nMask = (float)(1024 - (nch << 7));
      denomS[(z << 10) + bm + tid] = (dS[0][tid] + dS[1][tid]) + (dS[2][tid] + dS[3][tid])
                                     + nMask*__expf(vvRow[tid] - mRow[tid]);
    }
  }
}

// pass 3: PV dequant-GEMM. No QK recompute, no LDS marshalling, no barriers:
// read q3 levels in A-fragment layout, n = clamp(rint(exp((q-zp)s - m)*rp)),
// af = f16(n*scale*1024), MFMA with vT, direct ctx store. Paired groups.
__global__ __launch_bounds__(256) void k_qk_pv(const unsigned short* __restrict__ q3buf,
                                               const _Float16* __restrict__ vT,
                                               float* __restrict__ ctx,
                                               const unsigned* __restrict__ rowmax,
                                               const float* __restrict__ denomS, unsigned* stats){
  QK_IDS
  int j = blockIdx.x, z = blockIdx.y;
  int b = z >> 4, h = z & 15;
  LogitQ L = derive_logit(stats);
  FQP p4 = fqp(0.0f, 1.0f/dec_slot(stats, 32));
  float c1024 = p4.scale*1024.0f;
  float zp3 = L.f3.zp, s3 = L.f3.scale;
  const _Float16* Vb = vT + (size_t)(b*8 + (h>>1))*131072;
  float* Cb = ctx + ((size_t)b << 10)*2048 + (size_t)h*128;
  float cmn = FLT_MAX, cmx = -FLT_MAX;
  for (int g = 0; g < 2; g++){
    int r = g ? (31 - j) : j;
    int bm = r << 5;
    int nch = (r >> 2) + 1;
    int aa = r >> 2, bb2 = r & 3;
    int cum = (aa + 1)*(2*aa + bb2);
    const unsigned short* Qu = q3buf + ((size_t)z*144 + cum)*4096;
    float mR[2], rpR[2];
    #pragma unroll
    for (int mt = 0; mt < 2; mt++){
      int row = (z << 10) + bm + (mt<<4) + l15;
      mR[mt] = chainU(o2f(rowmax[row]), L);
      rpR[mt] = p4.inv/denomS[row];
    }
    f4_t pacc[2][2];
    { f4_t zz = {0.f,0.f,0.f,0.f}; for (int i=0;i<2;i++) for (int jj=0;jj<2;jj++) pacc[i][jj]=zz; }
    for (int c = 0; c < nch; c++){
      const unsigned short* Qc = Qu + (size_t)c*4096;
      #pragma unroll
      for (int k0 = 0; k0 < 4; k0++){
        h8_t af[2], bf[2];
        #pragma unroll
        for (int mt = 0; mt < 2; mt++){
          const unsigned short* pr = Qc + ((mt<<4) + l15)*128 + (k0<<5) + (quad<<3);
          u16x4 u = *(const u16x4*)pr, w = *(const u16x4*)(pr + 4);
          h8_t o;
          #pragma unroll
          for (int jj = 0; jj < 4; jj++){
            float a3u = ((float)u[jj] - zp3)*s3;
            float nu = fminf(fmaxf(rintf(__expf(a3u - mR[mt])*rpR[mt]), 0.0f), 65535.0f);
            o[jj] = (_Float16)(nu*c1024);
            float a3w = ((float)w[jj] - zp3)*s3;
            float nw = fminf(fmaxf(rintf(__expf(a3w - mR[mt])*rpR[mt]), 0.0f), 65535.0f);
            o[jj+4] = (_Float16)(nw*c1024);
          }
          af[mt] = o;
        }
        #pragma unroll
        for (int nt = 0; nt < 2; nt++)
          bf[nt] = *(const h8_t*)(Vb + (size_t)((wn<<5) + (nt<<4) + l15)*1024 + (c<<7) + (k0<<5) + (quad<<3));
        #pragma unroll
        for (int mt = 0; mt < 2; mt++)
          #pragma unroll
          for (int nt = 0; nt < 2; nt++)
            pacc[mt][nt] = __builtin_amdgcn_mfma_f32_16x16x32_f16(af[mt], bf[nt], pacc[mt][nt], 0, 0, 0);
      }
    }
    #pragma unroll
    for (int mt = 0; mt < 2; mt++)
      #pragma unroll
      for (int nt = 0; nt < 2; nt++){
        int Cc = (wn<<5) + (nt<<4) + l15;
        #pragma unroll
        for (int i = 0; i < 4; i++){
          int R = bm + (mt<<4) + (quad<<2) + i;
          float v = pacc[mt][nt][i]*(1.0f/1024.0f);
          Cb[(size_t)R*2048 + Cc] = v;
          cmn = fminf(cmn, v); cmx = fmaxf(cmx, v);
        }
      }
  }
  __shared__ float red[256];
  float bmn = bred_min(cmn, red), bmx = bred_max(cmx, red);
  if (tid == 0){ atomicMin(&stats[36*16], f2o(bmn)); atomicMax(&stats[37*16], f2o(bmx)); }
}

// attn f32 expansion: uniform BW-bound. grid (chunk=8, group=32, z=32).
// Lane mapping: idx = it*256 + tid, row = idx>>5, col = (idx&31)<<2 ->
// 32 lanes x 16B = 512B contiguous per wave store (full-line coverage).
__global__ __launch_bounds__(256) void k_attn_expand(const unsigned short* __restrict__ q3buf,
                                                     float* __restrict__ attn,
                                                     const unsigned* __restrict__ rowmax,
                                                     const float* __restrict__ denomS,
                                                     const unsigned* stats){
  int c = blockIdx.x, r = blockIdx.y, z = blockIdx.z;
  int nch = (r >> 2) + 1;
  int tid = threadIdx.x;
  float* Cb = attn + ((size_t)z << 20) + ((size_t)(r << 5))*1024 + (c << 7);
  if (c >= nch){
    f4_t zz = {0.f,0.f,0.f,0.f};
    #pragma unroll
    for (int it = 0; it < 4; it++){
      int idx = (it << 8) + tid;           // 1024 f4 = 32 rows x 32 segs
      int row = idx >> 5, col = (idx & 31) << 2;
      __builtin_nontemporal_store(zz, (f4_t*)(Cb + (size_t)row*1024 + col));
    }
    return;
  }
  LogitQ L = derive_logit(stats);
  FQP p4 = fqp(0.0f, 1.0f/dec_slot(stats, 32));
  float zp3 = L.f3.zp, s3 = L.f3.scale;
  int aa = r >> 2, bb2 = r & 3;
  int cum = (aa + 1)*(2*aa + bb2);
  const unsigned short* Qu = q3buf + ((size_t)z*144 + cum + c)*4096;
  #pragma unroll
  for (int it = 0; it < 4; it++){
    int idx = (it << 8) + tid;
    int row = idx >> 5, col = (idx & 31) << 2;
    int grow = (z << 10) + (r << 5) + row;
    float m = chainU(o2f(rowmax[grow]), L);
    float rp = p4.inv/denomS[grow];
    u16x4 u = *(const u16x4*)(Qu + row*128 + col);
    f4_t v4;
    #pragma unroll
    for (int jj = 0; jj < 4; jj++){
      float a3 = ((float)u[jj] - zp3)*s3;
      float n = fminf(fmaxf(rintf(__expf(a3 - m)*rp), 0.0f), 65535.0f);
      v4[jj] = n*p4.scale;
    }
    __builtin_nontemporal_store(v4, (f4_t*)(Cb + (size_t)row*1024 + col));
  }
}

// ===========================================================================

// fq16(A) then per-128 rmsnorm; writes (B,NH,S,D) fp32; reduces full+half ranges
__global__ __launch_bounds__(256) void k_rms(const float* __restrict__ lin, float* __restrict__ buf,
                                             const float* __restrict__ gw, unsigned* stats,
                                             int slot_lin, int slot_out, int NHh, int rows){
  FQP pA = fqp(dec_slot(stats, slot_lin), dec_slot(stats, slot_lin+1));
  int lane = threadIdx.x & 63;
  int wv = (blockIdx.x*256 + threadIdx.x) >> 6;
  int nwv = (gridDim.x*256) >> 6;
  float w0 = gw[lane], w1 = gw[lane + 64];
  float fmn = FLT_MAX, fmx = -FLT_MAX, hmn = FLT_MAX, hmx = -FLT_MAX;
  for (int r = wv; r < rows; r += nwv){
    int h = r % NHh; int rem = r / NHh; int s2 = rem & 1023; int b = rem >> 10;
    const float* src = lin + (size_t)r*128;
    float x0 = fqa(src[lane], pA), x1 = fqa(src[lane + 64], pA);
    float ss = x0*x0 + x1*x1;
    #pragma unroll
    for (int m = 1; m < 64; m <<= 1) ss += __shfl_xor(ss, m, 64);
    float rr = 1.0f/sqrtf(ss*(1.0f/128.0f) + 1e-6f);
    float y0 = x0*rr*w0, y1 = x1*rr*w1;
    float* dst = buf + ((size_t)((b*NHh + h) << 10) + s2)*128;
    dst[lane] = y0; dst[lane + 64] = y1;
    fmn = fminf(fmn, fminf(y0, y1)); fmx = fmaxf(fmx, fmaxf(y0, y1));
    hmn = fminf(hmn, y1); hmx = fmaxf(hmx, y1);
  }
  __shared__ float red[256];
  float a = bred_min(fmn, red), bb = bred_max(fmx, red);
  float c = bred_min(hmn, red), d = bred_max(hmx, red);
  if (threadIdx.x == 0){
    atomicMin(&stats[slot_out*16], f2o(a));     atomicMax(&stats[(slot_out+1)*16], f2o(bb));
    atomicMin(&stats[(slot_out+2)*16], f2o(c)); atomicMax(&stats[(slot_out+3)*16], f2o(d));
  }
}

struct RopeQ { FQP B, C, E, F; };
__device__ RopeQ derive_rope(const unsigned* st, int base){
  float ymn = dec_slot(st, base),   ymx = dec_slot(st, base+1);
  float y2mn = dec_slot(st, base+2), y2mx = dec_slot(st, base+3);
  RopeQ r;
  r.B = fqp(ymn, ymx);
  float zmn = fqa(ymn, r.B), zmx = fqa(ymx, r.B);
  r.C = fqp(zmn, zmx);
  float zlo = fqa(zmn, r.C), zhi = fqa(zmx, r.C);
  float z2lo = fqa(fqa(y2mn, r.B), r.C), z2hi = fqa(fqa(y2mx, r.B), r.C);
  r.E = fqp(-z2hi, -z2lo);
  float nlo = fqa(-z2hi, r.E), nhi = fqa(-z2lo, r.E);
  r.F = fqp_raw(fminf(fminf(zlo, nlo), 0.0f), fmaxf(fmaxf(zhi, nhi), 0.0f));
  return r;
}

// merged RoPE: blocks [0,1024) -> Q (slots 8/16/24, NHh=16, 32768 rows),
// blocks [1024,1536) -> K (slots 12/20/26, NHh=8, 16384 rows).
__global__ __launch_bounds__(256) void k_rope(float* __restrict__ bufq, float* __restrict__ bufk,
                                              const float* __restrict__ cosp, const float* __restrict__ sinp,
                                              unsigned* stats, int do_write){
  int isK = (blockIdx.x >= 1024);
  float* buf = isK ? bufk : bufq;
  int slot_norm = isK ? 12 : 8, slot_prod = isK ? 20 : 16, slot_sum = isK ? 26 : 24;
  int NHh = isK ? 8 : 16, rows = isK ? 16384 : 32768;
  int bid = isK ? (blockIdx.x - 1024) : blockIdx.x;
  int nblk = isK ? 512 : 1024;
  RopeQ R = derive_rope(stats, slot_norm);
  FQP pD, pG;
  if (do_write){
    pD = fqp(dec_slot(stats, slot_prod),   dec_slot(stats, slot_prod+1));
    pG = fqp(dec_slot(stats, slot_prod+2), dec_slot(stats, slot_prod+3));
  }
  int lane = threadIdx.x & 63;
  int wv = (bid*256 + threadIdx.x) >> 6, nwv = (nblk*256) >> 6;
  float m0 = FLT_MAX, M0 = -FLT_MAX, m1 = FLT_MAX, M1 = -FLT_MAX;
  for (int r = wv; r < rows; r += nwv){
    int s2 = r & 1023; int bh = r >> 10; int b = bh/NHh;
    float* base = buf + (size_t)r*128;
    float y0 = base[lane], y1 = base[lane + 64];
    float z0 = fqa(fqa(y0, R.B), R.C), z1 = fqa(fqa(y1, R.B), R.C);
    const float* cr = cosp + (size_t)((b << 10) + s2)*128;
    const float* sr = sinp + (size_t)((b << 10) + s2)*128;
    float c0 = cr[lane], c1 = cr[lane + 64], sn0 = sr[lane], sn1 = sr[lane + 64];
    float pc0 = z0*c0, pc1 = z1*c1;
    float rh0 = fqa(fqa(-z1, R.E), R.F);
    float rh1 = fqa(z0, R.F);
    float ps0 = rh0*sn0, ps1 = rh1*sn1;
    if (!do_write){
      m0 = fminf(m0, fminf(pc0, pc1)); M0 = fmaxf(M0, fmaxf(pc0, pc1));
      m1 = fminf(m1, fminf(ps0, ps1)); M1 = fmaxf(M1, fmaxf(ps0, ps1));
    } else {
      float sv0 = fqa(pc0, pD) + fqa(ps0, pG);
      float sv1 = fqa(pc1, pD) + fqa(ps1, pG);
      base[lane] = sv0; base[lane + 64] = sv1;
      m0 = fminf(m0, fminf(sv0, sv1)); M0 = fmaxf(M0, fmaxf(sv0, sv1));
    }
  }
  __shared__ float red[256];
  if (!do_write){
    float a = bred_min(m0, red), bb = bred_max(M0, red);
    float c = bred_min(m1, red), d = bred_max(M1, red);
    if (threadIdx.x == 0){
      atomicMin(&stats[slot_prod*16], f2o(a));     atomicMax(&stats[(slot_prod+1)*16], f2o(bb));
      atomicMin(&stats[(slot_prod+2)*16], f2o(c)); atomicMax(&stats[(slot_prod+3)*16], f2o(d));
    }
  } else {
    float a = bred_min(m0, red), bb = bred_max(M0, red);
    if (threadIdx.x == 0){ atomicMin(&stats[slot_sum*16], f2o(a)); atomicMax(&stats[(slot_sum+1)*16], f2o(bb)); }
  }
}

// V transpose + fq8(fq16) -> f16: vT[b][kv][d][t]
__global__ __launch_bounds__(256) void k_vT(const float* __restrict__ vlin, _Float16* __restrict__ vT,
                                            const unsigned* stats){
  FQP pv = fqp(dec_slot(stats, 6), dec_slot(stats, 7));
  float vlo = fqa(dec_slot(stats, 6), pv), vhi = fqa(dec_slot(stats, 7), pv);
  float v8s = fmaxf(fmaxf(fabsf(vlo), fabsf(vhi))/127.0f, 1e-12f), v8si = 1.0f/v8s;
  __shared__ float tile[64][65];
  int bkv = blockIdx.z, t0 = blockIdx.x << 6, d0 = blockIdx.y << 6;
  int b = bkv >> 3, kv = bkv & 7;
  const float* src = vlin + ((size_t)(b << 10))*1024 + (size_t)kv*128;
  int tx = threadIdx.x & 63, tq = threadIdx.x >> 6;
  #pragma unroll
  for (int i = 0; i < 16; i++){
    int tt = (i << 2) + tq;
    float x = src[(size_t)(t0 + tt)*1024 + d0 + tx];
    tile[tx][tt] = fq8(fqa(x, pv), v8s, v8si);
  }
  __syncthreads();
  _Float16* dst = vT + (size_t)bkv*131072;
  #pragma unroll
  for (int i = 0; i < 16; i++){
    int dd = (i << 2) + tq;
    dst[(size_t)(d0 + dd)*1024 + t0 + tx] = (_Float16)tile[dd][tx];
  }
}

extern "C" void kernel_launch(void* const* d_in, const int* in_sizes, int n_in,
                              void* d_out, int out_size, void* d_ws, size_t ws_size,
                              hipStream_t stream){
  (void)in_sizes; (void)n_in; (void)out_size; (void)ws_size;
  const float* hs   = (const float*)d_in[0];
  const float* cosp = (const float*)d_in[1];
  const float* sinp = (const float*)d_in[2];
  const float* Wq   = (const float*)d_in[4];
  const float* Wk   = (const float*)d_in[5];
  const float* Wv   = (const float*)d_in[6];
  const float* Wo   = (const float*)d_in[7];
  const float* qnw  = (const float*)d_in[8];
  const float* knw  = (const float*)d_in[9];

  float* outp = (float*)d_out;
  float* attn = outp + 4194304;      // final quantized softmax

  const size_t MEG = 1u << 20;       // floats
  float* wsf = (float*)d_ws;
  _Float16* woq_h = (_Float16*)(wsf + 0);
  _Float16* wqq_h = (_Float16*)(wsf + 2*MEG);
  _Float16* wkq_h = (_Float16*)(wsf + 4*MEG);
  _Float16* wvq_h = (_Float16*)(wsf + 5*MEG);
  _Float16* hsq_h = (_Float16*)(wsf + 6*MEG);
  float* qlin = wsf + 8*MEG;  float* ctx = qlin;   // ctx reuses qlin
  float* klin = wsf + 12*MEG;
  float* vlin = wsf + 14*MEG;
  float* qbuf = wsf + 16*MEG;
  float* kbuf = wsf + 20*MEG;
  _Float16* q_h   = (_Float16*)(wsf + 22*MEG);
  _Float16* k_h   = (_Float16*)(wsf + 24*MEG);
  _Float16* vT_h  = (_Float16*)(wsf + 25*MEG);
  _Float16* ctx_h = (_Float16*)(wsf + 26*MEG);
  unsigned* rowmin = (unsigned*)(wsf + 28*MEG);
  unsigned* rowmax = (unsigned*)(wsf + 28*MEG + 32768);
  float* denomS = wsf + 28*MEG + 65536;
  unsigned* stats = (unsigned*)(wsf + 28*MEG + 98304);
  // q3 levels: 32 z * 144 units * 4096 u16 = 36 MB. Overlays klin/vlin/qbuf/
  // kbuf (wsf+12M..21M floats) -- all dead before k_qk_denom writes it.
  unsigned short* q3buf = (unsigned short*)(wsf + 12*MEG);

  k_init<<<4, 256, 0, stream>>>(stats);

  k_quantw4<<<12288, 256, 0, stream>>>(Wq, Wk, Wv, Wo, wqq_h, wkq_h, wvq_h, woq_h);

  k_minmax<<<1024, 256, 0, stream>>>(hs, 4194304, stats, 0);
  k_fq_ew16<<<4096, 256, 0, stream>>>(hs, hsq_h, stats, 0);

  // fused Q/K/V projections (512 blocks -> 2 blocks/CU), raw-range stats fused
  k_hgemm_qkv<<<dim3(8, 16, 4), 256, 0, stream>>>(hsq_h, wqq_h, wkq_h, wvq_h,
                                                  qlin, klin, vlin, 2048, stats);

  // fq16 + rmsnorm (fp32) + range reductions
  k_rms<<<1024, 256, 0, stream>>>(qlin, qbuf, qnw, stats, 2, 8, 16, 32768);
  k_rms<<<512, 256, 0, stream>>>(klin, kbuf, knw, stats, 4, 12, 8, 16384);

  // RoPE: merged q+k range pass then merged write pass
  k_rope<<<1536, 256, 0, stream>>>(qbuf, kbuf, cosp, sinp, stats, 0);
  k_rope<<<1536, 256, 0, stream>>>(qbuf, kbuf, cosp, sinp, stats, 1);

  // merged operand conversion for QK; V transpose
  k_fq_qk<<<6144, 256, 0, stream>>>(qbuf, kbuf, q_h, k_h, stats);
  k_vT<<<dim3(16, 2, 16), 256, 0, stream>>>(vlin, vT_h, stats);

  // attention: stats (full sweep) -> denom (+q3 store) -> pv (dequant-GEMM)
  // -> expand (attn f32 write). denom/pv paired (j, 31-j) = 9 units/block.
  k_qk_stats<<<dim3(32, 32), 256, 0, stream>>>(q_h, k_h, stats, rowmin, rowmax);
  k_rowstat_m2<<<8, 256, 0, stream>>>(rowmin, stats, 32768);
  k_qk_denom<<<dim3(16, 32), 256, 0, stream>>>(q_h, k_h, rowmin, rowmax, denomS, q3buf, stats);
  k_denom_min<<<8, 256, 0, stream>>>(denomS, stats, 32768);
  k_qk_pv<<<dim3(16, 32), 256, 0, stream>>>(q3buf, vT_h, ctx, rowmax, denomS, stats);
  k_attn_expand<<<dim3(8, 32, 32), 256, 0, stream>>>(q3buf, attn, rowmax, denomS, stats);

  // ctx (stats fused in PV) -> f16 -> O-proj (128x64 tiles, 2 blocks/CU)
  k_fq_ew16<<<4096, 256, 0, stream>>>(ctx, ctx_h, stats, 36);
  k_hgemm_o<<<dim3(32, 16), 256, 0, stream>>>(ctx_h, woq_h, outp);
}

// Round 8
// 589.566 us; speedup vs baseline: 1.4235x; 1.0097x over previous
//
#include <hip/hip_runtime.h>
#include <cfloat>
#include <cmath>

// ---------------------------------------------------------------------------
// Qwen3Attention fake-quant forward. B=2 S=1024 HID=2048 NH=16 NKV=8 D=128.
// Round 14: (a) pv writes causal attn f32 directly from its in-register n
// values (16rows x 128B contiguous per wave instr, cached stores -> L2
// merges); expand replaced by a paired zero-fill of the masked region.
// (b) GEMMs stage two 32-wide K-tiles per barrier pair (BK=64, same LDS
// layout and MFMA order -> bit-exact, half the barriers). (c) rowstat/
// denom_min folded into stats/denom epilogues; hs minmax folded into
// quantw4. 3 fewer launches.
// ---------------------------------------------------------------------------

#define FQ_EPS      1.5259021896696422e-09f   // 0.0001/65535
#define SCALING_F   0.08838834764831845f      // 128**-0.5
#define S_LEN       1024

typedef _Float16 h8_t __attribute__((ext_vector_type(8)));
typedef _Float16 h4_t __attribute__((ext_vector_type(4)));
typedef float    f4_t __attribute__((ext_vector_type(4)));
typedef unsigned short u16x4 __attribute__((ext_vector_type(4)));

// ---- float <-> order-preserving unsigned encoding (for atomic min/max) ----
__device__ __forceinline__ unsigned f2o(float f){
  unsigned u = __float_as_uint(f);
  return (u & 0x80000000u) ? ~u : (u | 0x80000000u);
}
__device__ __forceinline__ float o2f(unsigned u){
  return __uint_as_float((u & 0x80000000u) ? (u ^ 0x80000000u) : ~u);
}
__device__ __forceinline__ float dec_slot(const unsigned* st, int s){ return o2f(st[s*16]); }

// ---- fq16 helpers ----
struct FQP { float scale, zp, inv; };
__device__ __forceinline__ FQP fqp_raw(float mn, float mx){
  FQP p; p.scale = fmaxf((mx - mn)/65535.0f, FQ_EPS); p.zp = rintf(-mn/p.scale);
  p.inv = 1.0f/p.scale; return p;
}
__device__ __forceinline__ FQP fqp(float mn0, float mx0){
  return fqp_raw(fminf(mn0, 0.0f), fmaxf(mx0, 0.0f));
}
__device__ __forceinline__ float fqa(float x, FQP p){
  float q = rintf(x*p.inv) + p.zp;
  q = fminf(fmaxf(q, 0.0f), 65535.0f);
  return (q - p.zp)*p.scale;
}
__device__ __forceinline__ float fq8(float x, float s, float si){
  return fminf(fmaxf(rintf(x*si), -128.0f), 127.0f)*s;
}

// ---- block reductions (blockDim == 256) ----
__device__ __forceinline__ float bred_min(float v, float* red){
  int tid = threadIdx.x; red[tid] = v; __syncthreads();
  for (int s = 128; s > 0; s >>= 1){ if (tid < s) red[tid] = fminf(red[tid], red[tid+s]); __syncthreads(); }
  float r = red[0]; __syncthreads(); return r;
}
__device__ __forceinline__ float bred_max(float v, float* red){
  int tid = threadIdx.x; red[tid] = v; __syncthreads();
  for (int s = 128; s > 0; s >>= 1){ if (tid < s) red[tid] = fmaxf(red[tid], red[tid+s]); __syncthreads(); }
  float r = red[0]; __syncthreads(); return r;
}

// ---- stats slot map (even=min, odd=max) ----
// 0/1 hs | 2/3 qlin | 4/5 klin | 6/7 vlin | 8/9 qn | 10/11 qn2 | 12/13 kn | 14/15 kn2
// 16/17 q*c | 18/19 qrh*s | 20/21 k*c | 22/23 krh*s | 24/25 qsum | 26/27 ksum
// 28/29 logits | 31 unmaskedMax | 32 denomMin | 35 maxOfRowMins | 36/37 ctx

__global__ void k_init(unsigned* stats){
  int i = blockIdx.x*blockDim.x + threadIdx.x;
  if (i < 1024) stats[i] = (((i & 15) == 0) && (((i >> 4) & 1) == 0)) ? 0xFFFFFFFFu : 0u;
}

// lpbq weight quantization -> f16 (blocks < 12288) + hs global minmax
// (blocks >= 12288, grid-stride identical to the old k_minmax -> bit-exact).
__global__ __launch_bounds__(256) void k_quantw4(const float* __restrict__ Wq, const float* __restrict__ Wk,
                                                 const float* __restrict__ Wv, const float* __restrict__ Wo,
                                                 _Float16* __restrict__ Qh, _Float16* __restrict__ Kh,
                                                 _Float16* __restrict__ Vh, _Float16* __restrict__ Oh,
                                                 const float* __restrict__ hs, unsigned* stats){
  int bx = blockIdx.x;
  if (bx >= 12288){
    float mn = FLT_MAX, mx = -FLT_MAX;
    for (int i = (bx - 12288)*256 + threadIdx.x; i < 4194304; i += 262144){
      float v = hs[i]; mn = fminf(mn, v); mx = fmaxf(mx, v);
    }
    __shared__ float red[256];
    float bmn = bred_min(mn, red), bmx = bred_max(mx, red);
    if (threadIdx.x == 0){ atomicMin(&stats[0], f2o(bmn)); atomicMax(&stats[16], f2o(bmx)); }
    return;
  }
  const float* W; _Float16* Wh; int base;
  if (bx < 4096){ W = Wq; Wh = Qh; base = 0; }
  else if (bx < 6144){ W = Wk; Wh = Kh; base = 4096; }
  else if (bx < 8192){ W = Wv; Wh = Vh; base = 6144; }
  else { W = Wo; Wh = Oh; base = 8192; }
  int i = (bx - base)*256 + threadIdx.x;
  float4 v = ((const float4*)W)[i];
  float am = fmaxf(fmaxf(fabsf(v.x), fabsf(v.y)), fmaxf(fabsf(v.z), fabsf(v.w)));
  #pragma unroll
  for (int m = 1; m < 8; m <<= 1) am = fmaxf(am, __shfl_xor(am, m, 64));
  float s = fmaxf(am/7.0f, 1e-12f), si = 1.0f/s;
  h4_t o;
  o[0] = (_Float16)(fminf(fmaxf(rintf(v.x*si), -8.0f), 7.0f)*s);
  o[1] = (_Float16)(fminf(fmaxf(rintf(v.y*si), -8.0f), 7.0f)*s);
  o[2] = (_Float16)(fminf(fmaxf(rintf(v.z*si), -8.0f), 7.0f)*s);
  o[3] = (_Float16)(fminf(fmaxf(rintf(v.w*si), -8.0f), 7.0f)*s);
  *(h4_t*)(Wh + ((size_t)i << 2)) = o;
}

// fq16 elementwise -> f16, 4 elems/thread (used for hs and ctx)
__global__ __launch_bounds__(256) void k_fq_ew16(const float* __restrict__ x, _Float16* __restrict__ y,
                                                 const unsigned* stats, int slot){
  FQP p = fqp(dec_slot(stats, slot), dec_slot(stats, slot+1));
  int i = blockIdx.x*256 + threadIdx.x;
  float4 v = ((const float4*)x)[i];
  h4_t o;
  o[0] = (_Float16)fqa(v.x, p); o[1] = (_Float16)fqa(v.y, p);
  o[2] = (_Float16)fqa(v.z, p); o[3] = (_Float16)fqa(v.w, p);
  *(h4_t*)(y + ((size_t)i << 2)) = o;
}

// merged q/k operand conversion: blocks [0,4096) -> fq16(qbuf)->q_h (slot 24),
// blocks [4096,6144) -> fq8(fq16(kbuf))->k_h (slot 26)
__global__ __launch_bounds__(256) void k_fq_qk(const float* __restrict__ qbuf, const float* __restrict__ kbuf,
                                               _Float16* __restrict__ q_h, _Float16* __restrict__ k_h,
                                               const unsigned* stats){
  int bx = blockIdx.x;
  if (bx < 4096){
    FQP p = fqp(dec_slot(stats, 24), dec_slot(stats, 25));
    int i = bx*256 + threadIdx.x;
    float4 v = ((const float4*)qbuf)[i];
    h4_t o;
    o[0] = (_Float16)fqa(v.x, p); o[1] = (_Float16)fqa(v.y, p);
    o[2] = (_Float16)fqa(v.z, p); o[3] = (_Float16)fqa(v.w, p);
    *(h4_t*)(q_h + ((size_t)i << 2)) = o;
  } else {
    FQP p = fqp(dec_slot(stats, 26), dec_slot(stats, 27));
    float lo = fqa(dec_slot(stats, 26), p), hi = fqa(dec_slot(stats, 27), p);
    float s8 = fmaxf(fmaxf(fabsf(lo), fabsf(hi))/127.0f, 1e-12f), s8i = 1.0f/s8;
    int i = (bx - 4096)*256 + threadIdx.x;
    float4 v = ((const float4*)kbuf)[i];
    h4_t o;
    o[0] = (_Float16)fq8(fqa(v.x, p), s8, s8i); o[1] = (_Float16)fq8(fqa(v.y, p), s8, s8i);
    o[2] = (_Float16)fq8(fqa(v.z, p), s8, s8i); o[3] = (_Float16)fq8(fqa(v.w, p), s8, s8i);
    *(h4_t*)(k_h + ((size_t)i << 2)) = o;
  }
}

// ================= f16 MFMA GEMM core for projections (NT) =================
// async staging: LDS dest is wave-uniform base + lane*16B (constraint-safe).
#define GLDS16(g, l) __builtin_amdgcn_global_load_lds( \
    (__attribute__((address_space(1))) unsigned int*)(g), \
    (__attribute__((address_space(3))) unsigned int*)(l), 16, 0, 0)

__device__ __forceinline__ void stage_tile(const _Float16* __restrict__ src, int ld, int k0,
                                           _Float16* __restrict__ dst){
  #pragma unroll
  for (int it = 0; it < 2; it++){
    int c = threadIdx.x + (it << 8);
    int row = c >> 2, off = (c & 3) << 3;
    GLDS16(src + (size_t)row*ld + k0 + off, dst + (c << 3));
  }
}

// BK=64: stage two 32-wide tiles per barrier pair; MFMA order identical to
// two BK=32 iterations -> bit-exact; barrier count halves.
__device__ __forceinline__ void hgemm_main64(const _Float16* __restrict__ A, int lda,
                                             const _Float16* __restrict__ B, int ldb, int K,
                                             f4_t acc[4][4], _Float16* As, _Float16* As2,
                                             _Float16* Bs, _Float16* Bs2){
  int lane = threadIdx.x & 63, wave = threadIdx.x >> 6;
  int wm = wave & 1, wn = wave >> 1, quad = lane >> 4, l15 = lane & 15;
  for (int k0 = 0; k0 < K; k0 += 64){
    __syncthreads();
    stage_tile(A, lda, k0, As);
    stage_tile(A, lda, k0 + 32, As2);
    stage_tile(B, ldb, k0, Bs);
    stage_tile(B, ldb, k0 + 32, Bs2);
    __syncthreads();
    #pragma unroll
    for (int half = 0; half < 2; half++){
      const _Float16* Ah = half ? As2 : As;
      const _Float16* Bh = half ? Bs2 : Bs;
      h8_t af[4], bf[4];
      #pragma unroll
      for (int mt = 0; mt < 4; mt++)
        af[mt] = *(const h8_t*)(Ah + ((((wm<<6) + (mt<<4) + l15)) << 5) + (quad << 3));
      #pragma unroll
      for (int nt = 0; nt < 4; nt++)
        bf[nt] = *(const h8_t*)(Bh + ((((wn<<6) + (nt<<4) + l15)) << 5) + (quad << 3));
      #pragma unroll
      for (int mt = 0; mt < 4; mt++)
        #pragma unroll
        for (int nt = 0; nt < 4; nt++)
          acc[mt][nt] = __builtin_amdgcn_mfma_f32_16x16x32_f16(af[mt], bf[nt], acc[mt][nt], 0, 0, 0);
    }
  }
}

// C/D lane map (m89-verified): D[row=(quad*4+reg)][col=l15].

// fused Q/K/V projections: z=0,1 -> Q col-halves (slot 2), z=2 -> K (slot 4),
// z=3 -> V (slot 6). 512 blocks -> 2 blocks/CU -> 8 waves/CU.
__global__ __launch_bounds__(256) void k_hgemm_qkv(const _Float16* __restrict__ A,
                                                   const _Float16* __restrict__ Bq,
                                                   const _Float16* __restrict__ Bk,
                                                   const _Float16* __restrict__ Bv,
                                                   float* __restrict__ Cq, float* __restrict__ Ck,
                                                   float* __restrict__ Cv,
                                                   int K, unsigned* stats){
  __shared__ __align__(16) _Float16 As[4096], As2[4096], Bs[4096], Bs2[4096];
  __shared__ float red[256];
  f4_t acc[4][4];
  { f4_t zz = {0.f,0.f,0.f,0.f};
    for (int i=0;i<4;i++) for (int j=0;j<4;j++) acc[i][j] = zz; }
  int lane = threadIdx.x & 63, wave = threadIdx.x >> 6;
  int wm = wave & 1, wn = wave >> 1, quad = lane >> 4, l15 = lane & 15; (void)lane;
  int z = blockIdx.z;
  const _Float16* Bmat; float* C; int slotC, N, cbase;
  if (z < 2){ Bmat = Bq + (((size_t)z << 10))*K; C = Cq; slotC = 2; N = 2048; cbase = z << 10; }
  else if (z == 2){ Bmat = Bk; C = Ck; slotC = 4; N = 1024; cbase = 0; }
  else { Bmat = Bv; C = Cv; slotC = 6; N = 1024; cbase = 0; }
  int bm = blockIdx.y << 7, bn = blockIdx.x << 7;
  hgemm_main64(A + (size_t)bm*K, K, Bmat + (size_t)bn*K, K, K, acc, As, As2, Bs, Bs2);
  float mn = FLT_MAX, mx = -FLT_MAX;
  #pragma unroll
  for (int mt = 0; mt < 4; mt++)
    #pragma unroll
    for (int nt = 0; nt < 4; nt++){
      int Cc = cbase + bn + (wn<<6) + (nt<<4) + l15;
      #pragma unroll
      for (int i = 0; i < 4; i++){
        int R = bm + (wm<<6) + (mt<<4) + (quad<<2) + i;
        float v = acc[mt][nt][i];
        C[(size_t)R*N + Cc] = v;
        mn = fminf(mn, v); mx = fmaxf(mx, v);
      }
    }
  float bmn = bred_min(mn, red), bmx = bred_max(mx, red);
  if (threadIdx.x == 0){ atomicMin(&stats[slotC*16], f2o(bmn)); atomicMax(&stats[(slotC+1)*16], f2o(bmx)); }
}

// O-proj: 128x64 tiles, grid (32,16) = 512 blocks = 2 blocks/CU, BK=64.
__global__ __launch_bounds__(256) void k_hgemm_o(const _Float16* __restrict__ A,
                                                 const _Float16* __restrict__ B,
                                                 float* __restrict__ C){
  __shared__ __align__(16) _Float16 As[4096], As2[4096], Bs[2048], Bs2[2048];
  f4_t acc[4][2];
  { f4_t zz = {0.f,0.f,0.f,0.f};
    for (int i = 0; i < 4; i++) for (int j = 0; j < 2; j++) acc[i][j] = zz; }
  int lane = threadIdx.x & 63, wave = threadIdx.x >> 6;
  int wm = wave & 1, wn = wave >> 1, quad = lane >> 4, l15 = lane & 15;
  int bm = blockIdx.y << 7, bn = blockIdx.x << 6;
  const _Float16* Ab = A + (size_t)bm*2048;
  const _Float16* Bb = B + (size_t)bn*2048;
  for (int k0 = 0; k0 < 2048; k0 += 64){
    __syncthreads();
    stage_tile(Ab, 2048, k0, As);
    stage_tile(Ab, 2048, k0 + 32, As2);
    { int c = threadIdx.x;                       // 64 rows x 32 k = 4 KB, one shot
      int row = c >> 2, off = (c & 3) << 3;
      GLDS16(Bb + (size_t)row*2048 + k0 + off, Bs + (c << 3));
      GLDS16(Bb + (size_t)row*2048 + k0 + 32 + off, Bs2 + (c << 3)); }
    __syncthreads();
    #pragma unroll
    for (int half = 0; half < 2; half++){
      const _Float16* Ah = half ? As2 : As;
      const _Float16* Bh = half ? Bs2 : Bs;
      h8_t af[4], bf[2];
      #pragma unroll
      for (int mt = 0; mt < 4; mt++)
        af[mt] = *(const h8_t*)(Ah + ((((wm<<6) + (mt<<4) + l15)) << 5) + (quad << 3));
      #pragma unroll
      for (int nt = 0; nt < 2; nt++)
        bf[nt] = *(const h8_t*)(Bh + ((((wn<<5) + (nt<<4) + l15)) << 5) + (quad << 3));
      #pragma unroll
      for (int mt = 0; mt < 4; mt++)
        #pragma unroll
        for (int nt = 0; nt < 2; nt++)
          acc[mt][nt] = __builtin_amdgcn_mfma_f32_16x16x32_f16(af[mt], bf[nt], acc[mt][nt], 0, 0, 0);
    }
  }
  #pragma unroll
  for (int mt = 0; mt < 4; mt++)
    #pragma unroll
    for (int nt = 0; nt < 2; nt++){
      int Cc = bn + (wn<<5) + (nt<<4) + l15;
      #pragma unroll
      for (int i = 0; i < 4; i++){
        int R = bm + (wm<<6) + (mt<<4) + (quad<<2) + i;
        C[(size_t)R*2048 + Cc] = acc[mt][nt][i];
      }
    }
}

// ====================== QK^T attention passes (32-row) =====================
// block = 256 thr (4 waves). A 32-row group r (0..31) covers q-rows
// [32r, 32r+32); it needs nch(r) = (r>>2)+1 K-chunks of 128. Wave wn owns
// cols [32*wn, 32*wn+32): acc[2][2]. Pairing (j, 31-j) -> constant 9
// chunk-units per block. q3 levels (post-f3 u16) are exact -> stored once by
// denom, consumed by pv (PV GEMM + attn f32 write) bit-exactly.
// causal unit index: cum(r) = (a+1)*(2a+b), a=r>>2, b=r&3; unit = cum + chunk.

#define QK_IDS \
  int lane = threadIdx.x & 63, wn = threadIdx.x >> 6; \
  int quad = lane >> 4, l15 = lane & 15; \
  int tid = threadIdx.x; (void)tid; (void)lane;

__device__ __forceinline__ void qk_load_a(const _Float16* __restrict__ Ab, int quad, int l15,
                                          h8_t Aq[2][4]){
  #pragma unroll
  for (int mt = 0; mt < 2; mt++)
    #pragma unroll
    for (int k0 = 0; k0 < 4; k0++)
      Aq[mt][k0] = *(const h8_t*)(Ab + (size_t)((mt<<4) + l15)*128 + (k0<<5) + (quad<<3));
}

__device__ __forceinline__ void qk_chunk32(const h8_t Aq[2][4], const _Float16* __restrict__ Kb,
                                           int bn, int wn, int quad, int l15, f4_t acc[2][2]){
  #pragma unroll
  for (int k0 = 0; k0 < 4; k0++){
    h8_t bf[2];
    #pragma unroll
    for (int nt = 0; nt < 2; nt++)
      bf[nt] = *(const h8_t*)(Kb + (size_t)(bn + (wn<<5) + (nt<<4) + l15)*128 + (k0<<5) + (quad<<3));
    #pragma unroll
    for (int mt = 0; mt < 2; mt++)
      #pragma unroll
      for (int nt = 0; nt < 2; nt++)
        acc[mt][nt] = __builtin_amdgcn_mfma_f32_16x16x32_f16(Aq[mt][k0], bf[nt], acc[mt][nt], 0, 0, 0);
  }
}

// pass 1: per-row min (full), max (full), max (causal) accumulators; global
// mn/mx/mxU AND maxOfRowMins (slot 35) derived in epilogue (order-free).
// 32-row groups, grid (32, 32).
__global__ __launch_bounds__(256) void k_qk_stats(const _Float16* __restrict__ q_h, const _Float16* __restrict__ k_h,
                                                  unsigned* stats, unsigned* rowmin, unsigned* rowmax){
  QK_IDS
  int bm = blockIdx.x << 5, z = blockIdx.y;
  int b = z >> 4, h = z & 15;
  const _Float16* Ab = q_h + (size_t)z*131072 + (size_t)bm*128;
  const _Float16* Kb = k_h + (size_t)(b*8 + (h>>1))*131072;
  h8_t Aq[2][4];
  qk_load_a(Ab, quad, l15, Aq);
  float rmv[2][4], rxa[2][4], rxv[2][4];
  #pragma unroll
  for (int mt = 0; mt < 2; mt++)
    #pragma unroll
    for (int i = 0; i < 4; i++){ rmv[mt][i] = FLT_MAX; rxa[mt][i] = -FLT_MAX; rxv[mt][i] = -FLT_MAX; }
  for (int bn = 0; bn < 1024; bn += 128){
    f4_t acc[2][2];
    { f4_t zz = {0.f,0.f,0.f,0.f}; for (int i=0;i<2;i++) for (int j=0;j<2;j++) acc[i][j]=zz; }
    qk_chunk32(Aq, Kb, bn, wn, quad, l15, acc);
    #pragma unroll
    for (int mt = 0; mt < 2; mt++){
      int rb = bm + (mt<<4) + (quad<<2);
      #pragma unroll
      for (int nt = 0; nt < 2; nt++){
        int t = bn + (wn<<5) + (nt<<4) + l15;
        #pragma unroll
        for (int i = 0; i < 4; i++){
          float v = acc[mt][nt][i];
          rmv[mt][i] = fminf(rmv[mt][i], v);
          rxa[mt][i] = fmaxf(rxa[mt][i], v);
          if (t <= rb + i) rxv[mt][i] = fmaxf(rxv[mt][i], v);
        }
      }
    }
  }
  #pragma unroll
  for (int d = 1; d < 16; d <<= 1)
    #pragma unroll
    for (int mt = 0; mt < 2; mt++)
      #pragma unroll
      for (int i = 0; i < 4; i++){
        rmv[mt][i] = fminf(rmv[mt][i], __shfl_xor(rmv[mt][i], d, 64));
        rxa[mt][i] = fmaxf(rxa[mt][i], __shfl_xor(rxa[mt][i], d, 64));
        rxv[mt][i] = fmaxf(rxv[mt][i], __shfl_xor(rxv[mt][i], d, 64));
      }
  __shared__ float rminS[4][32], rmaxS[4][32];
  if (l15 == 0){
    #pragma unroll
    for (int mt = 0; mt < 2; mt++)
      #pragma unroll
      for (int i = 0; i < 4; i++){
        int rl = (mt<<4) + (quad<<2) + i;
        rminS[wn][rl] = rmv[mt][i];
        rmaxS[wn][rl] = rxv[mt][i];
      }
  }
  __syncthreads();
  if (tid < 32){
    float a = fminf(fminf(rminS[0][tid], rminS[1][tid]), fminf(rminS[2][tid], rminS[3][tid]));
    float c = fmaxf(fmaxf(rmaxS[0][tid], rmaxS[1][tid]), fmaxf(rmaxS[2][tid], rmaxS[3][tid]));
    rowmin[(z << 10) + bm + tid] = f2o(a);
    rowmax[(z << 10) + bm + tid] = f2o(c);
    // maxOfRowMins (slot 35): max over this block's 32 row-mins, width-32 shuffle
    float am = a;
    #pragma unroll
    for (int d = 1; d < 32; d <<= 1) am = fmaxf(am, __shfl_xor(am, d, 32));
    if (tid == 0) atomicMax(&stats[35*16], f2o(am));
  }
  float mn = FLT_MAX, mx = -FLT_MAX, mxU = -FLT_MAX;
  #pragma unroll
  for (int mt = 0; mt < 2; mt++)
    #pragma unroll
    for (int i = 0; i < 4; i++){
      mn = fminf(mn, rmv[mt][i]);
      mx = fmaxf(mx, rxa[mt][i]);
      mxU = fmaxf(mxU, rxv[mt][i]);
    }
  __shared__ float red[256];
  float bmn = bred_min(mn, red), bmx = bred_max(mx, red), bmU = bred_max(mxU, red);
  if (tid == 0){
    atomicMin(&stats[28*16], f2o(bmn));
    atomicMax(&stats[29*16], f2o(bmx));
    atomicMax(&stats[31*16], f2o(bmU));
  }
}

struct LogitQ { FQP f1, f2, fam, fvv, f3; float sc, c20; };
__device__ LogitQ derive_logit(const unsigned* st){
  LogitQ L;
  FQP ps = fqp(SCALING_F, SCALING_F); L.sc = fqa(SCALING_F, ps);
  FQP p20 = fqp(-20.0f, -20.0f);      L.c20 = fqa(-20.0f, p20);
  float gmn = dec_slot(st, 28), gmx = dec_slot(st, 29);
  float gU = dec_slot(st, 31), M2 = dec_slot(st, 35);
  L.f1 = fqp(gmn, gmx);
  float l1lo = fqa(gmn, L.f1), l1hi = fqa(gmx, L.f1);
  L.f2 = fqp(l1lo*L.sc, l1hi*L.sc);
  float amlo = fqa(fqa(gmn, L.f1)*L.sc, L.f2);
  float amhi = fqa(fqa(M2, L.f1)*L.sc, L.f2);
  L.fam = fqp(amlo, amhi);
  float vslo = fqa(amlo, L.fam) + L.c20, vshi = fqa(amhi, L.fam) + L.c20;
  L.fvv = fqp(vslo, vshi);
  float mn3 = fqa(vslo, L.fvv);
  float mx3 = fqa(fqa(gU, L.f1)*L.sc, L.f2);
  L.f3 = fqp(mn3, mx3);
  return L;
}
__device__ __forceinline__ float chainU(float raw, const LogitQ& L){
  return fqa(fqa(fqa(raw, L.f1)*L.sc, L.f2), L.f3);
}

// pass 2: per-row denominators + q3-level store (u16, causal-packed) +
// denomMin (slot 32) folded into the epilogue. Paired 32-row groups
// (j, 31-j) = 9 units/block. Skipped masked chunks contribute
// count*exp(vv-m) per row analytically.
__global__ __launch_bounds__(256) void k_qk_denom(const _Float16* __restrict__ q_h, const _Float16* __restrict__ k_h,
                                                  const unsigned* __restrict__ rowmin,
                                                  const unsigned* __restrict__ rowmax,
                                                  float* __restrict__ denomS,
                                                  unsigned short* __restrict__ q3buf,
                                                  unsigned* stats){
  QK_IDS
  int j = blockIdx.x, z = blockIdx.y;
  int b = z >> 4, h = z & 15;
  LogitQ L = derive_logit(stats);
  const _Float16* Kb = k_h + (size_t)(b*8 + (h>>1))*131072;
  __shared__ float mRow[32], vvRow[32], vvLev[32];
  __shared__ float dS[4][32];
  for (int g = 0; g < 2; g++){
    int r = g ? (31 - j) : j;
    int bm = r << 5;
    int nch = (r >> 2) + 1;
    int cstar = (r >> 2) << 7;          // diagonal-chunk base
    int aa = r >> 2, bb2 = r & 3;
    int cum = (aa + 1)*(2*aa + bb2);    // causal units before group r
    unsigned short* Qu = q3buf + ((size_t)z*144 + cum)*4096;
    __syncthreads();                    // prior group done with mRow/vvRow/dS
    if (tid < 32){
      int row = (z << 10) + bm + tid;
      mRow[tid] = chainU(o2f(rowmax[row]), L);
      float tr = fqa(fqa(o2f(rowmin[row]), L.f1)*L.sc, L.f2);
      float w = fqa(fqa(tr, L.fam) + L.c20, L.fvv);
      float lv = fminf(fmaxf(rintf(w*L.f3.inv) + L.f3.zp, 0.0f), 65535.0f);
      vvLev[tid] = lv;
      vvRow[tid] = (lv - L.f3.zp)*L.f3.scale;   // == fqa(w, f3)
    }
    const _Float16* Ab = q_h + (size_t)z*131072 + (size_t)bm*128;
    h8_t Aq[2][4];
    qk_load_a(Ab, quad, l15, Aq);
    __syncthreads();                    // mRow/vvRow/vvLev visible
    float rs[2][4];
    #pragma unroll
    for (int mt = 0; mt < 2; mt++)
      #pragma unroll
      for (int i = 0; i < 4; i++) rs[mt][i] = 0.0f;
    for (int bn = 0; bn < (nch << 7); bn += 128){
      f4_t acc[2][2];
      { f4_t zz = {0.f,0.f,0.f,0.f}; for (int i=0;i<2;i++) for (int jj=0;jj<2;jj++) acc[i][jj]=zz; }
      qk_chunk32(Aq, Kb, bn, wn, quad, l15, acc);
      unsigned short* Qc = Qu + (size_t)(bn >> 7)*4096;
      if (bn < cstar){
        // fully unmasked chunk: no causal select
        #pragma unroll
        for (int mt = 0; mt < 2; mt++){
          #pragma unroll
          for (int nt = 0; nt < 2; nt++){
            int cl = (wn<<5) + (nt<<4) + l15;
            #pragma unroll
            for (int i = 0; i < 4; i++){
              int rl = (mt<<4) + (quad<<2) + i;
              float a2 = fqa(fqa(acc[mt][nt][i], L.f1)*L.sc, L.f2);
              float lvl = fminf(fmaxf(rintf(a2*L.f3.inv) + L.f3.zp, 0.0f), 65535.0f);
              Qc[rl*128 + cl] = (unsigned short)lvl;
              float a3 = (lvl - L.f3.zp)*L.f3.scale;   // == fqa(a2, f3)
              rs[mt][i] += __expf(a3 - mRow[rl]);
            }
          }
        }
      } else {
        // diagonal (mixed) chunk: per-element causal select on the LEVEL
        #pragma unroll
        for (int mt = 0; mt < 2; mt++){
          #pragma unroll
          for (int nt = 0; nt < 2; nt++){
            int cl = (wn<<5) + (nt<<4) + l15;
            int t = bn + cl;
            #pragma unroll
            for (int i = 0; i < 4; i++){
              int rl = (mt<<4) + (quad<<2) + i;
              float a2 = fqa(fqa(acc[mt][nt][i], L.f1)*L.sc, L.f2);
              float lvl = fminf(fmaxf(rintf(a2*L.f3.inv) + L.f3.zp, 0.0f), 65535.0f);
              float qs = (t <= bm + rl) ? lvl : vvLev[rl];
              Qc[rl*128 + cl] = (unsigned short)qs;
              float a3 = (qs - L.f3.zp)*L.f3.scale;
              rs[mt][i] += __expf(a3 - mRow[rl]);
            }
          }
        }
      }
    }
    #pragma unroll
    for (int d = 1; d < 16; d <<= 1)
      #pragma unroll
      for (int mt = 0; mt < 2; mt++)
        #pragma unroll
        for (int i = 0; i < 4; i++) rs[mt][i] += __shfl_xor(rs[mt][i], d, 64);
    if (l15 == 0){
      #pragma unroll
      for (int mt = 0; mt < 2; mt++)
        #pragma unroll
        for (int i = 0; i < 4; i++) dS[wn][(mt<<4) + (quad<<2) + i] = rs[mt][i];
    }
    __syncthreads();
    if (tid < 32){
      float nMask = (float)(1024 - (nch << 7));
      float ds = (dS[0][tid] + dS[1][tid]) + (dS[2][tid] + dS[3][tid])
                 + nMask*__expf(vvRow[tid] - mRow[tid]);
      denomS[(z << 10) + bm + tid] = ds;
      float dm = ds;
      #pragma unroll
      for (int d = 1; d < 32; d <<= 1) dm = fminf(dm, __shfl_xor(dm, d, 32));
      if (tid == 0) atomicMin(&stats[32*16], f2o(dm));
    }
  }
}

// pass 3: PV dequant-GEMM + direct causal attn f32 write. Reads q3 levels in
// A-fragment layout, n = clamp(rint(exp((q-zp)s - m)*rp)); attn = n*p4.scale
// written straight from registers (16 rows x 128B contiguous per wave instr,
// cached stores -> L2 merges the u/w half-sector pairs); af = f16(n*scale*
// 1024) feeds PV MFMA. Paired groups; no barriers in the main loop.
__global__ __launch_bounds__(256) void k_qk_pv(const unsigned short* __restrict__ q3buf,
                                               const _Float16* __restrict__ vT,
                                               float* __restrict__ ctx, float* __restrict__ attn,
                                               const unsigned* __restrict__ rowmax,
                                               const float* __restrict__ denomS, unsigned* stats){
  QK_IDS
  int j = blockIdx.x, z = blockIdx.y;
  int b = z >> 4, h = z & 15;
  LogitQ L = derive_logit(stats);
  FQP p4 = fqp(0.0f, 1.0f/dec_slot(stats, 32));
  float c1024 = p4.scale*1024.0f;
  float p4s = p4.scale;
  float zp3 = L.f3.zp, s3 = L.f3.scale;
  const _Float16* Vb = vT + (size_t)(b*8 + (h>>1))*131072;
  float* Cb = ctx + ((size_t)b << 10)*2048 + (size_t)h*128;
  float cmn = FLT_MAX, cmx = -FLT_MAX;
  for (int g = 0; g < 2; g++){
    int r = g ? (31 - j) : j;
    int bm = r << 5;
    int nch = (r >> 2) + 1;
    int aa = r >> 2, bb2 = r & 3;
    int cum = (aa + 1)*(2*aa + bb2);
    const unsigned short* Qu = q3buf + ((size_t)z*144 + cum)*4096;
    float* Ap = attn + ((size_t)z << 20) + (size_t)bm*1024;
    float mR[2], rpR[2];
    #pragma unroll
    for (int mt = 0; mt < 2; mt++){
      int row = (z << 10) + bm + (mt<<4) + l15;
      mR[mt] = chainU(o2f(rowmax[row]), L);
      rpR[mt] = p4.inv/denomS[row];
    }
    f4_t pacc[2][2];
    { f4_t zz = {0.f,0.f,0.f,0.f}; for (int i=0;i<2;i++) for (int jj=0;jj<2;jj++) pacc[i][jj]=zz; }
    for (int c = 0; c < nch; c++){
      const unsigned short* Qc = Qu + (size_t)c*4096;
      #pragma unroll
      for (int k0 = 0; k0 < 4; k0++){
        h8_t af[2], bf[2];
        #pragma unroll
        for (int mt = 0; mt < 2; mt++){
          const unsigned short* pr = Qc + ((mt<<4) + l15)*128 + (k0<<5) + (quad<<3);
          u16x4 u = *(const u16x4*)pr, w = *(const u16x4*)(pr + 4);
          h8_t o;
          f4_t va, vb;
          #pragma unroll
          for (int jj = 0; jj < 4; jj++){
            float a3u = ((float)u[jj] - zp3)*s3;
            float nu = fminf(fmaxf(rintf(__expf(a3u - mR[mt])*rpR[mt]), 0.0f), 65535.0f);
            o[jj] = (_Float16)(nu*c1024);
            va[jj] = nu*p4s;
            float a3w = ((float)w[jj] - zp3)*s3;
            float nw = fminf(fmaxf(rintf(__expf(a3w - mR[mt])*rpR[mt]), 0.0f), 65535.0f);
            o[jj+4] = (_Float16)(nw*c1024);
            vb[jj] = nw*p4s;
          }
          af[mt] = o;
          float* ap = Ap + (size_t)((mt<<4) + l15)*1024 + (c<<7) + (k0<<5) + (quad<<3);
          *(f4_t*)ap = va;
          *(f4_t*)(ap + 4) = vb;
        }
        #pragma unroll
        for (int nt = 0; nt < 2; nt++)
          bf[nt] = *(const h8_t*)(Vb + (size_t)((wn<<5) + (nt<<4) + l15)*1024 + (c<<7) + (k0<<5) + (quad<<3));
        #pragma unroll
        for (int mt = 0; mt < 2; mt++)
          #pragma unroll
          for (int nt = 0; nt < 2; nt++)
            pacc[mt][nt] = __builtin_amdgcn_mfma_f32_16x16x32_f16(af[mt], bf[nt], pacc[mt][nt], 0, 0, 0);
      }
    }
    #pragma unroll
    for (int mt = 0; mt < 2; mt++)
      #pragma unroll
      for (int nt = 0; nt < 2; nt++){
        int Cc = (wn<<5) + (nt<<4) + l15;
        #pragma unroll
        for (int i = 0; i < 4; i++){
          int R = bm + (mt<<4) + (quad<<2) + i;
          float v = pacc[mt][nt][i]*(1.0f/1024.0f);
          Cb[(size_t)R*2048 + Cc] = v;
          cmn = fminf(cmn, v); cmx = fmaxf(cmx, v);
        }
      }
  }
  __shared__ float red[256];
  float bmn = bred_min(cmn, red), bmx = bred_max(cmx, red);
  if (tid == 0){ atomicMin(&stats[36*16], f2o(bmn)); atomicMax(&stats[37*16], f2o(bmx)); }
}

// masked-region zero-fill: paired groups (j, 31-j) -> uniform 114 KB/block.
// 1 KB contiguous per wave store (proven round-5 pattern).
__global__ __launch_bounds__(256) void k_attn_zero(float* __restrict__ attn){
  int j = blockIdx.x, z = blockIdx.y;
  int lane = threadIdx.x & 63, wn = threadIdx.x >> 6;
  f4_t zz = {0.f,0.f,0.f,0.f};
  #pragma unroll
  for (int g = 0; g < 2; g++){
    int r = g ? (31 - j) : j;
    int nch = (r >> 2) + 1;
    int col0 = nch << 7;
    if (col0 >= 1024) continue;
    float* Cb = attn + ((size_t)z << 20) + ((size_t)(r << 5))*1024;
    for (int rr = wn; rr < 32; rr += 4){
      float* rowp = Cb + (size_t)rr*1024;
      for (int c = col0 + (lane << 2); c < 1024; c += 256)
        __builtin_nontemporal_store(zz, (f4_t*)(rowp + c));
    }
  }
}

// ===========================================================================

// fq16(A) then per-128 rmsnorm; writes (B,NH,S,D) fp32; reduces full+half ranges
__global__ __launch_bounds__(256) void k_rms(const float* __restrict__ lin, float* __restrict__ buf,
                                             const float* __restrict__ gw, unsigned* stats,
                                             int slot_lin, int slot_out, int NHh, int rows){
  FQP pA = fqp(dec_slot(stats, slot_lin), dec_slot(stats, slot_lin+1));
  int lane = threadIdx.x & 63;
  int wv = (blockIdx.x*256 + threadIdx.x) >> 6;
  int nwv = (gridDim.x*256) >> 6;
  float w0 = gw[lane], w1 = gw[lane + 64];
  float fmn = FLT_MAX, fmx = -FLT_MAX, hmn = FLT_MAX, hmx = -FLT_MAX;
  for (int r = wv; r < rows; r += nwv){
    int h = r % NHh; int rem = r / NHh; int s2 = rem & 1023; int b = rem >> 10;
    const float* src = lin + (size_t)r*128;
    float x0 = fqa(src[lane], pA), x1 = fqa(src[lane + 64], pA);
    float ss = x0*x0 + x1*x1;
    #pragma unroll
    for (int m = 1; m < 64; m <<= 1) ss += __shfl_xor(ss, m, 64);
    float rr = 1.0f/sqrtf(ss*(1.0f/128.0f) + 1e-6f);
    float y0 = x0*rr*w0, y1 = x1*rr*w1;
    float* dst = buf + ((size_t)((b*NHh + h) << 10) + s2)*128;
    dst[lane] = y0; dst[lane + 64] = y1;
    fmn = fminf(fmn, fminf(y0, y1)); fmx = fmaxf(fmx, fmaxf(y0, y1));
    hmn = fminf(hmn, y1); hmx = fmaxf(hmx, y1);
  }
  __shared__ float red[256];
  float a = bred_min(fmn, red), bb = bred_max(fmx, red);
  float c = bred_min(hmn, red), d = bred_max(hmx, red);
  if (threadIdx.x == 0){
    atomicMin(&stats[slot_out*16], f2o(a));     atomicMax(&stats[(slot_out+1)*16], f2o(bb));
    atomicMin(&stats[(slot_out+2)*16], f2o(c)); atomicMax(&stats[(slot_out+3)*16], f2o(d));
  }
}

struct RopeQ { FQP B, C, E, F; };
__device__ RopeQ derive_rope(const unsigned* st, int base){
  float ymn = dec_slot(st, base),   ymx = dec_slot(st, base+1);
  float y2mn = dec_slot(st, base+2), y2mx = dec_slot(st, base+3);
  RopeQ r;
  r.B = fqp(ymn, ymx);
  float zmn = fqa(ymn, r.B), zmx = fqa(ymx, r.B);
  r.C = fqp(zmn, zmx);
  float zlo = fqa(zmn, r.C), zhi = fqa(zmx, r.C);
  float z2lo = fqa(fqa(y2mn, r.B), r.C), z2hi = fqa(fqa(y2mx, r.B), r.C);
  r.E = fqp(-z2hi, -z2lo);
  float nlo = fqa(-z2hi, r.E), nhi = fqa(-z2lo, r.E);
  r.F = fqp_raw(fminf(fminf(zlo, nlo), 0.0f), fmaxf(fmaxf(zhi, nhi), 0.0f));
  return r;
}

// merged RoPE: blocks [0,1024) -> Q (slots 8/16/24, NHh=16, 32768 rows),
// blocks [1024,1536) -> K (slots 12/20/26, NHh=8, 16384 rows).
__global__ __launch_bounds__(256) void k_rope(float* __restrict__ bufq, float* __restrict__ bufk,
                                              const float* __restrict__ cosp, const float* __restrict__ sinp,
                                              unsigned* stats, int do_write){
  int isK = (blockIdx.x >= 1024);
  float* buf = isK ? bufk : bufq;
  int slot_norm = isK ? 12 : 8, slot_prod = isK ? 20 : 16, slot_sum = isK ? 26 : 24;
  int NHh = isK ? 8 : 16, rows = isK ? 16384 : 32768;
  int bid = isK ? (blockIdx.x - 1024) : blockIdx.x;
  int nblk = isK ? 512 : 1024;
  RopeQ R = derive_rope(stats, slot_norm);
  FQP pD, pG;
  if (do_write){
    pD = fqp(dec_slot(stats, slot_prod),   dec_slot(stats, slot_prod+1));
    pG = fqp(dec_slot(stats, slot_prod+2), dec_slot(stats, slot_prod+3));
  }
  int lane = threadIdx.x & 63;
  int wv = (bid*256 + threadIdx.x) >> 6, nwv = (nblk*256) >> 6;
  float m0 = FLT_MAX, M0 = -FLT_MAX, m1 = FLT_MAX, M1 = -FLT_MAX;
  for (int r = wv; r < rows; r += nwv){
    int s2 = r & 1023; int bh = r >> 10; int b = bh/NHh;
    float* base = buf + (size_t)r*128;
    float y0 = base[lane], y1 = base[lane + 64];
    float z0 = fqa(fqa(y0, R.B), R.C), z1 = fqa(fqa(y1, R.B), R.C);
    const float* cr = cosp + (size_t)((b << 10) + s2)*128;
    const float* sr = sinp + (size_t)((b << 10) + s2)*128;
    float c0 = cr[lane], c1 = cr[lane + 64], sn0 = sr[lane], sn1 = sr[lane + 64];
    float pc0 = z0*c0, pc1 = z1*c1;
    float rh0 = fqa(fqa(-z1, R.E), R.F);
    float rh1 = fqa(z0, R.F);
    float ps0 = rh0*sn0, ps1 = rh1*sn1;
    if (!do_write){
      m0 = fminf(m0, fminf(pc0, pc1)); M0 = fmaxf(M0, fmaxf(pc0, pc1));
      m1 = fminf(m1, fminf(ps0, ps1)); M1 = fmaxf(M1, fmaxf(ps0, ps1));
    } else {
      float sv0 = fqa(pc0, pD) + fqa(ps0, pG);
      float sv1 = fqa(pc1, pD) + fqa(ps1, pG);
      base[lane] = sv0; base[lane + 64] = sv1;
      m0 = fminf(m0, fminf(sv0, sv1)); M0 = fmaxf(M0, fmaxf(sv0, sv1));
    }
  }
  __shared__ float red[256];
  if (!do_write){
    float a = bred_min(m0, red), bb = bred_max(M0, red);
    float c = bred_min(m1, red), d = bred_max(M1, red);
    if (threadIdx.x == 0){
      atomicMin(&stats[slot_prod*16], f2o(a));     atomicMax(&stats[(slot_prod+1)*16], f2o(bb));
      atomicMin(&stats[(slot_prod+2)*16], f2o(c)); atomicMax(&stats[(slot_prod+3)*16], f2o(d));
    }
  } else {
    float a = bred_min(m0, red), bb = bred_max(M0, red);
    if (threadIdx.x == 0){ atomicMin(&stats[slot_sum*16], f2o(a)); atomicMax(&stats[(slot_sum+1)*16], f2o(bb)); }
  }
}

// V transpose + fq8(fq16) -> f16: vT[b][kv][d][t]
__global__ __launch_bounds__(256) void k_vT(const float* __restrict__ vlin, _Float16* __restrict__ vT,
                                            const unsigned* stats){
  FQP pv = fqp(dec_slot(stats, 6), dec_slot(stats, 7));
  float vlo = fqa(dec_slot(stats, 6), pv), vhi = fqa(dec_slot(stats, 7), pv);
  float v8s = fmaxf(fmaxf(fabsf(vlo), fabsf(vhi))/127.0f, 1e-12f), v8si = 1.0f/v8s;
  __shared__ float tile[64][65];
  int bkv = blockIdx.z, t0 = blockIdx.x << 6, d0 = blockIdx.y << 6;
  int b = bkv >> 3, kv = bkv & 7;
  const float* src = vlin + ((size_t)(b << 10))*1024 + (size_t)kv*128;
  int tx = threadIdx.x & 63, tq = threadIdx.x >> 6;
  #pragma unroll
  for (int i = 0; i < 16; i++){
    int tt = (i << 2) + tq;
    float x = src[(size_t)(t0 + tt)*1024 + d0 + tx];
    tile[tx][tt] = fq8(fqa(x, pv), v8s, v8si);
  }
  __syncthreads();
  _Float16* dst = vT + (size_t)bkv*131072;
  #pragma unroll
  for (int i = 0; i < 16; i++){
    int dd = (i << 2) + tq;
    dst[(size_t)(d0 + dd)*1024 + t0 + tx] = (_Float16)tile[dd][tx];
  }
}

extern "C" void kernel_launch(void* const* d_in, const int* in_sizes, int n_in,
                              void* d_out, int out_size, void* d_ws, size_t ws_size,
                              hipStream_t stream){
  (void)in_sizes; (void)n_in; (void)out_size; (void)ws_size;
  const float* hs   = (const float*)d_in[0];
  const float* cosp = (const float*)d_in[1];
  const float* sinp = (const float*)d_in[2];
  const float* Wq   = (const float*)d_in[4];
  const float* Wk   = (const float*)d_in[5];
  const float* Wv   = (const float*)d_in[6];
  const float* Wo   = (const float*)d_in[7];
  const float* qnw  = (const float*)d_in[8];
  const float* knw  = (const float*)d_in[9];

  float* outp = (float*)d_out;
  float* attn = outp + 4194304;      // final quantized softmax

  const size_t MEG = 1u << 20;       // floats
  float* wsf = (float*)d_ws;
  _Float16* woq_h = (_Float16*)(wsf + 0);
  _Float16* wqq_h = (_Float16*)(wsf + 2*MEG);
  _Float16* wkq_h = (_Float16*)(wsf + 4*MEG);
  _Float16* wvq_h = (_Float16*)(wsf + 5*MEG);
  _Float16* hsq_h = (_Float16*)(wsf + 6*MEG);
  float* qlin = wsf + 8*MEG;  float* ctx = qlin;   // ctx reuses qlin
  float* klin = wsf + 12*MEG;
  float* vlin = wsf + 14*MEG;
  float* qbuf = wsf + 16*MEG;
  float* kbuf = wsf + 20*MEG;
  _Float16* q_h   = (_Float16*)(wsf + 22*MEG);
  _Float16* k_h   = (_Float16*)(wsf + 24*MEG);
  _Float16* vT_h  = (_Float16*)(wsf + 25*MEG);
  _Float16* ctx_h = (_Float16*)(wsf + 26*MEG);
  unsigned* rowmin = (unsigned*)(wsf + 28*MEG);
  unsigned* rowmax = (unsigned*)(wsf + 28*MEG + 32768);
  float* denomS = wsf + 28*MEG + 65536;
  unsigned* stats = (unsigned*)(wsf + 28*MEG + 98304);
  // q3 levels: 32 z * 144 units * 4096 u16 = 36 MB. Overlays klin/vlin/qbuf/
  // kbuf (wsf+12M..21M floats) -- all dead before k_qk_denom writes it.
  unsigned short* q3buf = (unsigned short*)(wsf + 12*MEG);

  k_init<<<4, 256, 0, stream>>>(stats);

  // weight quant (blocks 0..12287) + hs minmax (blocks 12288..13311)
  k_quantw4<<<13312, 256, 0, stream>>>(Wq, Wk, Wv, Wo, wqq_h, wkq_h, wvq_h, woq_h, hs, stats);

  k_fq_ew16<<<4096, 256, 0, stream>>>(hs, hsq_h, stats, 0);

  // fused Q/K/V projections (512 blocks -> 2 blocks/CU, BK=64), stats fused
  k_hgemm_qkv<<<dim3(8, 16, 4), 256, 0, stream>>>(hsq_h, wqq_h, wkq_h, wvq_h,
                                                  qlin, klin, vlin, 2048, stats);

  // fq16 + rmsnorm (fp32) + range reductions
  k_rms<<<1024, 256, 0, stream>>>(qlin, qbuf, qnw, stats, 2, 8, 16, 32768);
  k_rms<<<512, 256, 0, stream>>>(klin, kbuf, knw, stats, 4, 12, 8, 16384);

  // RoPE: merged q+k range pass then merged write pass
  k_rope<<<1536, 256, 0, stream>>>(qbuf, kbuf, cosp, sinp, stats, 0);
  k_rope<<<1536, 256, 0, stream>>>(qbuf, kbuf, cosp, sinp, stats, 1);

  // merged operand conversion for QK; V transpose
  k_fq_qk<<<6144, 256, 0, stream>>>(qbuf, kbuf, q_h, k_h, stats);
  k_vT<<<dim3(16, 2, 16), 256, 0, stream>>>(vlin, vT_h, stats);

  // attention: stats (full sweep, slot35 fused) -> denom (+q3 store, slot32
  // fused) -> pv (dequant-GEMM + causal attn write) -> masked zero-fill.
  k_qk_stats<<<dim3(32, 32), 256, 0, stream>>>(q_h, k_h, stats, rowmin, rowmax);
  k_qk_denom<<<dim3(16, 32), 256, 0, stream>>>(q_h, k_h, rowmin, rowmax, denomS, q3buf, stats);
  k_qk_pv<<<dim3(16, 32), 256, 0, stream>>>(q3buf, vT_h, ctx, attn, rowmax, denomS, stats);
  k_attn_zero<<<dim3(16, 32), 256, 0, stream>>>(attn);

  // ctx (stats fused in PV) -> f16 -> O-proj (128x64 tiles, 2 blocks/CU, BK=64)
  k_fq_ew16<<<4096, 256, 0, stream>>>(ctx, ctx_h, stats, 36);
  k_hgemm_o<<<dim3(32, 16), 256, 0, stream>>>(ctx_h, woq_h, outp);
}

// Round 10
// 550.659 us; speedup vs baseline: 1.5241x; 1.0707x over previous
//
#include <hip/hip_runtime.h>
#include <cfloat>
#include <cmath>

// ---------------------------------------------------------------------------
// Qwen3Attention fake-quant forward. B=2 S=1024 HID=2048 NH=16 NKV=8 D=128.
// Round 15 (resubmit; round-9 bench was an infra failure): (a) stats pass
// split into below-diag / diag / above-diag regions (2 accum ops/elem
// instead of 3.5; global max = max(causal,masked), order-free -> bit-exact);
// (b) QKV proj 128x64 tiles, grid (16,16,4) = 4 blocks/CU; (c) launch folds:
// attn zero-fill into stats launch, rms q+k merged, vT into fq_qk launch.
// 13 launches total.
// ---------------------------------------------------------------------------

#define FQ_EPS      1.5259021896696422e-09f   // 0.0001/65535
#define SCALING_F   0.08838834764831845f      // 128**-0.5
#define S_LEN       1024

typedef _Float16 h8_t __attribute__((ext_vector_type(8)));
typedef _Float16 h4_t __attribute__((ext_vector_type(4)));
typedef float    f4_t __attribute__((ext_vector_type(4)));
typedef unsigned short u16x4 __attribute__((ext_vector_type(4)));

// ---- float <-> order-preserving unsigned encoding (for atomic min/max) ----
__device__ __forceinline__ unsigned f2o(float f){
  unsigned u = __float_as_uint(f);
  return (u & 0x80000000u) ? ~u : (u | 0x80000000u);
}
__device__ __forceinline__ float o2f(unsigned u){
  return __uint_as_float((u & 0x80000000u) ? (u ^ 0x80000000u) : ~u);
}
__device__ __forceinline__ float dec_slot(const unsigned* st, int s){ return o2f(st[s*16]); }

// ---- fq16 helpers ----
struct FQP { float scale, zp, inv; };
__device__ __forceinline__ FQP fqp_raw(float mn, float mx){
  FQP p; p.scale = fmaxf((mx - mn)/65535.0f, FQ_EPS); p.zp = rintf(-mn/p.scale);
  p.inv = 1.0f/p.scale; return p;
}
__device__ __forceinline__ FQP fqp(float mn0, float mx0){
  return fqp_raw(fminf(mn0, 0.0f), fmaxf(mx0, 0.0f));
}
__device__ __forceinline__ float fqa(float x, FQP p){
  float q = rintf(x*p.inv) + p.zp;
  q = fminf(fmaxf(q, 0.0f), 65535.0f);
  return (q - p.zp)*p.scale;
}
__device__ __forceinline__ float fq8(float x, float s, float si){
  return fminf(fmaxf(rintf(x*si), -128.0f), 127.0f)*s;
}

// ---- block reductions (blockDim == 256) ----
__device__ __forceinline__ float bred_min(float v, float* red){
  int tid = threadIdx.x; red[tid] = v; __syncthreads();
  for (int s = 128; s > 0; s >>= 1){ if (tid < s) red[tid] = fminf(red[tid], red[tid+s]); __syncthreads(); }
  float r = red[0]; __syncthreads(); return r;
}
__device__ __forceinline__ float bred_max(float v, float* red){
  int tid = threadIdx.x; red[tid] = v; __syncthreads();
  for (int s = 128; s > 0; s >>= 1){ if (tid < s) red[tid] = fmaxf(red[tid], red[tid+s]); __syncthreads(); }
  float r = red[0]; __syncthreads(); return r;
}

// ---- stats slot map (even=min, odd=max) ----
// 0/1 hs | 2/3 qlin | 4/5 klin | 6/7 vlin | 8/9 qn | 10/11 qn2 | 12/13 kn | 14/15 kn2
// 16/17 q*c | 18/19 qrh*s | 20/21 k*c | 22/23 krh*s | 24/25 qsum | 26/27 ksum
// 28/29 logits | 31 unmaskedMax | 32 denomMin | 35 maxOfRowMins | 36/37 ctx

__global__ void k_init(unsigned* stats){
  int i = blockIdx.x*blockDim.x + threadIdx.x;
  if (i < 1024) stats[i] = (((i & 15) == 0) && (((i >> 4) & 1) == 0)) ? 0xFFFFFFFFu : 0u;
}

// lpbq weight quantization -> f16 (blocks < 12288) + hs global minmax
// (blocks >= 12288, grid-stride identical to the old k_minmax -> bit-exact).
__global__ __launch_bounds__(256) void k_quantw4(const float* __restrict__ Wq, const float* __restrict__ Wk,
                                                 const float* __restrict__ Wv, const float* __restrict__ Wo,
                                                 _Float16* __restrict__ Qh, _Float16* __restrict__ Kh,
                                                 _Float16* __restrict__ Vh, _Float16* __restrict__ Oh,
                                                 const float* __restrict__ hs, unsigned* stats){
  int bx = blockIdx.x;
  if (bx >= 12288){
    float mn = FLT_MAX, mx = -FLT_MAX;
    for (int i = (bx - 12288)*256 + threadIdx.x; i < 4194304; i += 262144){
      float v = hs[i]; mn = fminf(mn, v); mx = fmaxf(mx, v);
    }
    __shared__ float red[256];
    float bmn = bred_min(mn, red), bmx = bred_max(mx, red);
    if (threadIdx.x == 0){ atomicMin(&stats[0], f2o(bmn)); atomicMax(&stats[16], f2o(bmx)); }
    return;
  }
  const float* W; _Float16* Wh; int base;
  if (bx < 4096){ W = Wq; Wh = Qh; base = 0; }
  else if (bx < 6144){ W = Wk; Wh = Kh; base = 4096; }
  else if (bx < 8192){ W = Wv; Wh = Vh; base = 6144; }
  else { W = Wo; Wh = Oh; base = 8192; }
  int i = (bx - base)*256 + threadIdx.x;
  float4 v = ((const float4*)W)[i];
  float am = fmaxf(fmaxf(fabsf(v.x), fabsf(v.y)), fmaxf(fabsf(v.z), fabsf(v.w)));
  #pragma unroll
  for (int m = 1; m < 8; m <<= 1) am = fmaxf(am, __shfl_xor(am, m, 64));
  float s = fmaxf(am/7.0f, 1e-12f), si = 1.0f/s;
  h4_t o;
  o[0] = (_Float16)(fminf(fmaxf(rintf(v.x*si), -8.0f), 7.0f)*s);
  o[1] = (_Float16)(fminf(fmaxf(rintf(v.y*si), -8.0f), 7.0f)*s);
  o[2] = (_Float16)(fminf(fmaxf(rintf(v.z*si), -8.0f), 7.0f)*s);
  o[3] = (_Float16)(fminf(fmaxf(rintf(v.w*si), -8.0f), 7.0f)*s);
  *(h4_t*)(Wh + ((size_t)i << 2)) = o;
}

// fq16 elementwise -> f16, 4 elems/thread (used for hs and ctx)
__global__ __launch_bounds__(256) void k_fq_ew16(const float* __restrict__ x, _Float16* __restrict__ y,
                                                 const unsigned* stats, int slot){
  FQP p = fqp(dec_slot(stats, slot), dec_slot(stats, slot+1));
  int i = blockIdx.x*256 + threadIdx.x;
  float4 v = ((const float4*)x)[i];
  h4_t o;
  o[0] = (_Float16)fqa(v.x, p); o[1] = (_Float16)fqa(v.y, p);
  o[2] = (_Float16)fqa(v.z, p); o[3] = (_Float16)fqa(v.w, p);
  *(h4_t*)(y + ((size_t)i << 2)) = o;
}

// merged q/k operand conversion + V transpose:
// blocks [0,4096)    -> fq16(qbuf)->q_h (slot 24)
// blocks [4096,6144) -> fq8(fq16(kbuf))->k_h (slot 26)
// blocks [6144,6656) -> vT tile (old grid (16,2,16) linearized)
__global__ __launch_bounds__(256) void k_fq_qk_vt(const float* __restrict__ qbuf, const float* __restrict__ kbuf,
                                                  const float* __restrict__ vlin,
                                                  _Float16* __restrict__ q_h, _Float16* __restrict__ k_h,
                                                  _Float16* __restrict__ vT,
                                                  const unsigned* stats){
  __shared__ float tile[64][65];
  int bx = blockIdx.x;
  if (bx < 4096){
    FQP p = fqp(dec_slot(stats, 24), dec_slot(stats, 25));
    int i = bx*256 + threadIdx.x;
    float4 v = ((const float4*)qbuf)[i];
    h4_t o;
    o[0] = (_Float16)fqa(v.x, p); o[1] = (_Float16)fqa(v.y, p);
    o[2] = (_Float16)fqa(v.z, p); o[3] = (_Float16)fqa(v.w, p);
    *(h4_t*)(q_h + ((size_t)i << 2)) = o;
  } else if (bx < 6144){
    FQP p = fqp(dec_slot(stats, 26), dec_slot(stats, 27));
    float lo = fqa(dec_slot(stats, 26), p), hi = fqa(dec_slot(stats, 27), p);
    float s8 = fmaxf(fmaxf(fabsf(lo), fabsf(hi))/127.0f, 1e-12f), s8i = 1.0f/s8;
    int i = (bx - 4096)*256 + threadIdx.x;
    float4 v = ((const float4*)kbuf)[i];
    h4_t o;
    o[0] = (_Float16)fq8(fqa(v.x, p), s8, s8i); o[1] = (_Float16)fq8(fqa(v.y, p), s8, s8i);
    o[2] = (_Float16)fq8(fqa(v.z, p), s8, s8i); o[3] = (_Float16)fq8(fqa(v.w, p), s8, s8i);
    *(h4_t*)(k_h + ((size_t)i << 2)) = o;
  } else {
    int idx = bx - 6144;                 // [0,512): x=idx&15, y=(idx>>4)&1, z=idx>>5
    int t0 = (idx & 15) << 6, d0 = ((idx >> 4) & 1) << 6, bkv = idx >> 5;
    FQP pv = fqp(dec_slot(stats, 6), dec_slot(stats, 7));
    float vlo = fqa(dec_slot(stats, 6), pv), vhi = fqa(dec_slot(stats, 7), pv);
    float v8s = fmaxf(fmaxf(fabsf(vlo), fabsf(vhi))/127.0f, 1e-12f), v8si = 1.0f/v8s;
    int b = bkv >> 3, kv = bkv & 7;
    const float* src = vlin + ((size_t)(b << 10))*1024 + (size_t)kv*128;
    int tx = threadIdx.x & 63, tq = threadIdx.x >> 6;
    #pragma unroll
    for (int i = 0; i < 16; i++){
      int tt = (i << 2) + tq;
      float x = src[(size_t)(t0 + tt)*1024 + d0 + tx];
      tile[tx][tt] = fq8(fqa(x, pv), v8s, v8si);
    }
    __syncthreads();
    _Float16* dst = vT + (size_t)bkv*131072;
    #pragma unroll
    for (int i = 0; i < 16; i++){
      int dd = (i << 2) + tq;
      dst[(size_t)(d0 + dd)*1024 + t0 + tx] = (_Float16)tile[dd][tx];
    }
  }
}

// ================= f16 MFMA GEMM core for projections (NT) =================
// async staging: LDS dest is wave-uniform base + lane*16B (constraint-safe).
#define GLDS16(g, l) __builtin_amdgcn_global_load_lds( \
    (__attribute__((address_space(1))) unsigned int*)(g), \
    (__attribute__((address_space(3))) unsigned int*)(l), 16, 0, 0)

__device__ __forceinline__ void stage_tile(const _Float16* __restrict__ src, int ld, int k0,
                                           _Float16* __restrict__ dst){
  #pragma unroll
  for (int it = 0; it < 2; it++){
    int c = threadIdx.x + (it << 8);
    int row = c >> 2, off = (c & 3) << 3;
    GLDS16(src + (size_t)row*ld + k0 + off, dst + (c << 3));
  }
}

// C/D lane map (m89-verified): D[row=(quad*4+reg)][col=l15].

// fused Q/K/V projections, 128x64 tiles: grid (16,16,4) = 1024 blocks = 4/CU.
// z=0,1 -> Q col-halves (slot 2), z=2 -> K (slot 4), z=3 -> V (slot 6).
// BK=64 (two 32-wide halves per barrier pair); per-element MFMA chain
// identical to the 128x128/BK=32 version -> bit-exact.
__global__ __launch_bounds__(256) void k_hgemm_qkv(const _Float16* __restrict__ A,
                                                   const _Float16* __restrict__ Bq,
                                                   const _Float16* __restrict__ Bk,
                                                   const _Float16* __restrict__ Bv,
                                                   float* __restrict__ Cq, float* __restrict__ Ck,
                                                   float* __restrict__ Cv,
                                                   int K, unsigned* stats){
  __shared__ __align__(16) _Float16 As[4096], As2[4096], Bs[2048], Bs2[2048];
  __shared__ float red[256];
  f4_t acc[4][2];
  { f4_t zz = {0.f,0.f,0.f,0.f};
    for (int i = 0; i < 4; i++) for (int j = 0; j < 2; j++) acc[i][j] = zz; }
  int lane = threadIdx.x & 63, wave = threadIdx.x >> 6;
  int wm = wave & 1, wn = wave >> 1, quad = lane >> 4, l15 = lane & 15;
  int z = blockIdx.z;
  const _Float16* Bmat; float* C; int slotC, N, cbase;
  if (z < 2){ Bmat = Bq + (((size_t)z << 10))*K; C = Cq; slotC = 2; N = 2048; cbase = z << 10; }
  else if (z == 2){ Bmat = Bk; C = Ck; slotC = 4; N = 1024; cbase = 0; }
  else { Bmat = Bv; C = Cv; slotC = 6; N = 1024; cbase = 0; }
  int bm = blockIdx.y << 7, bn = blockIdx.x << 6;
  const _Float16* Ab = A + (size_t)bm*K;
  const _Float16* Bb = Bmat + (size_t)bn*K;
  for (int k0 = 0; k0 < K; k0 += 64){
    __syncthreads();
    stage_tile(Ab, K, k0, As);
    stage_tile(Ab, K, k0 + 32, As2);
    { int c = threadIdx.x;                       // 64 rows x 32 k = 4 KB per half
      int row = c >> 2, off = (c & 3) << 3;
      GLDS16(Bb + (size_t)row*K + k0 + off, Bs + (c << 3));
      GLDS16(Bb + (size_t)row*K + k0 + 32 + off, Bs2 + (c << 3)); }
    __syncthreads();
    #pragma unroll
    for (int half = 0; half < 2; half++){
      const _Float16* Ah = half ? As2 : As;
      const _Float16* Bh = half ? Bs2 : Bs;
      h8_t af[4], bf[2];
      #pragma unroll
      for (int mt = 0; mt < 4; mt++)
        af[mt] = *(const h8_t*)(Ah + ((((wm<<6) + (mt<<4) + l15)) << 5) + (quad << 3));
      #pragma unroll
      for (int nt = 0; nt < 2; nt++)
        bf[nt] = *(const h8_t*)(Bh + ((((wn<<5) + (nt<<4) + l15)) << 5) + (quad << 3));
      #pragma unroll
      for (int mt = 0; mt < 4; mt++)
        #pragma unroll
        for (int nt = 0; nt < 2; nt++)
          acc[mt][nt] = __builtin_amdgcn_mfma_f32_16x16x32_f16(af[mt], bf[nt], acc[mt][nt], 0, 0, 0);
    }
  }
  float mn = FLT_MAX, mx = -FLT_MAX;
  #pragma unroll
  for (int mt = 0; mt < 4; mt++)
    #pragma unroll
    for (int nt = 0; nt < 2; nt++){
      int Cc = cbase + bn + (wn<<5) + (nt<<4) + l15;
      #pragma unroll
      for (int i = 0; i < 4; i++){
        int R = bm + (wm<<6) + (mt<<4) + (quad<<2) + i;
        float v = acc[mt][nt][i];
        C[(size_t)R*N + Cc] = v;
        mn = fminf(mn, v); mx = fmaxf(mx, v);
      }
    }
  float bmn = bred_min(mn, red), bmx = bred_max(mx, red);
  if (threadIdx.x == 0){ atomicMin(&stats[slotC*16], f2o(bmn)); atomicMax(&stats[(slotC+1)*16], f2o(bmx)); }
}

// O-proj: 128x64 tiles, grid (32,16) = 512 blocks = 2 blocks/CU, BK=64.
__global__ __launch_bounds__(256) void k_hgemm_o(const _Float16* __restrict__ A,
                                                 const _Float16* __restrict__ B,
                                                 float* __restrict__ C){
  __shared__ __align__(16) _Float16 As[4096], As2[4096], Bs[2048], Bs2[2048];
  f4_t acc[4][2];
  { f4_t zz = {0.f,0.f,0.f,0.f};
    for (int i = 0; i < 4; i++) for (int j = 0; j < 2; j++) acc[i][j] = zz; }
  int lane = threadIdx.x & 63, wave = threadIdx.x >> 6;
  int wm = wave & 1, wn = wave >> 1, quad = lane >> 4, l15 = lane & 15;
  int bm = blockIdx.y << 7, bn = blockIdx.x << 6;
  const _Float16* Ab = A + (size_t)bm*2048;
  const _Float16* Bb = B + (size_t)bn*2048;
  for (int k0 = 0; k0 < 2048; k0 += 64){
    __syncthreads();
    stage_tile(Ab, 2048, k0, As);
    stage_tile(Ab, 2048, k0 + 32, As2);
    { int c = threadIdx.x;
      int row = c >> 2, off = (c & 3) << 3;
      GLDS16(Bb + (size_t)row*2048 + k0 + off, Bs + (c << 3));
      GLDS16(Bb + (size_t)row*2048 + k0 + 32 + off, Bs2 + (c << 3)); }
    __syncthreads();
    #pragma unroll
    for (int half = 0; half < 2; half++){
      const _Float16* Ah = half ? As2 : As;
      const _Float16* Bh = half ? Bs2 : Bs;
      h8_t af[4], bf[2];
      #pragma unroll
      for (int mt = 0; mt < 4; mt++)
        af[mt] = *(const h8_t*)(Ah + ((((wm<<6) + (mt<<4) + l15)) << 5) + (quad << 3));
      #pragma unroll
      for (int nt = 0; nt < 2; nt++)
        bf[nt] = *(const h8_t*)(Bh + ((((wn<<5) + (nt<<4) + l15)) << 5) + (quad << 3));
      #pragma unroll
      for (int mt = 0; mt < 4; mt++)
        #pragma unroll
        for (int nt = 0; nt < 2; nt++)
          acc[mt][nt] = __builtin_amdgcn_mfma_f32_16x16x32_f16(af[mt], bf[nt], acc[mt][nt], 0, 0, 0);
    }
  }
  #pragma unroll
  for (int mt = 0; mt < 4; mt++)
    #pragma unroll
    for (int nt = 0; nt < 2; nt++){
      int Cc = bn + (wn<<5) + (nt<<4) + l15;
      #pragma unroll
      for (int i = 0; i < 4; i++){
        int R = bm + (wm<<6) + (mt<<4) + (quad<<2) + i;
        C[(size_t)R*2048 + Cc] = acc[mt][nt][i];
      }
    }
}

// ====================== QK^T attention passes (32-row) =====================
// block = 256 thr (4 waves). A 32-row group r (0..31) covers q-rows
// [32r, 32r+32); it needs nch(r) = (r>>2)+1 K-chunks of 128. Wave wn owns
// cols [32*wn, 32*wn+32): acc[2][2]. Pairing (j, 31-j) -> constant 9
// chunk-units per block. q3 levels (post-f3 u16) are exact -> stored once by
// denom, consumed by pv (PV GEMM + attn f32 write) bit-exactly.
// causal unit index: cum(r) = (a+1)*(2a+b), a=r>>2, b=r&3; unit = cum + chunk.

#define QK_IDS \
  int lane = threadIdx.x & 63, wn = threadIdx.x >> 6; \
  int quad = lane >> 4, l15 = lane & 15; \
  int tid = threadIdx.x; (void)tid; (void)lane;

__device__ __forceinline__ void qk_load_a(const _Float16* __restrict__ Ab, int quad, int l15,
                                          h8_t Aq[2][4]){
  #pragma unroll
  for (int mt = 0; mt < 2; mt++)
    #pragma unroll
    for (int k0 = 0; k0 < 4; k0++)
      Aq[mt][k0] = *(const h8_t*)(Ab + (size_t)((mt<<4) + l15)*128 + (k0<<5) + (quad<<3));
}

__device__ __forceinline__ void qk_chunk32(const h8_t Aq[2][4], const _Float16* __restrict__ Kb,
                                           int bn, int wn, int quad, int l15, f4_t acc[2][2]){
  #pragma unroll
  for (int k0 = 0; k0 < 4; k0++){
    h8_t bf[2];
    #pragma unroll
    for (int nt = 0; nt < 2; nt++)
      bf[nt] = *(const h8_t*)(Kb + (size_t)(bn + (wn<<5) + (nt<<4) + l15)*128 + (k0<<5) + (quad<<3));
    #pragma unroll
    for (int mt = 0; mt < 2; mt++)
      #pragma unroll
      for (int nt = 0; nt < 2; nt++)
        acc[mt][nt] = __builtin_amdgcn_mfma_f32_16x16x32_f16(Aq[mt][k0], bf[nt], acc[mt][nt], 0, 0, 0);
  }
}

// pass 1 (+ masked attn zero-fill in blocks x>=32): region-split stats.
// Below-diag chunks: {rmv, rxv}. Above-diag: {rmv, rxm}. Diagonal only pays
// the causal compare. Globals: mn=min(rmv), mxU=max(rxv), mx=max(rxv,rxm)
// (each element in exactly one of rxv/rxm; min/max order-free -> bit-exact).
__global__ __launch_bounds__(256) void k_qk_stats(const _Float16* __restrict__ q_h, const _Float16* __restrict__ k_h,
                                                  unsigned* stats, unsigned* rowmin, unsigned* rowmax,
                                                  float* __restrict__ attn){
  QK_IDS
  int z = blockIdx.y;
  if (blockIdx.x >= 32){
    // masked-region zero-fill: paired groups (j, 31-j), 1KB/wave-instr.
    int j = blockIdx.x - 32;
    f4_t zz = {0.f,0.f,0.f,0.f};
    #pragma unroll
    for (int g = 0; g < 2; g++){
      int r = g ? (31 - j) : j;
      int nch = (r >> 2) + 1;
      int col0 = nch << 7;
      if (col0 >= 1024) continue;
      float* Cb = attn + ((size_t)z << 20) + ((size_t)(r << 5))*1024;
      for (int rr = wn; rr < 32; rr += 4){
        float* rowp = Cb + (size_t)rr*1024;
        for (int c = col0 + (lane << 2); c < 1024; c += 256)
          __builtin_nontemporal_store(zz, (f4_t*)(rowp + c));
      }
    }
    return;
  }
  int bm = blockIdx.x << 5;
  int b = z >> 4, h = z & 15;
  int cstar = (blockIdx.x >> 2) << 7;            // diagonal-chunk base
  const _Float16* Ab = q_h + (size_t)z*131072 + (size_t)bm*128;
  const _Float16* Kb = k_h + (size_t)(b*8 + (h>>1))*131072;
  h8_t Aq[2][4];
  qk_load_a(Ab, quad, l15, Aq);
  float rmv[2][4], rxv[2][4], rxm[2][4];
  #pragma unroll
  for (int mt = 0; mt < 2; mt++)
    #pragma unroll
    for (int i = 0; i < 4; i++){ rmv[mt][i] = FLT_MAX; rxv[mt][i] = -FLT_MAX; rxm[mt][i] = -FLT_MAX; }
  // fully causal chunks
  for (int bn = 0; bn < cstar; bn += 128){
    f4_t acc[2][2];
    { f4_t zz = {0.f,0.f,0.f,0.f}; for (int i=0;i<2;i++) for (int j=0;j<2;j++) acc[i][j]=zz; }
    qk_chunk32(Aq, Kb, bn, wn, quad, l15, acc);
    #pragma unroll
    for (int mt = 0; mt < 2; mt++)
      #pragma unroll
      for (int nt = 0; nt < 2; nt++)
        #pragma unroll
        for (int i = 0; i < 4; i++){
          float v = acc[mt][nt][i];
          rmv[mt][i] = fminf(rmv[mt][i], v);
          rxv[mt][i] = fmaxf(rxv[mt][i], v);
        }
  }
  // diagonal (mixed) chunk
  {
    int bn = cstar;
    f4_t acc[2][2];
    { f4_t zz = {0.f,0.f,0.f,0.f}; for (int i=0;i<2;i++) for (int j=0;j<2;j++) acc[i][j]=zz; }
    qk_chunk32(Aq, Kb, bn, wn, quad, l15, acc);
    #pragma unroll
    for (int mt = 0; mt < 2; mt++){
      int rb = bm + (mt<<4) + (quad<<2);
      #pragma unroll
      for (int nt = 0; nt < 2; nt++){
        int t = bn + (wn<<5) + (nt<<4) + l15;
        #pragma unroll
        for (int i = 0; i < 4; i++){
          float v = acc[mt][nt][i];
          rmv[mt][i] = fminf(rmv[mt][i], v);
          if (t <= rb + i) rxv[mt][i] = fmaxf(rxv[mt][i], v);
          else             rxm[mt][i] = fmaxf(rxm[mt][i], v);
        }
      }
    }
  }
  // fully masked chunks
  for (int bn = cstar + 128; bn < 1024; bn += 128){
    f4_t acc[2][2];
    { f4_t zz = {0.f,0.f,0.f,0.f}; for (int i=0;i<2;i++) for (int j=0;j<2;j++) acc[i][j]=zz; }
    qk_chunk32(Aq, Kb, bn, wn, quad, l15, acc);
    #pragma unroll
    for (int mt = 0; mt < 2; mt++)
      #pragma unroll
      for (int nt = 0; nt < 2; nt++)
        #pragma unroll
        for (int i = 0; i < 4; i++){
          float v = acc[mt][nt][i];
          rmv[mt][i] = fminf(rmv[mt][i], v);
          rxm[mt][i] = fmaxf(rxm[mt][i], v);
        }
  }
  #pragma unroll
  for (int d = 1; d < 16; d <<= 1)
    #pragma unroll
    for (int mt = 0; mt < 2; mt++)
      #pragma unroll
      for (int i = 0; i < 4; i++){
        rmv[mt][i] = fminf(rmv[mt][i], __shfl_xor(rmv[mt][i], d, 64));
        rxv[mt][i] = fmaxf(rxv[mt][i], __shfl_xor(rxv[mt][i], d, 64));
        rxm[mt][i] = fmaxf(rxm[mt][i], __shfl_xor(rxm[mt][i], d, 64));
      }
  __shared__ float rminS[4][32], rmaxS[4][32];
  if (l15 == 0){
    #pragma unroll
    for (int mt = 0; mt < 2; mt++)
      #pragma unroll
      for (int i = 0; i < 4; i++){
        int rl = (mt<<4) + (quad<<2) + i;
        rminS[wn][rl] = rmv[mt][i];
        rmaxS[wn][rl] = rxv[mt][i];
      }
  }
  __syncthreads();
  if (tid < 32){
    float a = fminf(fminf(rminS[0][tid], rminS[1][tid]), fminf(rminS[2][tid], rminS[3][tid]));
    float c = fmaxf(fmaxf(rmaxS[0][tid], rmaxS[1][tid]), fmaxf(rmaxS[2][tid], rmaxS[3][tid]));
    rowmin[(z << 10) + bm + tid] = f2o(a);
    rowmax[(z << 10) + bm + tid] = f2o(c);
    // maxOfRowMins (slot 35): width-32 shuffle max over this block's row-mins
    float am = a;
    #pragma unroll
    for (int d = 1; d < 32; d <<= 1) am = fmaxf(am, __shfl_xor(am, d, 32));
    if (tid == 0) atomicMax(&stats[35*16], f2o(am));
  }
  float mn = FLT_MAX, mxU = -FLT_MAX, mxM = -FLT_MAX;
  #pragma unroll
  for (int mt = 0; mt < 2; mt++)
    #pragma unroll
    for (int i = 0; i < 4; i++){
      mn = fminf(mn, rmv[mt][i]);
      mxU = fmaxf(mxU, rxv[mt][i]);
      mxM = fmaxf(mxM, rxm[mt][i]);
    }
  __shared__ float red[256];
  float bmn = bred_min(mn, red), bmU = bred_max(mxU, red), bmM = bred_max(mxM, red);
  if (tid == 0){
    atomicMin(&stats[28*16], f2o(bmn));
    atomicMax(&stats[29*16], f2o(fmaxf(bmU, bmM)));
    atomicMax(&stats[31*16], f2o(bmU));
  }
}

struct LogitQ { FQP f1, f2, fam, fvv, f3; float sc, c20; };
__device__ LogitQ derive_logit(const unsigned* st){
  LogitQ L;
  FQP ps = fqp(SCALING_F, SCALING_F); L.sc = fqa(SCALING_F, ps);
  FQP p20 = fqp(-20.0f, -20.0f);      L.c20 = fqa(-20.0f, p20);
  float gmn = dec_slot(st, 28), gmx = dec_slot(st, 29);
  float gU = dec_slot(st, 31), M2 = dec_slot(st, 35);
  L.f1 = fqp(gmn, gmx);
  float l1lo = fqa(gmn, L.f1), l1hi = fqa(gmx, L.f1);
  L.f2 = fqp(l1lo*L.sc, l1hi*L.sc);
  float amlo = fqa(fqa(gmn, L.f1)*L.sc, L.f2);
  float amhi = fqa(fqa(M2, L.f1)*L.sc, L.f2);
  L.fam = fqp(amlo, amhi);
  float vslo = fqa(amlo, L.fam) + L.c20, vshi = fqa(amhi, L.fam) + L.c20;
  L.fvv = fqp(vslo, vshi);
  float mn3 = fqa(vslo, L.fvv);
  float mx3 = fqa(fqa(gU, L.f1)*L.sc, L.f2);
  L.f3 = fqp(mn3, mx3);
  return L;
}
__device__ __forceinline__ float chainU(float raw, const LogitQ& L){
  return fqa(fqa(fqa(raw, L.f1)*L.sc, L.f2), L.f3);
}

// pass 2: per-row denominators + q3-level store (u16, causal-packed) +
// denomMin (slot 32) folded into the epilogue. Paired 32-row groups
// (j, 31-j) = 9 units/block. Skipped masked chunks contribute
// count*exp(vv-m) per row analytically.
__global__ __launch_bounds__(256) void k_qk_denom(const _Float16* __restrict__ q_h, const _Float16* __restrict__ k_h,
                                                  const unsigned* __restrict__ rowmin,
                                                  const unsigned* __restrict__ rowmax,
                                                  float* __restrict__ denomS,
                                                  unsigned short* __restrict__ q3buf,
                                                  unsigned* stats){
  QK_IDS
  int j = blockIdx.x, z = blockIdx.y;
  int b = z >> 4, h = z & 15;
  LogitQ L = derive_logit(stats);
  const _Float16* Kb = k_h + (size_t)(b*8 + (h>>1))*131072;
  __shared__ float mRow[32], vvRow[32], vvLev[32];
  __shared__ float dS[4][32];
  for (int g = 0; g < 2; g++){
    int r = g ? (31 - j) : j;
    int bm = r << 5;
    int nch = (r >> 2) + 1;
    int cstar = (r >> 2) << 7;          // diagonal-chunk base
    int aa = r >> 2, bb2 = r & 3;
    int cum = (aa + 1)*(2*aa + bb2);    // causal units before group r
    unsigned short* Qu = q3buf + ((size_t)z*144 + cum)*4096;
    __syncthreads();                    // prior group done with mRow/vvRow/dS
    if (tid < 32){
      int row = (z << 10) + bm + tid;
      mRow[tid] = chainU(o2f(rowmax[row]), L);
      float tr = fqa(fqa(o2f(rowmin[row]), L.f1)*L.sc, L.f2);
      float w = fqa(fqa(tr, L.fam) + L.c20, L.fvv);
      float lv = fminf(fmaxf(rintf(w*L.f3.inv) + L.f3.zp, 0.0f), 65535.0f);
      vvLev[tid] = lv;
      vvRow[tid] = (lv - L.f3.zp)*L.f3.scale;   // == fqa(w, f3)
    }
    const _Float16* Ab = q_h + (size_t)z*131072 + (size_t)bm*128;
    h8_t Aq[2][4];
    qk_load_a(Ab, quad, l15, Aq);
    __syncthreads();                    // mRow/vvRow/vvLev visible
    float rs[2][4];
    #pragma unroll
    for (int mt = 0; mt < 2; mt++)
      #pragma unroll
      for (int i = 0; i < 4; i++) rs[mt][i] = 0.0f;
    for (int bn = 0; bn < (nch << 7); bn += 128){
      f4_t acc[2][2];
      { f4_t zz = {0.f,0.f,0.f,0.f}; for (int i=0;i<2;i++) for (int jj=0;jj<2;jj++) acc[i][jj]=zz; }
      qk_chunk32(Aq, Kb, bn, wn, quad, l15, acc);
      unsigned short* Qc = Qu + (size_t)(bn >> 7)*4096;
      if (bn < cstar){
        // fully unmasked chunk: no causal select
        #pragma unroll
        for (int mt = 0; mt < 2; mt++){
          #pragma unroll
          for (int nt = 0; nt < 2; nt++){
            int cl = (wn<<5) + (nt<<4) + l15;
            #pragma unroll
            for (int i = 0; i < 4; i++){
              int rl = (mt<<4) + (quad<<2) + i;
              float a2 = fqa(fqa(acc[mt][nt][i], L.f1)*L.sc, L.f2);
              float lvl = fminf(fmaxf(rintf(a2*L.f3.inv) + L.f3.zp, 0.0f), 65535.0f);
              Qc[rl*128 + cl] = (unsigned short)lvl;
              float a3 = (lvl - L.f3.zp)*L.f3.scale;   // == fqa(a2, f3)
              rs[mt][i] += __expf(a3 - mRow[rl]);
            }
          }
        }
      } else {
        // diagonal (mixed) chunk: per-element causal select on the LEVEL
        #pragma unroll
        for (int mt = 0; mt < 2; mt++){
          #pragma unroll
          for (int nt = 0; nt < 2; nt++){
            int cl = (wn<<5) + (nt<<4) + l15;
            int t = bn + cl;
            #pragma unroll
            for (int i = 0; i < 4; i++){
              int rl = (mt<<4) + (quad<<2) + i;
              float a2 = fqa(fqa(acc[mt][nt][i], L.f1)*L.sc, L.f2);
              float lvl = fminf(fmaxf(rintf(a2*L.f3.inv) + L.f3.zp, 0.0f), 65535.0f);
              float qs = (t <= bm + rl) ? lvl : vvLev[rl];
              Qc[rl*128 + cl] = (unsigned short)qs;
              float a3 = (qs - L.f3.zp)*L.f3.scale;
              rs[mt][i] += __expf(a3 - mRow[rl]);
            }
          }
        }
      }
    }
    #pragma unroll
    for (int d = 1; d < 16; d <<= 1)
      #pragma unroll
      for (int mt = 0; mt < 2; mt++)
        #pragma unroll
        for (int i = 0; i < 4; i++) rs[mt][i] += __shfl_xor(rs[mt][i], d, 64);
    if (l15 == 0){
      #pragma unroll
      for (int mt = 0; mt < 2; mt++)
        #pragma unroll
        for (int i = 0; i < 4; i++) dS[wn][(mt<<4) + (quad<<2) + i] = rs[mt][i];
    }
    __syncthreads();
    if (tid < 32){
      float nMask = (float)(1024 - (nch << 7));
      float ds = (dS[0][tid] + dS[1][tid]) + (dS[2][tid] + dS[3][tid])
                 + nMask*__expf(vvRow[tid] - mRow[tid]);
      denomS[(z << 10) + bm + tid] = ds;
      float dm = ds;
      #pragma unroll
      for (int d = 1; d < 32; d <<= 1) dm = fminf(dm, __shfl_xor(dm, d, 32));
      if (tid == 0) atomicMin(&stats[32*16], f2o(dm));
    }
  }
}

// pass 3: PV dequant-GEMM + direct causal attn f32 write. Reads q3 levels in
// A-fragment layout, n = clamp(rint(exp((q-zp)s - m)*rp)); attn = n*p4.scale
// written straight from registers (cached stores -> L2 merges); af =
// f16(n*scale*1024) feeds PV MFMA. Paired groups; no main-loop barriers.
__global__ __launch_bounds__(256) void k_qk_pv(const unsigned short* __restrict__ q3buf,
                                               const _Float16* __restrict__ vT,
                                               float* __restrict__ ctx, float* __restrict__ attn,
                                               const unsigned* __restrict__ rowmax,
                                               const float* __restrict__ denomS, unsigned* stats){
  QK_IDS
  int j = blockIdx.x, z = blockIdx.y;
  int b = z >> 4, h = z & 15;
  LogitQ L = derive_logit(stats);
  FQP p4 = fqp(0.0f, 1.0f/dec_slot(stats, 32));
  float c1024 = p4.scale*1024.0f;
  float p4s = p4.scale;
  float zp3 = L.f3.zp, s3 = L.f3.scale;
  const _Float16* Vb = vT + (size_t)(b*8 + (h>>1))*131072;
  float* Cb = ctx + ((size_t)b << 10)*2048 + (size_t)h*128;
  float cmn = FLT_MAX, cmx = -FLT_MAX;
  for (int g = 0; g < 2; g++){
    int r = g ? (31 - j) : j;
    int bm = r << 5;
    int nch = (r >> 2) + 1;
    int aa = r >> 2, bb2 = r & 3;
    int cum = (aa + 1)*(2*aa + bb2);
    const unsigned short* Qu = q3buf + ((size_t)z*144 + cum)*4096;
    float* Ap = attn + ((size_t)z << 20) + (size_t)bm*1024;
    float mR[2], rpR[2];
    #pragma unroll
    for (int mt = 0; mt < 2; mt++){
      int row = (z << 10) + bm + (mt<<4) + l15;
      mR[mt] = chainU(o2f(rowmax[row]), L);
      rpR[mt] = p4.inv/denomS[row];
    }
    f4_t pacc[2][2];
    { f4_t zz = {0.f,0.f,0.f,0.f}; for (int i=0;i<2;i++) for (int jj=0;jj<2;jj++) pacc[i][jj]=zz; }
    for (int c = 0; c < nch; c++){
      const unsigned short* Qc = Qu + (size_t)c*4096;
      #pragma unroll
      for (int k0 = 0; k0 < 4; k0++){
        h8_t af[2], bf[2];
        #pragma unroll
        for (int mt = 0; mt < 2; mt++){
          const unsigned short* pr = Qc + ((mt<<4) + l15)*128 + (k0<<5) + (quad<<3);
          u16x4 u = *(const u16x4*)pr, w = *(const u16x4*)(pr + 4);
          h8_t o;
          f4_t va, vb;
          #pragma unroll
          for (int jj = 0; jj < 4; jj++){
            float a3u = ((float)u[jj] - zp3)*s3;
            float nu = fminf(fmaxf(rintf(__expf(a3u - mR[mt])*rpR[mt]), 0.0f), 65535.0f);
            o[jj] = (_Float16)(nu*c1024);
            va[jj] = nu*p4s;
            float a3w = ((float)w[jj] - zp3)*s3;
            float nw = fminf(fmaxf(rintf(__expf(a3w - mR[mt])*rpR[mt]), 0.0f), 65535.0f);
            o[jj+4] = (_Float16)(nw*c1024);
            vb[jj] = nw*p4s;
          }
          af[mt] = o;
          float* ap = Ap + (size_t)((mt<<4) + l15)*1024 + (c<<7) + (k0<<5) + (quad<<3);
          *(f4_t*)ap = va;
          *(f4_t*)(ap + 4) = vb;
        }
        #pragma unroll
        for (int nt = 0; nt < 2; nt++)
          bf[nt] = *(const h8_t*)(Vb + (size_t)((wn<<5) + (nt<<4) + l15)*1024 + (c<<7) + (k0<<5) + (quad<<3));
        #pragma unroll
        for (int mt = 0; mt < 2; mt++)
          #pragma unroll
          for (int nt = 0; nt < 2; nt++)
            pacc[mt][nt] = __builtin_amdgcn_mfma_f32_16x16x32_f16(af[mt], bf[nt], pacc[mt][nt], 0, 0, 0);
      }
    }
    #pragma unroll
    for (int mt = 0; mt < 2; mt++)
      #pragma unroll
      for (int nt = 0; nt < 2; nt++){
        int Cc = (wn<<5) + (nt<<4) + l15;
        #pragma unroll
        for (int i = 0; i < 4; i++){
          int R = bm + (mt<<4) + (quad<<2) + i;
          float v = pacc[mt][nt][i]*(1.0f/1024.0f);
          Cb[(size_t)R*2048 + Cc] = v;
          cmn = fminf(cmn, v); cmx = fmaxf(cmx, v);
        }
      }
  }
  __shared__ float red[256];
  float bmn = bred_min(cmn, red), bmx = bred_max(cmx, red);
  if (tid == 0){ atomicMin(&stats[36*16], f2o(bmn)); atomicMax(&stats[37*16], f2o(bmx)); }
}

// ===========================================================================

// merged fq16+rmsnorm: blocks [0,1024) -> Q (slots 2->8, NHh=16, 32768 rows),
// blocks [1024,1536) -> K (slots 4->12, NHh=8, 16384 rows). Same grid-stride
// per sub-range as the previous separate launches -> bit-exact.
__global__ __launch_bounds__(256) void k_rms2(const float* __restrict__ qlin, float* __restrict__ qbuf,
                                              const float* __restrict__ qnw,
                                              const float* __restrict__ klin, float* __restrict__ kbuf,
                                              const float* __restrict__ knw, unsigned* stats){
  int isK = (blockIdx.x >= 1024);
  const float* lin = isK ? klin : qlin;
  float* buf = isK ? kbuf : qbuf;
  const float* gw = isK ? knw : qnw;
  int slot_lin = isK ? 4 : 2, slot_out = isK ? 12 : 8;
  int NHh = isK ? 8 : 16, rows = isK ? 16384 : 32768;
  int bid = isK ? (blockIdx.x - 1024) : blockIdx.x;
  int nblk = isK ? 512 : 1024;
  FQP pA = fqp(dec_slot(stats, slot_lin), dec_slot(stats, slot_lin+1));
  int lane = threadIdx.x & 63;
  int wv = (bid*256 + threadIdx.x) >> 6;
  int nwv = (nblk*256) >> 6;
  float w0 = gw[lane], w1 = gw[lane + 64];
  float fmn = FLT_MAX, fmx = -FLT_MAX, hmn = FLT_MAX, hmx = -FLT_MAX;
  for (int r = wv; r < rows; r += nwv){
    int h = r % NHh; int rem = r / NHh; int s2 = rem & 1023; int b = rem >> 10;
    const float* src = lin + (size_t)r*128;
    float x0 = fqa(src[lane], pA), x1 = fqa(src[lane + 64], pA);
    float ss = x0*x0 + x1*x1;
    #pragma unroll
    for (int m = 1; m < 64; m <<= 1) ss += __shfl_xor(ss, m, 64);
    float rr = 1.0f/sqrtf(ss*(1.0f/128.0f) + 1e-6f);
    float y0 = x0*rr*w0, y1 = x1*rr*w1;
    float* dst = buf + ((size_t)((b*NHh + h) << 10) + s2)*128;
    dst[lane] = y0; dst[lane + 64] = y1;
    fmn = fminf(fmn, fminf(y0, y1)); fmx = fmaxf(fmx, fmaxf(y0, y1));
    hmn = fminf(hmn, y1); hmx = fmaxf(hmx, y1);
  }
  __shared__ float red[256];
  float a = bred_min(fmn, red), bb = bred_max(fmx, red);
  float c = bred_min(hmn, red), d = bred_max(hmx, red);
  if (threadIdx.x == 0){
    atomicMin(&stats[slot_out*16], f2o(a));     atomicMax(&stats[(slot_out+1)*16], f2o(bb));
    atomicMin(&stats[(slot_out+2)*16], f2o(c)); atomicMax(&stats[(slot_out+3)*16], f2o(d));
  }
}

struct RopeQ { FQP B, C, E, F; };
__device__ RopeQ derive_rope(const unsigned* st, int base){
  float ymn = dec_slot(st, base),   ymx = dec_slot(st, base+1);
  float y2mn = dec_slot(st, base+2), y2mx = dec_slot(st, base+3);
  RopeQ r;
  r.B = fqp(ymn, ymx);
  float zmn = fqa(ymn, r.B), zmx = fqa(ymx, r.B);
  r.C = fqp(zmn, zmx);
  float zlo = fqa(zmn, r.C), zhi = fqa(zmx, r.C);
  float z2lo = fqa(fqa(y2mn, r.B), r.C), z2hi = fqa(fqa(y2mx, r.B), r.C);
  r.E = fqp(-z2hi, -z2lo);
  float nlo = fqa(-z2hi, r.E), nhi = fqa(-z2lo, r.E);
  r.F = fqp_raw(fminf(fminf(zlo, nlo), 0.0f), fmaxf(fmaxf(zhi, nhi), 0.0f));
  return r;
}

// merged RoPE: blocks [0,1024) -> Q (slots 8/16/24, NHh=16, 32768 rows),
// blocks [1024,1536) -> K (slots 12/20/26, NHh=8, 16384 rows).
__global__ __launch_bounds__(256) void k_rope(float* __restrict__ bufq, float* __restrict__ bufk,
                                              const float* __restrict__ cosp, const float* __restrict__ sinp,
                                              unsigned* stats, int do_write){
  int isK = (blockIdx.x >= 1024);
  float* buf = isK ? bufk : bufq;
  int slot_norm = isK ? 12 : 8, slot_prod = isK ? 20 : 16, slot_sum = isK ? 26 : 24;
  int NHh = isK ? 8 : 16, rows = isK ? 16384 : 32768;
  int bid = isK ? (blockIdx.x - 1024) : blockIdx.x;
  int nblk = isK ? 512 : 1024;
  RopeQ R = derive_rope(stats, slot_norm);
  FQP pD, pG;
  if (do_write){
    pD = fqp(dec_slot(stats, slot_prod),   dec_slot(stats, slot_prod+1));
    pG = fqp(dec_slot(stats, slot_prod+2), dec_slot(stats, slot_prod+3));
  }
  int lane = threadIdx.x & 63;
  int wv = (bid*256 + threadIdx.x) >> 6, nwv = (nblk*256) >> 6;
  float m0 = FLT_MAX, M0 = -FLT_MAX, m1 = FLT_MAX, M1 = -FLT_MAX;
  for (int r = wv; r < rows; r += nwv){
    int s2 = r & 1023; int bh = r >> 10; int b = bh/NHh;
    float* base = buf + (size_t)r*128;
    float y0 = base[lane], y1 = base[lane + 64];
    float z0 = fqa(fqa(y0, R.B), R.C), z1 = fqa(fqa(y1, R.B), R.C);
    const float* cr = cosp + (size_t)((b << 10) + s2)*128;
    const float* sr = sinp + (size_t)((b << 10) + s2)*128;
    float c0 = cr[lane], c1 = cr[lane + 64], sn0 = sr[lane], sn1 = sr[lane + 64];
    float pc0 = z0*c0, pc1 = z1*c1;
    float rh0 = fqa(fqa(-z1, R.E), R.F);
    float rh1 = fqa(z0, R.F);
    float ps0 = rh0*sn0, ps1 = rh1*sn1;
    if (!do_write){
      m0 = fminf(m0, fminf(pc0, pc1)); M0 = fmaxf(M0, fmaxf(pc0, pc1));
      m1 = fminf(m1, fminf(ps0, ps1)); M1 = fmaxf(M1, fmaxf(ps0, ps1));
    } else {
      float sv0 = fqa(pc0, pD) + fqa(ps0, pG);
      float sv1 = fqa(pc1, pD) + fqa(ps1, pG);
      base[lane] = sv0; base[lane + 64] = sv1;
      m0 = fminf(m0, fminf(sv0, sv1)); M0 = fmaxf(M0, fmaxf(sv0, sv1));
    }
  }
  __shared__ float red[256];
  if (!do_write){
    float a = bred_min(m0, red), bb = bred_max(M0, red);
    float c = bred_min(m1, red), d = bred_max(M1, red);
    if (threadIdx.x == 0){
      atomicMin(&stats[slot_prod*16], f2o(a));     atomicMax(&stats[(slot_prod+1)*16], f2o(bb));
      atomicMin(&stats[(slot_prod+2)*16], f2o(c)); atomicMax(&stats[(slot_prod+3)*16], f2o(d));
    }
  } else {
    float a = bred_min(m0, red), bb = bred_max(M0, red);
    if (threadIdx.x == 0){ atomicMin(&stats[slot_sum*16], f2o(a)); atomicMax(&stats[(slot_sum+1)*16], f2o(bb)); }
  }
}

extern "C" void kernel_launch(void* const* d_in, const int* in_sizes, int n_in,
                              void* d_out, int out_size, void* d_ws, size_t ws_size,
                              hipStream_t stream){
  (void)in_sizes; (void)n_in; (void)out_size; (void)ws_size;
  const float* hs   = (const float*)d_in[0];
  const float* cosp = (const float*)d_in[1];
  const float* sinp = (const float*)d_in[2];
  const float* Wq   = (const float*)d_in[4];
  const float* Wk   = (const float*)d_in[5];
  const float* Wv   = (const float*)d_in[6];
  const float* Wo   = (const float*)d_in[7];
  const float* qnw  = (const float*)d_in[8];
  const float* knw  = (const float*)d_in[9];

  float* outp = (float*)d_out;
  float* attn = outp + 4194304;      // final quantized softmax

  const size_t MEG = 1u << 20;       // floats
  float* wsf = (float*)d_ws;
  _Float16* woq_h = (_Float16*)(wsf + 0);
  _Float16* wqq_h = (_Float16*)(wsf + 2*MEG);
  _Float16* wkq_h = (_Float16*)(wsf + 4*MEG);
  _Float16* wvq_h = (_Float16*)(wsf + 5*MEG);
  _Float16* hsq_h = (_Float16*)(wsf + 6*MEG);
  float* qlin = wsf + 8*MEG;  float* ctx = qlin;   // ctx reuses qlin
  float* klin = wsf + 12*MEG;
  float* vlin = wsf + 14*MEG;
  float* qbuf = wsf + 16*MEG;
  float* kbuf = wsf + 20*MEG;
  _Float16* q_h   = (_Float16*)(wsf + 22*MEG);
  _Float16* k_h   = (_Float16*)(wsf + 24*MEG);
  _Float16* vT_h  = (_Float16*)(wsf + 25*MEG);
  _Float16* ctx_h = (_Float16*)(wsf + 26*MEG);
  unsigned* rowmin = (unsigned*)(wsf + 28*MEG);
  unsigned* rowmax = (unsigned*)(wsf + 28*MEG + 32768);
  float* denomS = wsf + 28*MEG + 65536;
  unsigned* stats = (unsigned*)(wsf + 28*MEG + 98304);
  // q3 levels: 32 z * 144 units * 4096 u16 = 36 MB. Overlays klin/vlin/qbuf/
  // kbuf (wsf+12M..21M floats) -- all dead before k_qk_denom writes it.
  unsigned short* q3buf = (unsigned short*)(wsf + 12*MEG);

  k_init<<<4, 256, 0, stream>>>(stats);

  // weight quant (blocks 0..12287) + hs minmax (blocks 12288..13311)
  k_quantw4<<<13312, 256, 0, stream>>>(Wq, Wk, Wv, Wo, wqq_h, wkq_h, wvq_h, woq_h, hs, stats);

  k_fq_ew16<<<4096, 256, 0, stream>>>(hs, hsq_h, stats, 0);

  // fused Q/K/V projections (128x64 tiles, 1024 blocks = 4/CU, BK=64)
  k_hgemm_qkv<<<dim3(16, 16, 4), 256, 0, stream>>>(hsq_h, wqq_h, wkq_h, wvq_h,
                                                   qlin, klin, vlin, 2048, stats);

  // merged fq16 + rmsnorm (q + k in one launch)
  k_rms2<<<1536, 256, 0, stream>>>(qlin, qbuf, qnw, klin, kbuf, knw, stats);

  // RoPE: merged q+k range pass then merged write pass
  k_rope<<<1536, 256, 0, stream>>>(qbuf, kbuf, cosp, sinp, stats, 0);
  k_rope<<<1536, 256, 0, stream>>>(qbuf, kbuf, cosp, sinp, stats, 1);

  // merged operand conversion for QK + V transpose
  k_fq_qk_vt<<<6656, 256, 0, stream>>>(qbuf, kbuf, vlin, q_h, k_h, vT_h, stats);

  // attention: stats (region-split, slot35 fused, + masked attn zero-fill) ->
  // denom (+q3 store, slot32 fused) -> pv (dequant-GEMM + causal attn write)
  k_qk_stats<<<dim3(48, 32), 256, 0, stream>>>(q_h, k_h, stats, rowmin, rowmax, attn);
  k_qk_denom<<<dim3(16, 32), 256, 0, stream>>>(q_h, k_h, rowmin, rowmax, denomS, q3buf, stats);
  k_qk_pv<<<dim3(16, 32), 256, 0, stream>>>(q3buf, vT_h, ctx, attn, rowmax, denomS, stats);

  // ctx (stats fused in PV) -> f16 -> O-proj (128x64 tiles, 2 blocks/CU, BK=64)
  k_fq_ew16<<<4096, 256, 0, stream>>>(ctx, ctx_h, stats, 36);
  k_hgemm_o<<<dim3(32, 16), 256, 0, stream>>>(ctx_h, woq_h, outp);
}